// Round 12
// baseline (1614.882 us; speedup 1.0000x reference)
//
#include <hip/hip_runtime.h>
#include <hip/hip_bf16.h>
#include <math.h>

#define N_ATOMS 2048
#define E_EDGES 65536
#define B_BATCH 8
#define H_DIM 128
#define G_DIM 50
#define F_DIM 64
#define S_DIM 16
#define MH_DIM 32
#define K_TOP 512
#define L_LAYERS 2
#define EPW2 16
#define PCHUNK 32
#define GPAD 52

static constexpr float STEP   = 10.0f / 49.0f;
static constexpr float COEFF  = -12.005f;
static constexpr float PI10   = 0.31415926535897931f;
static constexpr float LN2    = 0.69314718055994531f;
static constexpr float LAMBDA = 0.002f;

#define DEV static __device__ __forceinline__

DEV float ssp_f(float x) { return fmaxf(x, 0.f) + log1pf(expf(-fabsf(x))) - LN2; }
DEV float ccut_f(float d) { return 0.5f * (cosf(d * PI10) + 1.f); }
DEV float sigm_f(float x) { return 1.f / (1.f + expf(-x)); }

// ---------------- dtype detect ----------------
__global__ __launch_bounds__(256) void k_detect(const unsigned short* raw, int n, int* flag) {
    __shared__ int any;
    if (threadIdx.x == 0) any = 0;
    __syncthreads();
    for (int i = threadIdx.x; i < n; i += 256) {
        unsigned int bits = ((unsigned int)raw[i]) << 16;
        float f = __uint_as_float(bits);
        if (!(fabsf(f) <= 1e10f)) any = 1;
    }
    __syncthreads();
    if (threadIdx.x == 0) flag[0] = any;
}

// ---------------- fused convert ----------------
struct ConvArgs {
    const void* p[25];
    int off[26];
};

__global__ __launch_bounds__(256) void k_convert_all(ConvArgs a, float* dst, const int* flag) {
    int i = blockIdx.x * 256 + threadIdx.x;
    int total = a.off[25];
    if (i >= total) return;
    int seg = 0;
    while (i >= a.off[seg + 1]) seg++;
    int k = i - a.off[seg];
    if (flag[0]) {
        dst[i] = ((const float*)a.p[seg])[k];
    } else {
        unsigned int bits = ((unsigned int)((const unsigned short*)a.p[seg])[k]) << 16;
        dst[i] = __uint_as_float(bits);
    }
}

// ---------------- edge counting-sort by dst ----------------
__global__ __launch_bounds__(256) void k_ehist(const int* dst, int* hist) {
    int e = blockIdx.x * 256 + threadIdx.x;
    atomicAdd(&hist[dst[e]], 1);
}

__global__ __launch_bounds__(1024) void k_escan(const int* hist, int* ebase, int* ecur) {
    __shared__ int bufA[N_ATOMS], bufB[N_ATOMS];
    int t = threadIdx.x;
    for (int i = t; i < N_ATOMS; i += 1024) bufA[i] = hist[i];
    __syncthreads();
    int* in = bufA;
    int* out = bufB;
    for (int d = 1; d < N_ATOMS; d <<= 1) {
        for (int i = t; i < N_ATOMS; i += 1024) out[i] = in[i] + (i >= d ? in[i - d] : 0);
        __syncthreads();
        int* tmp = in; in = out; out = tmp;
    }
    for (int i = t; i < N_ATOMS; i += 1024) {
        int ex = in[i] - hist[i];
        ebase[i] = ex;
        ecur[i] = ex;
    }
}

__global__ __launch_bounds__(256) void k_escatter(const int* dst, int* ecur, int* esorted) {
    int e = blockIdx.x * 256 + threadIdx.x;
    int pos = atomicAdd(&ecur[dst[e]], 1);
    esorted[pos] = e;
}

// ---------------- embedding ----------------
__global__ __launch_bounds__(256) void k_embed(const int* atoms, const float* emb, float* h) {
    int i = blockIdx.x * 256 + threadIdx.x;
    int n = i >> 7, c = i & 127;
    h[i] = emb[atoms[n] * H_DIM + c];
}

// ---------------- x = h @ cf1 ----------------
__global__ __launch_bounds__(256) void k_x(const float* __restrict__ h, const float* __restrict__ cf1,
                                           float* __restrict__ x, int M) {
    int wave = threadIdx.x >> 6, lane = threadIdx.x & 63;
    int n = blockIdx.x * 4 + wave;
    if (n >= M) return;
    float acc = 0.f;
    for (int k = 0; k < H_DIM; k++) acc += h[n * H_DIM + k] * cf1[k * F_DIM + lane];
    x[n * F_DIM + lane] = acc;
}

// ---------------- edge filter over dst-sorted edges, b128 broadcasts, 3 waves/EU ----------------
__global__ __launch_bounds__(256, 3) void k_edge_s(const int* esorted, const float* pos,
                                                   const int* src, const int* dst, const float* x,
                                                   const float* mw1, const float* mb1,
                                                   const float* mw2, const float* mb2,
                                                   float* agg) {
    __shared__ float gbuf[4][GPAD], tbuf[4][F_DIM];
    int t = threadIdx.x, wave = t >> 6, lane = t & 63;
    float w1r[GPAD], w2r[F_DIM];
    #pragma unroll
    for (int g = 0; g < G_DIM; g++) w1r[g] = mw1[g * F_DIM + lane];
    w1r[50] = 0.f; w1r[51] = 0.f;
    #pragma unroll
    for (int k = 0; k < F_DIM; k++) w2r[k] = mw2[k * F_DIM + lane];
    float b1 = mb1[lane], b2v = mb2[lane];
    if (lane >= G_DIM && lane < GPAD) gbuf[wave][lane] = 0.f;
    int p0 = (blockIdx.x * 4 + wave) * EPW2;
    int curDst = -1;
    float acc = 0.f;
    for (int ee = 0; ee < EPW2; ee++) {
        int e = esorted[p0 + ee];
        int sI = src[e], dI = dst[e];
        float dx = pos[sI * 3 + 0] - pos[dI * 3 + 0];
        float dy = pos[sI * 3 + 1] - pos[dI * 3 + 1];
        float dz = pos[sI * 3 + 2] - pos[dI * 3 + 2];
        float d = sqrtf(dx * dx + dy * dy + dz * dz + 1e-12f);
        if (lane < G_DIM) { float u = d - lane * STEP; gbuf[wave][lane] = expf(COEFF * u * u); }
        float tv = b1;
        const float4* g4 = (const float4*)gbuf[wave];
        #pragma unroll
        for (int gg = 0; gg < 13; gg++) {
            float4 gv = g4[gg];
            tv += gv.x * w1r[4 * gg + 0];
            tv += gv.y * w1r[4 * gg + 1];
            tv += gv.z * w1r[4 * gg + 2];
            tv += gv.w * w1r[4 * gg + 3];
        }
        tv = ssp_f(tv);
        tbuf[wave][lane] = tv;
        float w = b2v;
        const float4* t4v = (const float4*)tbuf[wave];
        #pragma unroll
        for (int kk = 0; kk < 16; kk++) {
            float4 tq = t4v[kk];
            w += tq.x * w2r[4 * kk + 0];
            w += tq.y * w2r[4 * kk + 1];
            w += tq.z * w2r[4 * kk + 2];
            w += tq.w * w2r[4 * kk + 3];
        }
        w *= ccut_f(d);
        float contrib = x[sI * F_DIM + lane] * w;
        if (dI != curDst) {
            if (curDst >= 0) atomicAdd(&agg[curDst * F_DIM + lane], acc);
            acc = 0.f;
            curDst = dI;
        }
        acc += contrib;
    }
    if (curDst >= 0) atomicAdd(&agg[curDst * F_DIM + lane], acc);
}

// ---------------- out = base + ssp(agg@cf2w + cf2b) @ lw + lb ----------------
__global__ __launch_bounds__(256) void k_update(const float* __restrict__ agg, const float* __restrict__ base,
                                                const float* cf2w, const float* cf2b,
                                                const float* lw, const float* lb,
                                                float* out, int M) {
    __shared__ float tbuf[4][H_DIM];
    int wave = threadIdx.x >> 6, lane = threadIdx.x & 63;
    int n = blockIdx.x * 4 + wave;
    float t0 = cf2b[lane], t1 = cf2b[lane + 64];
    if (n < M) {
        for (int f = 0; f < F_DIM; f++) {
            float a = agg[n * F_DIM + f];
            t0 += a * cf2w[f * H_DIM + lane];
            t1 += a * cf2w[f * H_DIM + lane + 64];
        }
    }
    tbuf[wave][lane] = ssp_f(t0);
    tbuf[wave][lane + 64] = ssp_f(t1);
    __syncthreads();
    if (n < M) {
        float o0 = lb[lane], o1 = lb[lane + 64];
        const float4* t4v = (const float4*)tbuf[wave];
        #pragma unroll
        for (int kk = 0; kk < 32; kk++) {
            float4 tq = t4v[kk];
            int k4 = kk * 4;
            o0 += tq.x * lw[(k4 + 0) * H_DIM + lane];
            o1 += tq.x * lw[(k4 + 0) * H_DIM + lane + 64];
            o0 += tq.y * lw[(k4 + 1) * H_DIM + lane];
            o1 += tq.y * lw[(k4 + 1) * H_DIM + lane + 64];
            o0 += tq.z * lw[(k4 + 2) * H_DIM + lane];
            o1 += tq.z * lw[(k4 + 2) * H_DIM + lane + 64];
            o0 += tq.w * lw[(k4 + 3) * H_DIM + lane];
            o1 += tq.w * lw[(k4 + 3) * H_DIM + lane + 64];
        }
        out[n * H_DIM + lane]      = base[n * H_DIM + lane] + o0;
        out[n * H_DIM + lane + 64] = base[n * H_DIM + lane + 64] + o1;
    }
}

// ---------------- node scores ----------------
__global__ __launch_bounds__(256) void k_scores(const float* h_local,
                                                const float* msw1, const float* msb1,
                                                const float* msw2, const float* msb2,
                                                float* scores) {
    int n = blockIdx.x * 256 + threadIdx.x;
    if (n >= N_ATOMS) return;
    float hs[S_DIM];
    for (int s = 0; s < S_DIM; s++) hs[s] = h_local[n * H_DIM + s];
    float sc = msb2[0];
    for (int j = 0; j < MH_DIM; j++) {
        float v = msb1[j];
        for (int s = 0; s < S_DIM; s++) v += hs[s] * msw1[s * MH_DIM + j];
        sc += fmaxf(v, 0.f) * msw2[j];
    }
    scores[n] = sc;
}

// ---------------- exact rank ----------------
__global__ __launch_bounds__(256) void k_rank(const float* scores, int* rank) {
    __shared__ float s[N_ATOMS];
    for (int i = threadIdx.x; i < N_ATOMS; i += 256) s[i] = scores[i];
    __syncthreads();
    int i = blockIdx.x * 256 + threadIdx.x;
    float si = s[i];
    int r = 0;
    for (int j = 0; j < N_ATOMS; j++) {
        float sj = s[j];
        r += (sj > si) || (sj == si && j < i);
    }
    rank[i] = r;
}

// ---------------- selection, prefix, midx, m ----------------
__global__ __launch_bounds__(1024) void k_select(const float* scores, const int* rank,
                                                 int* is_m, int* invg, int* midx, float* m) {
    __shared__ int flag[N_ATOMS];
    __shared__ int bufA[N_ATOMS], bufB[N_ATOMS];
    __shared__ float kth;
    int t = threadIdx.x;
    for (int i = t; i < N_ATOMS; i += 1024) {
        int f = rank[i] < K_TOP;
        flag[i] = f;
        bufA[i] = f;
        if (rank[i] == K_TOP - 1) kth = scores[i];
    }
    __syncthreads();
    int* in = bufA;
    int* out = bufB;
    for (int d = 1; d < N_ATOMS; d <<= 1) {
        for (int i = t; i < N_ATOMS; i += 1024) out[i] = in[i] + (i >= d ? in[i - d] : 0);
        __syncthreads();
        int* tmp = in; in = out; out = tmp;
    }
    float kv = kth;
    for (int i = t; i < N_ATOMS; i += 1024) {
        int f = flag[i];
        int pos = in[i] - f;
        is_m[i] = f;
        invg[i] = f ? pos : 0;
        if (f) midx[pos] = i;
        m[i] = sigm_f(scores[i] - kv + 1e-6f);
    }
}

// ---------------- gather h_m / pos_m ----------------
__global__ __launch_bounds__(256) void k_gather(const int* midx, const float* h_local,
                                                const float* pos, float* h_m, float* pos_m) {
    int i = blockIdx.x * 256 + threadIdx.x;
    int k = i >> 7, c = i & 127;
    int n = midx[k];
    h_m[i] = h_local[n * H_DIM + c];
    if (c < 3) pos_m[k * 3 + c] = pos[n * 3 + c];
}

// ---------------- adjacency + valid-edge list ----------------
__global__ __launch_bounds__(256) void k_adj(const int* src, const int* dst, const int* is_m,
                                             const int* invg, unsigned char* adj,
                                             int* velist, int* nve) {
    int e = blockIdx.x * 256 + threadIdx.x;
    int s = src[e], d = dst[e];
    bool valid = is_m[s] && is_m[d];
    if (valid) adj[invg[s] * K_TOP + invg[d]] = 1;
    unsigned long long mask = __ballot(valid);
    int lane = threadIdx.x & 63;
    int cnt = __popcll(mask);
    int base = 0;
    if (lane == 0 && cnt) base = atomicAdd(nve, cnt);
    base = __shfl(base, 0);
    if (valid) velist[base + __popcll(mask & ((1ull << lane) - 1))] = e;
}

// ---------------- q/k projections ----------------
__global__ __launch_bounds__(256) void k_qk(const float* h_m, const float* wq,
                                            const float* wk, float* qm, float* km) {
    int gid = blockIdx.x * 256 + threadIdx.x;
    int r = gid >> 5, t = gid & 31;
    const float* w = (t < 16) ? wq : wk;
    int c = t & 15;
    float acc = 0.f;
    for (int s = 0; s < S_DIM; s++) acc += h_m[r * H_DIM + s] * w[s * S_DIM + c];
    if (t < 16) qm[r * S_DIM + c] = acc; else km[r * S_DIM + c] = acc;
}

// ---------------- attention softmax -> Av mask ----------------
__global__ __launch_bounds__(256) void k_attn(const float* qm, const float* km,
                                              const unsigned char* adj, unsigned char* Av) {
    __shared__ float lrow[K_TOP];
    __shared__ float red[256];
    int i = blockIdx.x, t = threadIdx.x;
    float q[S_DIM];
    for (int s = 0; s < S_DIM; s++) q[s] = qm[i * S_DIM + s];
    for (int j = t; j < K_TOP; j += 256) {
        float acc = 0.f;
        for (int s = 0; s < S_DIM; s++) acc += q[s] * km[j * S_DIM + s];
        lrow[j] = acc * 0.25f;
    }
    __syncthreads();
    float mx = -1e30f;
    for (int j = t; j < K_TOP; j += 256) mx = fmaxf(mx, lrow[j]);
    red[t] = mx; __syncthreads();
    for (int o = 128; o > 0; o >>= 1) { if (t < o) red[t] = fmaxf(red[t], red[t + o]); __syncthreads(); }
    mx = red[0]; __syncthreads();
    float sum = 0.f;
    for (int j = t; j < K_TOP; j += 256) sum += expf(lrow[j] - mx);
    red[t] = sum; __syncthreads();
    for (int o = 128; o > 0; o >>= 1) { if (t < o) red[t] += red[t + o]; __syncthreads(); }
    float inv_s = 1.f / red[0];
    for (int j = t; j < K_TOP; j += 256) {
        float a = expf(lrow[j] - mx) * inv_s;
        Av[i * K_TOP + j] = (a > LAMBDA) && (!adj[i * K_TOP + j]) && (i != j);
    }
}

// ---------------- deterministic j-major pair compaction ----------------
__global__ __launch_bounds__(256) void k_pcount(const unsigned char* Av, int* bcount) {
    __shared__ int wsum[4];
    int idx = blockIdx.x * 256 + threadIdx.x;
    int j = idx >> 9, i = idx & (K_TOP - 1);
    bool act = Av[i * K_TOP + j] != 0;
    unsigned long long mask = __ballot(act);
    int lane = threadIdx.x & 63, wave = threadIdx.x >> 6;
    if (lane == 0) wsum[wave] = __popcll(mask);
    __syncthreads();
    if (threadIdx.x == 0) bcount[blockIdx.x] = wsum[0] + wsum[1] + wsum[2] + wsum[3];
}

__global__ __launch_bounds__(1024) void k_pscan(const int* bcount, int* boffset, int* total) {
    __shared__ int bufA[1024], bufB[1024];
    int t = threadIdx.x;
    bufA[t] = bcount[t];
    __syncthreads();
    int* in = bufA;
    int* out = bufB;
    for (int d = 1; d < 1024; d <<= 1) {
        out[t] = in[t] + (t >= d ? in[t - d] : 0);
        __syncthreads();
        int* tmp = in; in = out; out = tmp;
    }
    boffset[t] = in[t] - bcount[t];
    if (t == 1023) total[0] = in[1023];
}

__global__ __launch_bounds__(256) void k_pscatter(const unsigned char* Av, const int* boffset,
                                                  unsigned int* plist) {
    __shared__ int wsum[4], woff[4];
    int idx = blockIdx.x * 256 + threadIdx.x;
    int j = idx >> 9, i = idx & (K_TOP - 1);
    bool act = Av[i * K_TOP + j] != 0;
    unsigned long long mask = __ballot(act);
    int lane = threadIdx.x & 63, wave = threadIdx.x >> 6;
    if (lane == 0) wsum[wave] = __popcll(mask);
    __syncthreads();
    if (threadIdx.x == 0) {
        int s = 0;
        for (int w = 0; w < 4; w++) { woff[w] = s; s += wsum[w]; }
    }
    __syncthreads();
    if (act) {
        int pos = boffset[blockIdx.x] + woff[wave] + __popcll(mask & ((1ull << lane) - 1));
        plist[pos] = ((unsigned int)j << 9) | (unsigned int)i;
    }
}

// ---------------- pairwise distances ----------------
__global__ __launch_bounds__(256) void k_dmat(const float* pos_m, float* dmat) {
    int idx = blockIdx.x * 256 + threadIdx.x;
    int i = idx >> 9, j = idx & (K_TOP - 1);
    float dx = pos_m[i * 3 + 0] - pos_m[j * 3 + 0];
    float dy = pos_m[i * 3 + 1] - pos_m[j * 3 + 1];
    float dz = pos_m[i * 3 + 2] - pos_m[j * 3 + 2];
    dmat[idx] = sqrtf(dx * dx + dy * dy + dz * dz + 1e-12f);
}

// ---------------- hi = h_m@Wi, hj = h_m@Wj ----------------
__global__ __launch_bounds__(256) void k_hij(const float* h_m, const float* aw1,
                                             float* hi, float* hj) {
    int wave = threadIdx.x >> 6, lane = threadIdx.x & 63;
    int idx = blockIdx.x * 4 + wave;
    int which = idx >> 9;
    int r = idx & (K_TOP - 1);
    const float* W = aw1 + which * H_DIM * H_DIM;
    float o0 = 0.f, o1 = 0.f;
    for (int k = 0; k < H_DIM; k++) {
        float hv = h_m[r * H_DIM + k];
        o0 += hv * W[k * H_DIM + lane];
        o1 += hv * W[k * H_DIM + lane + 64];
    }
    float* out = which ? hj : hi;
    out[r * H_DIM + lane] = o0;
    out[r * H_DIM + lane + 64] = o1;
}

// ---------------- per-pair attention scores, b128 broadcasts, 3 waves/EU ----------------
__global__ __launch_bounds__(256, 3) void k_score_p(const unsigned int* plist, const int* npairs,
                                                    const float* hi, const float* hj,
                                                    const float* aw1, const float* ab1,
                                                    const float* aw2, const float* ab2,
                                                    const float* dmat, float* sbuf) {
    __shared__ float gbuf[4][GPAD];
    int t = threadIdx.x, wave = t >> 6, lane = t & 63;
    const float* wd = aw1 + 2 * H_DIM * H_DIM;
    float wdr0[GPAD], wdr1[GPAD];
    #pragma unroll
    for (int g = 0; g < G_DIM; g++) {
        wdr0[g] = wd[g * H_DIM + lane];
        wdr1[g] = wd[g * H_DIM + lane + 64];
    }
    wdr0[50] = 0.f; wdr0[51] = 0.f;
    wdr1[50] = 0.f; wdr1[51] = 0.f;
    float ab0 = ab1[lane], ab1v = ab1[lane + 64];
    float aw0 = aw2[lane], aw1v = aw2[lane + 64];
    float b2 = ab2[0];
    if (lane >= G_DIM && lane < GPAD) gbuf[wave][lane] = 0.f;
    int n = npairs[0];
    int wid = blockIdx.x * 4 + wave;
    int nw = gridDim.x * 4;
    for (int p = wid; p < n; p += nw) {
        unsigned int key = plist[p];
        int j = key >> 9, i = key & (K_TOP - 1);
        int ij = i * K_TOP + j;
        float dd = dmat[ij];
        if (lane < G_DIM) { float u = dd - lane * STEP; gbuf[wave][lane] = expf(COEFF * u * u); }
        float v0 = hi[i * H_DIM + lane] + hj[j * H_DIM + lane] + ab0;
        float v1 = hi[i * H_DIM + lane + 64] + hj[j * H_DIM + lane + 64] + ab1v;
        const float4* g4 = (const float4*)gbuf[wave];
        #pragma unroll
        for (int gg = 0; gg < 13; gg++) {
            float4 gv = g4[gg];
            v0 += gv.x * wdr0[4 * gg + 0]; v1 += gv.x * wdr1[4 * gg + 0];
            v0 += gv.y * wdr0[4 * gg + 1]; v1 += gv.y * wdr1[4 * gg + 1];
            v0 += gv.z * wdr0[4 * gg + 2]; v1 += gv.z * wdr1[4 * gg + 2];
            v0 += gv.w * wdr0[4 * gg + 3]; v1 += gv.w * wdr1[4 * gg + 3];
        }
        float pv = fmaxf(v0, 0.f) * aw0 + fmaxf(v1, 0.f) * aw1v;
        for (int o = 1; o < 64; o <<= 1) pv += __shfl_xor(pv, o);
        if (lane == 0) sbuf[ij] = pv + b2;
    }
}

// ---------------- row softmax (Av-guarded) -> decay ----------------
__global__ __launch_bounds__(256) void k_decay(const float* sbuf, const unsigned char* Av, float* decay) {
    __shared__ float srow[K_TOP];
    __shared__ float red[256];
    int i = blockIdx.x, t = threadIdx.x;
    for (int j = t; j < K_TOP; j += 256)
        srow[j] = Av[i * K_TOP + j] ? sbuf[i * K_TOP + j] : -1e9f;
    __syncthreads();
    float mx = -1e30f;
    for (int j = t; j < K_TOP; j += 256) mx = fmaxf(mx, srow[j]);
    red[t] = mx; __syncthreads();
    for (int o = 128; o > 0; o >>= 1) { if (t < o) red[t] = fmaxf(red[t], red[t + o]); __syncthreads(); }
    mx = red[0]; __syncthreads();
    float sum = 0.f;
    for (int j = t; j < K_TOP; j += 256) sum += (srow[j] > -5e8f) ? expf(srow[j] - mx) : 0.f;
    red[t] = sum; __syncthreads();
    for (int o = 128; o > 0; o >>= 1) { if (t < o) red[t] += red[t + o]; __syncthreads(); }
    float s_total = red[0];
    float inv_s = (s_total > 0.f) ? 1.f / s_total : 0.f;
    for (int j = t; j < K_TOP; j += 256)
        decay[i * K_TOP + j] = (srow[j] > -5e8f) ? expf(srow[j] - mx) * inv_s : 0.f;
}

// ---------------- agg_d over j-major list, b128 broadcasts, 3 waves/EU ----------------
__global__ __launch_bounds__(256, 3) void k_aggd_p2(const unsigned int* plist, const int* npairs,
                                                    const float* xm, const float* dmat, const float* decay,
                                                    const float* mw1, const float* mb1,
                                                    const float* mw2, const float* mb2,
                                                    float* agg_m) {
    __shared__ float gbuf[4][GPAD], tbuf[4][F_DIM];
    int t = threadIdx.x, wave = t >> 6, lane = t & 63;
    float w1r[GPAD], w2r[F_DIM];
    #pragma unroll
    for (int g = 0; g < G_DIM; g++) w1r[g] = mw1[g * F_DIM + lane];
    w1r[50] = 0.f; w1r[51] = 0.f;
    #pragma unroll
    for (int k = 0; k < F_DIM; k++) w2r[k] = mw2[k * F_DIM + lane];
    float b1 = mb1[lane], b2v = mb2[lane];
    if (lane >= G_DIM && lane < GPAD) gbuf[wave][lane] = 0.f;
    int n = npairs[0];
    int nchunks = (n + PCHUNK - 1) / PCHUNK;
    int wid = blockIdx.x * 4 + wave;
    int nw = gridDim.x * 4;
    for (int c = wid; c < nchunks; c += nw) {
        int p0 = c * PCHUNK;
        int p1 = min(p0 + PCHUNK, n);
        int curJ = -1;
        float acc = 0.f;
        for (int p = p0; p < p1; p++) {
            unsigned int key = plist[p];
            int j = key >> 9, i = key & (K_TOP - 1);
            int ij = i * K_TOP + j;
            float dd = dmat[ij];
            float dec = decay[ij];
            if (lane < G_DIM) { float u = dd - lane * STEP; gbuf[wave][lane] = expf(COEFF * u * u) * dec; }
            float tv = b1;
            const float4* g4 = (const float4*)gbuf[wave];
            #pragma unroll
            for (int gg = 0; gg < 13; gg++) {
                float4 gv = g4[gg];
                tv += gv.x * w1r[4 * gg + 0];
                tv += gv.y * w1r[4 * gg + 1];
                tv += gv.z * w1r[4 * gg + 2];
                tv += gv.w * w1r[4 * gg + 3];
            }
            tv = ssp_f(tv);
            tbuf[wave][lane] = tv;
            float w = b2v;
            const float4* t4v = (const float4*)tbuf[wave];
            #pragma unroll
            for (int kk = 0; kk < 16; kk++) {
                float4 tq = t4v[kk];
                w += tq.x * w2r[4 * kk + 0];
                w += tq.y * w2r[4 * kk + 1];
                w += tq.z * w2r[4 * kk + 2];
                w += tq.w * w2r[4 * kk + 3];
            }
            float contrib = xm[i * F_DIM + lane] * w * ccut_f(dd);
            if (j != curJ) {
                if (curJ >= 0) atomicAdd(&agg_m[curJ * F_DIM + lane], acc);
                acc = 0.f;
                curJ = j;
            }
            acc += contrib;
        }
        if (curJ >= 0) atomicAdd(&agg_m[curJ * F_DIM + lane], acc);
    }
}

// ---------------- valid-edge filter over compacted list, b128, 3 waves/EU ----------------
__global__ __launch_bounds__(256, 3) void k_aggs_p(const int* velist, const int* nve,
                                                   const float* pos_m, const int* src, const int* dst,
                                                   const int* invg, const float* xm,
                                                   const float* mw1, const float* mb1,
                                                   const float* mw2, const float* mb2,
                                                   float* agg_m) {
    __shared__ float gbuf[4][GPAD], tbuf[4][F_DIM];
    int t = threadIdx.x, wave = t >> 6, lane = t & 63;
    float w1r[GPAD], w2r[F_DIM];
    #pragma unroll
    for (int g = 0; g < G_DIM; g++) w1r[g] = mw1[g * F_DIM + lane];
    w1r[50] = 0.f; w1r[51] = 0.f;
    #pragma unroll
    for (int k = 0; k < F_DIM; k++) w2r[k] = mw2[k * F_DIM + lane];
    float b1 = mb1[lane], b2v = mb2[lane];
    if (lane >= G_DIM && lane < GPAD) gbuf[wave][lane] = 0.f;
    int n = nve[0];
    int wid = blockIdx.x * 4 + wave;
    int nw = gridDim.x * 4;
    for (int p = wid; p < n; p += nw) {
        int e = velist[p];
        int sm = invg[src[e]];
        int dm = invg[dst[e]];
        float dx = pos_m[sm * 3 + 0] - pos_m[dm * 3 + 0];
        float dy = pos_m[sm * 3 + 1] - pos_m[dm * 3 + 1];
        float dz = pos_m[sm * 3 + 2] - pos_m[dm * 3 + 2];
        float d = sqrtf(dx * dx + dy * dy + dz * dz + 1e-12f);
        if (lane < G_DIM) { float u = d - lane * STEP; gbuf[wave][lane] = expf(COEFF * u * u); }
        float tv = b1;
        const float4* g4 = (const float4*)gbuf[wave];
        #pragma unroll
        for (int gg = 0; gg < 13; gg++) {
            float4 gv = g4[gg];
            tv += gv.x * w1r[4 * gg + 0];
            tv += gv.y * w1r[4 * gg + 1];
            tv += gv.z * w1r[4 * gg + 2];
            tv += gv.w * w1r[4 * gg + 3];
        }
        tv = ssp_f(tv);
        tbuf[wave][lane] = tv;
        float w = b2v;
        const float4* t4v = (const float4*)tbuf[wave];
        #pragma unroll
        for (int kk = 0; kk < 16; kk++) {
            float4 tq = t4v[kk];
            w += tq.x * w2r[4 * kk + 0];
            w += tq.y * w2r[4 * kk + 1];
            w += tq.z * w2r[4 * kk + 2];
            w += tq.w * w2r[4 * kk + 3];
        }
        atomicAdd(&agg_m[dm * F_DIM + lane], xm[sm * F_DIM + lane] * w * ccut_f(d));
    }
}

// ---------------- blend ----------------
__global__ __launch_bounds__(256) void k_blend(const float* h_local, const float* h_hier,
                                               const int* is_m, const int* invg, const float* m,
                                               float* h_out) {
    int idx = blockIdx.x * 256 + threadIdx.x;
    int n = idx >> 7, c = idx & 127;
    float mm = m[n];
    float hh = is_m[n] ? h_hier[invg[n] * H_DIM + c] : 0.f;
    h_out[idx] = (1.f - mm) * h_local[idx] + mm * hh;
}

// ---------------- parallel segment-sum pooling ----------------
__global__ __launch_bounds__(256) void k_pool(const float* __restrict__ h, const int* __restrict__ batch,
                                              float* pooled) {
    int c = threadIdx.x & 127, a = threadIdx.x >> 7;
    int n0 = blockIdx.x * 64;
    float acc = 0.f;
    int cur = batch[n0 + a];
    for (int i = a; i < 64; i += 2) {
        int n = n0 + i;
        int b = batch[n];
        if (b != cur) { atomicAdd(&pooled[cur * H_DIM + c], acc); acc = 0.f; cur = b; }
        acc += h[n * H_DIM + c];
    }
    atomicAdd(&pooled[cur * H_DIM + c], acc);
}

// ---------------- predict MLP ----------------
__global__ __launch_bounds__(128) void k_pred2(const float* pooled,
                                               const float* w1, const float* b1,
                                               const float* w2, const float* b2,
                                               void* outv, const int* flag) {
    __shared__ float c64[64];
    int b = blockIdx.x, t = threadIdx.x;
    if (t < 64) {
        float v = b1[t];
        for (int k = 0; k < H_DIM; k++) v += pooled[b * H_DIM + k] * w1[k * 64 + t];
        c64[t] = v * sigm_f(v);
    }
    __syncthreads();
    if (t == 0) {
        float o = b2[0];
        for (int k = 0; k < 64; k++) o += c64[k] * w2[k];
        if (flag[0]) ((float*)outv)[b] = o;
        else ((__hip_bfloat16*)outv)[b] = __float2bfloat16(o);
    }
}

extern "C" void kernel_launch(void* const* d_in, const int* in_sizes, int n_in,
                              void* d_out, int out_size, void* d_ws, size_t ws_size,
                              hipStream_t stream) {
    (void)n_in; (void)out_size; (void)ws_size;
    const int* atoms = (const int*)d_in[0];
    const int* src = (const int*)d_in[2];
    const int* dst = (const int*)d_in[3];
    const int* batch = (const int*)d_in[4];

    float* W = (float*)d_ws;
    int* dflag = (int*)W; W += 16;
    int* counters = (int*)W; W += 16;  // [0]=npairs, [1]=nve

    static const int fidx[25] = {1,5,6,7,8,9,10,11,12,13,14,15,16,17,18,19,20,21,22,23,24,25,26,27,28};
    float* fin[29];
    ConvArgs ca;
    float* convBase = W;
    int off = 0;
    for (int q = 0; q < 25; q++) {
        int i = fidx[q];
        ca.p[q] = d_in[i];
        ca.off[q] = off;
        fin[i] = convBase + off;
        off += in_sizes[i];
    }
    ca.off[25] = off;
    W += off;

    k_detect<<<1, 256, 0, stream>>>((const unsigned short*)d_in[5], in_sizes[5], dflag);
    k_convert_all<<<(off + 255) / 256, 256, 0, stream>>>(ca, convBase, dflag);

    const float* posf = fin[1];
    const float* embf = fin[5];

    float* h      = W; W += N_ATOMS * H_DIM;
    float* h_loc  = W; W += N_ATOMS * H_DIM;
    float* xbuf   = W; W += N_ATOMS * F_DIM;
    float* aggbuf = W; W += N_ATOMS * F_DIM;
    float* scores = W; W += N_ATOMS;
    float* mbuf   = W; W += N_ATOMS;
    float* h_m    = W; W += K_TOP * H_DIM;
    float* pos_m  = W; W += K_TOP * 3;
    float* xm     = W; W += K_TOP * F_DIM;
    float* qm     = W; W += K_TOP * S_DIM;
    float* km     = W; W += K_TOP * S_DIM;
    float* dmat   = W; W += K_TOP * K_TOP;
    float* decay  = W; W += K_TOP * K_TOP;
    float* sbuf   = W; W += K_TOP * K_TOP;
    float* hi     = W; W += K_TOP * H_DIM;
    float* hj     = W; W += K_TOP * H_DIM;
    float* agg_m  = W; W += K_TOP * F_DIM;
    float* h_hier = W; W += K_TOP * H_DIM;
    float* pooled = W; W += B_BATCH * H_DIM;
    int* rankb  = (int*)W; W += N_ATOMS;
    int* is_m   = (int*)W; W += N_ATOMS;
    int* invg   = (int*)W; W += N_ATOMS;
    int* midx   = (int*)W; W += K_TOP;
    unsigned int* plist = (unsigned int*)W; W += K_TOP * K_TOP;
    int* velist = (int*)W; W += E_EDGES;
    int* esorted = (int*)W; W += E_EDGES;
    int* ehist  = (int*)W; W += N_ATOMS;
    int* ebase  = (int*)W; W += N_ATOMS;
    int* ecur   = (int*)W; W += N_ATOMS;
    int* bcount = (int*)W; W += 1024;
    int* boffset = (int*)W; W += 1024;
    unsigned char* adj = (unsigned char*)W; W += (K_TOP * K_TOP) / 4;
    unsigned char* Av  = (unsigned char*)W; W += (K_TOP * K_TOP) / 4;

    // one-time: counting-sort edges by dst
    (void)hipMemsetAsync(ehist, 0, N_ATOMS * sizeof(int), stream);
    k_ehist<<<E_EDGES / 256, 256, 0, stream>>>(dst, ehist);
    k_escan<<<1, 1024, 0, stream>>>(ehist, ebase, ecur);
    k_escatter<<<E_EDGES / 256, 256, 0, stream>>>(dst, ecur, esorted);

    k_embed<<<(N_ATOMS * H_DIM) / 256, 256, 0, stream>>>(atoms, embf, h);

    for (int l = 0; l < L_LAYERS; l++) {
        const float* mw1 = fin[6]  + l * G_DIM * F_DIM;
        const float* mb1 = fin[7]  + l * F_DIM;
        const float* mw2 = fin[8]  + l * F_DIM * F_DIM;
        const float* mb2 = fin[9]  + l * F_DIM;
        const float* cf1 = fin[10] + l * H_DIM * F_DIM;
        const float* cf2w = fin[11] + l * F_DIM * H_DIM;
        const float* cf2b = fin[12] + l * H_DIM;
        const float* lw  = fin[13] + l * H_DIM * H_DIM;
        const float* lb  = fin[14] + l * H_DIM;
        const float* aw1 = fin[15] + l * (2 * H_DIM + G_DIM) * H_DIM;
        const float* ab1 = fin[16] + l * H_DIM;
        const float* aw2 = fin[17] + l * H_DIM;
        const float* ab2 = fin[18] + l;
        const float* msw1 = fin[19] + l * S_DIM * MH_DIM;
        const float* msb1 = fin[20] + l * MH_DIM;
        const float* msw2 = fin[21] + l * MH_DIM;
        const float* msb2 = fin[22] + l;
        const float* wq  = fin[23] + l * S_DIM * S_DIM;
        const float* wk  = fin[24] + l * S_DIM * S_DIM;

        k_x<<<N_ATOMS / 4, 256, 0, stream>>>(h, cf1, xbuf, N_ATOMS);
        (void)hipMemsetAsync(aggbuf, 0, N_ATOMS * F_DIM * sizeof(float), stream);
        k_edge_s<<<E_EDGES / (4 * EPW2), 256, 0, stream>>>(esorted, posf, src, dst, xbuf,
                                                           mw1, mb1, mw2, mb2, aggbuf);
        k_update<<<N_ATOMS / 4, 256, 0, stream>>>(aggbuf, h, cf2w, cf2b, lw, lb, h_loc, N_ATOMS);
        k_scores<<<N_ATOMS / 256, 256, 0, stream>>>(h_loc, msw1, msb1, msw2, msb2, scores);
        k_rank<<<N_ATOMS / 256, 256, 0, stream>>>(scores, rankb);
        k_select<<<1, 1024, 0, stream>>>(scores, rankb, is_m, invg, midx, mbuf);
        k_gather<<<(K_TOP * H_DIM) / 256, 256, 0, stream>>>(midx, h_loc, posf, h_m, pos_m);
        k_x<<<K_TOP / 4, 256, 0, stream>>>(h_m, cf1, xm, K_TOP);
        (void)hipMemsetAsync(adj, 0, K_TOP * K_TOP, stream);
        (void)hipMemsetAsync(counters, 0, 2 * sizeof(int), stream);
        k_adj<<<E_EDGES / 256, 256, 0, stream>>>(src, dst, is_m, invg, adj, velist, counters + 1);
        k_qk<<<(K_TOP * 32) / 256, 256, 0, stream>>>(h_m, wq, wk, qm, km);
        k_attn<<<K_TOP, 256, 0, stream>>>(qm, km, adj, Av);
        k_pcount<<<(K_TOP * K_TOP) / 256, 256, 0, stream>>>(Av, bcount);
        k_pscan<<<1, 1024, 0, stream>>>(bcount, boffset, counters);
        k_pscatter<<<(K_TOP * K_TOP) / 256, 256, 0, stream>>>(Av, boffset, plist);
        k_dmat<<<(K_TOP * K_TOP) / 256, 256, 0, stream>>>(pos_m, dmat);
        k_hij<<<(2 * K_TOP) / 4, 256, 0, stream>>>(h_m, aw1, hi, hj);
        k_score_p<<<1024, 256, 0, stream>>>(plist, counters, hi, hj, aw1, ab1, aw2, ab2, dmat, sbuf);
        k_decay<<<K_TOP, 256, 0, stream>>>(sbuf, Av, decay);
        (void)hipMemsetAsync(agg_m, 0, K_TOP * F_DIM * sizeof(float), stream);
        k_aggd_p2<<<1024, 256, 0, stream>>>(plist, counters, xm, dmat, decay, mw1, mb1, mw2, mb2, agg_m);
        k_aggs_p<<<256, 256, 0, stream>>>(velist, counters + 1, pos_m, src, dst, invg, xm,
                                          mw1, mb1, mw2, mb2, agg_m);
        k_update<<<K_TOP / 4, 256, 0, stream>>>(agg_m, h_m, cf2w, cf2b, lw, lb, h_hier, K_TOP);
        k_blend<<<(N_ATOMS * H_DIM) / 256, 256, 0, stream>>>(h_loc, h_hier, is_m, invg, mbuf, h);
    }

    (void)hipMemsetAsync(pooled, 0, B_BATCH * H_DIM * sizeof(float), stream);
    k_pool<<<N_ATOMS / 64, 256, 0, stream>>>(h, batch, pooled);
    k_pred2<<<B_BATCH, 128, 0, stream>>>(pooled, fin[25], fin[26], fin[27], fin[28], d_out, dflag);
}

// Round 13
// 746.859 us; speedup vs baseline: 2.1622x; 2.1622x over previous
//
#include <hip/hip_runtime.h>
#include <hip/hip_bf16.h>
#include <math.h>

#define N_ATOMS 2048
#define E_EDGES 65536
#define B_BATCH 8
#define H_DIM 128
#define G_DIM 50
#define F_DIM 64
#define S_DIM 16
#define MH_DIM 32
#define K_TOP 512
#define L_LAYERS 2
#define EPW2 16
#define PCHUNK 32
#define GPAD 52

static constexpr float STEP   = 10.0f / 49.0f;
static constexpr float COEFF  = -12.005f;
static constexpr float PI10   = 0.31415926535897931f;
static constexpr float LN2    = 0.69314718055994531f;
static constexpr float LAMBDA = 0.002f;

#define DEV static __device__ __forceinline__

DEV float ssp_f(float x) { return fmaxf(x, 0.f) + log1pf(expf(-fabsf(x))) - LN2; }
DEV float ccut_f(float d) { return 0.5f * (cosf(d * PI10) + 1.f); }
DEV float sigm_f(float x) { return 1.f / (1.f + expf(-x)); }

// ---------------- dtype detect ----------------
__global__ __launch_bounds__(256) void k_detect(const unsigned short* raw, int n, int* flag) {
    __shared__ int any;
    if (threadIdx.x == 0) any = 0;
    __syncthreads();
    for (int i = threadIdx.x; i < n; i += 256) {
        unsigned int bits = ((unsigned int)raw[i]) << 16;
        float f = __uint_as_float(bits);
        if (!(fabsf(f) <= 1e10f)) any = 1;
    }
    __syncthreads();
    if (threadIdx.x == 0) flag[0] = any;
}

// ---------------- fused convert ----------------
struct ConvArgs {
    const void* p[25];
    int off[26];
};

__global__ __launch_bounds__(256) void k_convert_all(ConvArgs a, float* dst, const int* flag) {
    int i = blockIdx.x * 256 + threadIdx.x;
    int total = a.off[25];
    if (i >= total) return;
    int seg = 0;
    while (i >= a.off[seg + 1]) seg++;
    int k = i - a.off[seg];
    if (flag[0]) {
        dst[i] = ((const float*)a.p[seg])[k];
    } else {
        unsigned int bits = ((unsigned int)((const unsigned short*)a.p[seg])[k]) << 16;
        dst[i] = __uint_as_float(bits);
    }
}

// ---------------- edge counting-sort by dst ----------------
__global__ __launch_bounds__(256) void k_ehist(const int* dst, int* hist) {
    int e = blockIdx.x * 256 + threadIdx.x;
    atomicAdd(&hist[dst[e]], 1);
}

__global__ __launch_bounds__(1024) void k_escan(const int* hist, int* ebase, int* ecur) {
    __shared__ int bufA[N_ATOMS], bufB[N_ATOMS];
    int t = threadIdx.x;
    for (int i = t; i < N_ATOMS; i += 1024) bufA[i] = hist[i];
    __syncthreads();
    int* in = bufA;
    int* out = bufB;
    for (int d = 1; d < N_ATOMS; d <<= 1) {
        for (int i = t; i < N_ATOMS; i += 1024) out[i] = in[i] + (i >= d ? in[i - d] : 0);
        __syncthreads();
        int* tmp = in; in = out; out = tmp;
    }
    for (int i = t; i < N_ATOMS; i += 1024) {
        int ex = in[i] - hist[i];
        ebase[i] = ex;
        ecur[i] = ex;
    }
}

__global__ __launch_bounds__(256) void k_escatter(const int* dst, int* ecur, int* esorted) {
    int e = blockIdx.x * 256 + threadIdx.x;
    int pos = atomicAdd(&ecur[dst[e]], 1);
    esorted[pos] = e;
}

// ---------------- one-time packed edge data {src, dst, dist} ----------------
__global__ __launch_bounds__(256) void k_edat(const int* esorted, const int* src, const int* dst,
                                              const float* pos, int4* edat) {
    int p = blockIdx.x * 256 + threadIdx.x;
    int e = esorted[p];
    int s = src[e], d = dst[e];
    float dx = pos[s * 3 + 0] - pos[d * 3 + 0];
    float dy = pos[s * 3 + 1] - pos[d * 3 + 1];
    float dz = pos[s * 3 + 2] - pos[d * 3 + 2];
    float dist = sqrtf(dx * dx + dy * dy + dz * dz + 1e-12f);
    edat[p] = make_int4(s, d, __float_as_int(dist), 0);
}

// ---------------- embedding ----------------
__global__ __launch_bounds__(256) void k_embed(const int* atoms, const float* emb, float* h) {
    int i = blockIdx.x * 256 + threadIdx.x;
    int n = i >> 7, c = i & 127;
    h[i] = emb[atoms[n] * H_DIM + c];
}

// ---------------- x = h @ cf1 ----------------
__global__ __launch_bounds__(256) void k_x(const float* __restrict__ h, const float* __restrict__ cf1,
                                           float* __restrict__ x, int M) {
    int wave = threadIdx.x >> 6, lane = threadIdx.x & 63;
    int n = blockIdx.x * 4 + wave;
    if (n >= M) return;
    float acc = 0.f;
    for (int k = 0; k < H_DIM; k++) acc += h[n * H_DIM + k] * cf1[k * F_DIM + lane];
    x[n * F_DIM + lane] = acc;
}

// ---------------- edge filter over packed edat, b128 broadcasts ----------------
__global__ __launch_bounds__(256) void k_edge_s(const int4* edat, const float* x,
                                                const float* mw1, const float* mb1,
                                                const float* mw2, const float* mb2,
                                                float* agg) {
    __shared__ float gbuf[4][GPAD], tbuf[4][F_DIM];
    int t = threadIdx.x, wave = t >> 6, lane = t & 63;
    float w1r[GPAD], w2r[F_DIM];
    #pragma unroll
    for (int g = 0; g < G_DIM; g++) w1r[g] = mw1[g * F_DIM + lane];
    w1r[50] = 0.f; w1r[51] = 0.f;
    #pragma unroll
    for (int k = 0; k < F_DIM; k++) w2r[k] = mw2[k * F_DIM + lane];
    float b1 = mb1[lane], b2v = mb2[lane];
    if (lane >= G_DIM && lane < GPAD) gbuf[wave][lane] = 0.f;
    int p0 = (blockIdx.x * 4 + wave) * EPW2;
    int curDst = -1;
    float acc = 0.f;
    for (int ee = 0; ee < EPW2; ee++) {
        int4 ed = edat[p0 + ee];
        int sI = ed.x, dI = ed.y;
        float d = __int_as_float(ed.z);
        if (lane < G_DIM) { float u = d - lane * STEP; gbuf[wave][lane] = expf(COEFF * u * u); }
        float tv = b1;
        const float4* g4 = (const float4*)gbuf[wave];
        #pragma unroll
        for (int gg = 0; gg < 13; gg++) {
            float4 gv = g4[gg];
            tv += gv.x * w1r[4 * gg + 0];
            tv += gv.y * w1r[4 * gg + 1];
            tv += gv.z * w1r[4 * gg + 2];
            tv += gv.w * w1r[4 * gg + 3];
        }
        tv = ssp_f(tv);
        tbuf[wave][lane] = tv;
        float w = b2v;
        const float4* t4v = (const float4*)tbuf[wave];
        #pragma unroll
        for (int kk = 0; kk < 16; kk++) {
            float4 tq = t4v[kk];
            w += tq.x * w2r[4 * kk + 0];
            w += tq.y * w2r[4 * kk + 1];
            w += tq.z * w2r[4 * kk + 2];
            w += tq.w * w2r[4 * kk + 3];
        }
        w *= ccut_f(d);
        float contrib = x[sI * F_DIM + lane] * w;
        if (dI != curDst) {
            if (curDst >= 0) atomicAdd(&agg[curDst * F_DIM + lane], acc);
            acc = 0.f;
            curDst = dI;
        }
        acc += contrib;
    }
    if (curDst >= 0) atomicAdd(&agg[curDst * F_DIM + lane], acc);
}

// ---------------- out = base + ssp(agg@cf2w + cf2b) @ lw + lb ----------------
__global__ __launch_bounds__(256) void k_update(const float* __restrict__ agg, const float* __restrict__ base,
                                                const float* cf2w, const float* cf2b,
                                                const float* lw, const float* lb,
                                                float* out, int M) {
    __shared__ float tbuf[4][H_DIM];
    int wave = threadIdx.x >> 6, lane = threadIdx.x & 63;
    int n = blockIdx.x * 4 + wave;
    float t0 = cf2b[lane], t1 = cf2b[lane + 64];
    if (n < M) {
        for (int f = 0; f < F_DIM; f++) {
            float a = agg[n * F_DIM + f];
            t0 += a * cf2w[f * H_DIM + lane];
            t1 += a * cf2w[f * H_DIM + lane + 64];
        }
    }
    tbuf[wave][lane] = ssp_f(t0);
    tbuf[wave][lane + 64] = ssp_f(t1);
    __syncthreads();
    if (n < M) {
        float o0 = lb[lane], o1 = lb[lane + 64];
        const float4* t4v = (const float4*)tbuf[wave];
        #pragma unroll
        for (int kk = 0; kk < 32; kk++) {
            float4 tq = t4v[kk];
            int k4 = kk * 4;
            o0 += tq.x * lw[(k4 + 0) * H_DIM + lane];
            o1 += tq.x * lw[(k4 + 0) * H_DIM + lane + 64];
            o0 += tq.y * lw[(k4 + 1) * H_DIM + lane];
            o1 += tq.y * lw[(k4 + 1) * H_DIM + lane + 64];
            o0 += tq.z * lw[(k4 + 2) * H_DIM + lane];
            o1 += tq.z * lw[(k4 + 2) * H_DIM + lane + 64];
            o0 += tq.w * lw[(k4 + 3) * H_DIM + lane];
            o1 += tq.w * lw[(k4 + 3) * H_DIM + lane + 64];
        }
        out[n * H_DIM + lane]      = base[n * H_DIM + lane] + o0;
        out[n * H_DIM + lane + 64] = base[n * H_DIM + lane + 64] + o1;
    }
}

// ---------------- node scores ----------------
__global__ __launch_bounds__(256) void k_scores(const float* h_local,
                                                const float* msw1, const float* msb1,
                                                const float* msw2, const float* msb2,
                                                float* scores) {
    int n = blockIdx.x * 256 + threadIdx.x;
    if (n >= N_ATOMS) return;
    float hs[S_DIM];
    for (int s = 0; s < S_DIM; s++) hs[s] = h_local[n * H_DIM + s];
    float sc = msb2[0];
    for (int j = 0; j < MH_DIM; j++) {
        float v = msb1[j];
        for (int s = 0; s < S_DIM; s++) v += hs[s] * msw1[s * MH_DIM + j];
        sc += fmaxf(v, 0.f) * msw2[j];
    }
    scores[n] = sc;
}

// ---------------- exact rank ----------------
__global__ __launch_bounds__(256) void k_rank(const float* scores, int* rank) {
    __shared__ float s[N_ATOMS];
    for (int i = threadIdx.x; i < N_ATOMS; i += 256) s[i] = scores[i];
    __syncthreads();
    int i = blockIdx.x * 256 + threadIdx.x;
    float si = s[i];
    int r = 0;
    for (int j = 0; j < N_ATOMS; j++) {
        float sj = s[j];
        r += (sj > si) || (sj == si && j < i);
    }
    rank[i] = r;
}

// ---------------- selection, prefix, midx, m ----------------
__global__ __launch_bounds__(1024) void k_select(const float* scores, const int* rank,
                                                 int* is_m, int* invg, int* midx, float* m) {
    __shared__ int flag[N_ATOMS];
    __shared__ int bufA[N_ATOMS], bufB[N_ATOMS];
    __shared__ float kth;
    int t = threadIdx.x;
    for (int i = t; i < N_ATOMS; i += 1024) {
        int f = rank[i] < K_TOP;
        flag[i] = f;
        bufA[i] = f;
        if (rank[i] == K_TOP - 1) kth = scores[i];
    }
    __syncthreads();
    int* in = bufA;
    int* out = bufB;
    for (int d = 1; d < N_ATOMS; d <<= 1) {
        for (int i = t; i < N_ATOMS; i += 1024) out[i] = in[i] + (i >= d ? in[i - d] : 0);
        __syncthreads();
        int* tmp = in; in = out; out = tmp;
    }
    float kv = kth;
    for (int i = t; i < N_ATOMS; i += 1024) {
        int f = flag[i];
        int pos = in[i] - f;
        is_m[i] = f;
        invg[i] = f ? pos : 0;
        if (f) midx[pos] = i;
        m[i] = sigm_f(scores[i] - kv + 1e-6f);
    }
}

// ---------------- gather h_m / pos_m ----------------
__global__ __launch_bounds__(256) void k_gather(const int* midx, const float* h_local,
                                                const float* pos, float* h_m, float* pos_m) {
    int i = blockIdx.x * 256 + threadIdx.x;
    int k = i >> 7, c = i & 127;
    int n = midx[k];
    h_m[i] = h_local[n * H_DIM + c];
    if (c < 3) pos_m[k * 3 + c] = pos[n * 3 + c];
}

// ---------------- adjacency + valid-edge list ----------------
__global__ __launch_bounds__(256) void k_adj(const int* src, const int* dst, const int* is_m,
                                             const int* invg, unsigned char* adj,
                                             int* velist, int* nve) {
    int e = blockIdx.x * 256 + threadIdx.x;
    int s = src[e], d = dst[e];
    bool valid = is_m[s] && is_m[d];
    if (valid) adj[invg[s] * K_TOP + invg[d]] = 1;
    unsigned long long mask = __ballot(valid);
    int lane = threadIdx.x & 63;
    int cnt = __popcll(mask);
    int base = 0;
    if (lane == 0 && cnt) base = atomicAdd(nve, cnt);
    base = __shfl(base, 0);
    if (valid) velist[base + __popcll(mask & ((1ull << lane) - 1))] = e;
}

// ---------------- per-valid-edge packed data {sm, dm, dist} ----------------
__global__ __launch_bounds__(256) void k_vdat(const int* velist, const int* nve,
                                              const int* src, const int* dst, const int* invg,
                                              const float* pos_m, int4* vdat) {
    int n = nve[0];
    for (int p = blockIdx.x * 256 + threadIdx.x; p < n; p += gridDim.x * 256) {
        int e = velist[p];
        int sm = invg[src[e]];
        int dm = invg[dst[e]];
        float dx = pos_m[sm * 3 + 0] - pos_m[dm * 3 + 0];
        float dy = pos_m[sm * 3 + 1] - pos_m[dm * 3 + 1];
        float dz = pos_m[sm * 3 + 2] - pos_m[dm * 3 + 2];
        float dist = sqrtf(dx * dx + dy * dy + dz * dz + 1e-12f);
        vdat[p] = make_int4(sm, dm, __float_as_int(dist), 0);
    }
}

// ---------------- q/k projections ----------------
__global__ __launch_bounds__(256) void k_qk(const float* h_m, const float* wq,
                                            const float* wk, float* qm, float* km) {
    int gid = blockIdx.x * 256 + threadIdx.x;
    int r = gid >> 5, t = gid & 31;
    const float* w = (t < 16) ? wq : wk;
    int c = t & 15;
    float acc = 0.f;
    for (int s = 0; s < S_DIM; s++) acc += h_m[r * H_DIM + s] * w[s * S_DIM + c];
    if (t < 16) qm[r * S_DIM + c] = acc; else km[r * S_DIM + c] = acc;
}

// ---------------- attention softmax -> Av mask ----------------
__global__ __launch_bounds__(256) void k_attn(const float* qm, const float* km,
                                              const unsigned char* adj, unsigned char* Av) {
    __shared__ float lrow[K_TOP];
    __shared__ float red[256];
    int i = blockIdx.x, t = threadIdx.x;
    float q[S_DIM];
    for (int s = 0; s < S_DIM; s++) q[s] = qm[i * S_DIM + s];
    for (int j = t; j < K_TOP; j += 256) {
        float acc = 0.f;
        for (int s = 0; s < S_DIM; s++) acc += q[s] * km[j * S_DIM + s];
        lrow[j] = acc * 0.25f;
    }
    __syncthreads();
    float mx = -1e30f;
    for (int j = t; j < K_TOP; j += 256) mx = fmaxf(mx, lrow[j]);
    red[t] = mx; __syncthreads();
    for (int o = 128; o > 0; o >>= 1) { if (t < o) red[t] = fmaxf(red[t], red[t + o]); __syncthreads(); }
    mx = red[0]; __syncthreads();
    float sum = 0.f;
    for (int j = t; j < K_TOP; j += 256) sum += expf(lrow[j] - mx);
    red[t] = sum; __syncthreads();
    for (int o = 128; o > 0; o >>= 1) { if (t < o) red[t] += red[t + o]; __syncthreads(); }
    float inv_s = 1.f / red[0];
    for (int j = t; j < K_TOP; j += 256) {
        float a = expf(lrow[j] - mx) * inv_s;
        Av[i * K_TOP + j] = (a > LAMBDA) && (!adj[i * K_TOP + j]) && (i != j);
    }
}

// ---------------- deterministic j-major pair compaction ----------------
__global__ __launch_bounds__(256) void k_pcount(const unsigned char* Av, int* bcount) {
    __shared__ int wsum[4];
    int idx = blockIdx.x * 256 + threadIdx.x;
    int j = idx >> 9, i = idx & (K_TOP - 1);
    bool act = Av[i * K_TOP + j] != 0;
    unsigned long long mask = __ballot(act);
    int lane = threadIdx.x & 63, wave = threadIdx.x >> 6;
    if (lane == 0) wsum[wave] = __popcll(mask);
    __syncthreads();
    if (threadIdx.x == 0) bcount[blockIdx.x] = wsum[0] + wsum[1] + wsum[2] + wsum[3];
}

__global__ __launch_bounds__(1024) void k_pscan(const int* bcount, int* boffset, int* total) {
    __shared__ int bufA[1024], bufB[1024];
    int t = threadIdx.x;
    bufA[t] = bcount[t];
    __syncthreads();
    int* in = bufA;
    int* out = bufB;
    for (int d = 1; d < 1024; d <<= 1) {
        out[t] = in[t] + (t >= d ? in[t - d] : 0);
        __syncthreads();
        int* tmp = in; in = out; out = tmp;
    }
    boffset[t] = in[t] - bcount[t];
    if (t == 1023) total[0] = in[1023];
}

__global__ __launch_bounds__(256) void k_pscatter(const unsigned char* Av, const int* boffset,
                                                  unsigned int* plist) {
    __shared__ int wsum[4], woff[4];
    int idx = blockIdx.x * 256 + threadIdx.x;
    int j = idx >> 9, i = idx & (K_TOP - 1);
    bool act = Av[i * K_TOP + j] != 0;
    unsigned long long mask = __ballot(act);
    int lane = threadIdx.x & 63, wave = threadIdx.x >> 6;
    if (lane == 0) wsum[wave] = __popcll(mask);
    __syncthreads();
    if (threadIdx.x == 0) {
        int s = 0;
        for (int w = 0; w < 4; w++) { woff[w] = s; s += wsum[w]; }
    }
    __syncthreads();
    if (act) {
        int pos = boffset[blockIdx.x] + woff[wave] + __popcll(mask & ((1ull << lane) - 1));
        plist[pos] = ((unsigned int)j << 9) | (unsigned int)i;
    }
}

// ---------------- pairwise distances ----------------
__global__ __launch_bounds__(256) void k_dmat(const float* pos_m, float* dmat) {
    int idx = blockIdx.x * 256 + threadIdx.x;
    int i = idx >> 9, j = idx & (K_TOP - 1);
    float dx = pos_m[i * 3 + 0] - pos_m[j * 3 + 0];
    float dy = pos_m[i * 3 + 1] - pos_m[j * 3 + 1];
    float dz = pos_m[i * 3 + 2] - pos_m[j * 3 + 2];
    dmat[idx] = sqrtf(dx * dx + dy * dy + dz * dz + 1e-12f);
}

// ---------------- packed pair data for score: {key, dd} ----------------
__global__ __launch_bounds__(256) void k_sdata(const unsigned int* plist, const int* npairs,
                                               const float* dmat, float2* sd) {
    int n = npairs[0];
    for (int p = blockIdx.x * 256 + threadIdx.x; p < n; p += gridDim.x * 256) {
        unsigned int key = plist[p];
        int j = key >> 9, i = key & (K_TOP - 1);
        sd[p] = make_float2(__uint_as_float(key), dmat[i * K_TOP + j]);
    }
}

// ---------------- packed pair data for aggd: {key, dd, dec} ----------------
__global__ __launch_bounds__(256) void k_pdat(const unsigned int* plist, const int* npairs,
                                              const float* dmat, const float* decay, float4* pd) {
    int n = npairs[0];
    for (int p = blockIdx.x * 256 + threadIdx.x; p < n; p += gridDim.x * 256) {
        unsigned int key = plist[p];
        int j = key >> 9, i = key & (K_TOP - 1);
        int ij = i * K_TOP + j;
        pd[p] = make_float4(__uint_as_float(key), dmat[ij], decay[ij], 0.f);
    }
}

// ---------------- hi = h_m@Wi, hj = h_m@Wj ----------------
__global__ __launch_bounds__(256) void k_hij(const float* h_m, const float* aw1,
                                             float* hi, float* hj) {
    int wave = threadIdx.x >> 6, lane = threadIdx.x & 63;
    int idx = blockIdx.x * 4 + wave;
    int which = idx >> 9;
    int r = idx & (K_TOP - 1);
    const float* W = aw1 + which * H_DIM * H_DIM;
    float o0 = 0.f, o1 = 0.f;
    for (int k = 0; k < H_DIM; k++) {
        float hv = h_m[r * H_DIM + k];
        o0 += hv * W[k * H_DIM + lane];
        o1 += hv * W[k * H_DIM + lane + 64];
    }
    float* out = which ? hj : hi;
    out[r * H_DIM + lane] = o0;
    out[r * H_DIM + lane + 64] = o1;
}

// ---------------- per-pair attention scores over packed sd ----------------
__global__ __launch_bounds__(256) void k_score_p(const float2* sd, const int* npairs,
                                                 const float* hi, const float* hj,
                                                 const float* aw1, const float* ab1,
                                                 const float* aw2, const float* ab2,
                                                 float* sbuf) {
    __shared__ float gbuf[4][GPAD];
    int t = threadIdx.x, wave = t >> 6, lane = t & 63;
    const float* wd = aw1 + 2 * H_DIM * H_DIM;
    float wdr0[GPAD], wdr1[GPAD];
    #pragma unroll
    for (int g = 0; g < G_DIM; g++) {
        wdr0[g] = wd[g * H_DIM + lane];
        wdr1[g] = wd[g * H_DIM + lane + 64];
    }
    wdr0[50] = 0.f; wdr0[51] = 0.f;
    wdr1[50] = 0.f; wdr1[51] = 0.f;
    float ab0 = ab1[lane], ab1v = ab1[lane + 64];
    float aw0 = aw2[lane], aw1v = aw2[lane + 64];
    float b2 = ab2[0];
    if (lane >= G_DIM && lane < GPAD) gbuf[wave][lane] = 0.f;
    int n = npairs[0];
    int wid = blockIdx.x * 4 + wave;
    int nw = gridDim.x * 4;
    for (int p = wid; p < n; p += nw) {
        float2 s2 = sd[p];
        unsigned int key = __float_as_uint(s2.x);
        float dd = s2.y;
        int j = key >> 9, i = key & (K_TOP - 1);
        int ij = i * K_TOP + j;
        if (lane < G_DIM) { float u = dd - lane * STEP; gbuf[wave][lane] = expf(COEFF * u * u); }
        float v0 = hi[i * H_DIM + lane] + hj[j * H_DIM + lane] + ab0;
        float v1 = hi[i * H_DIM + lane + 64] + hj[j * H_DIM + lane + 64] + ab1v;
        const float4* g4 = (const float4*)gbuf[wave];
        #pragma unroll
        for (int gg = 0; gg < 13; gg++) {
            float4 gv = g4[gg];
            v0 += gv.x * wdr0[4 * gg + 0]; v1 += gv.x * wdr1[4 * gg + 0];
            v0 += gv.y * wdr0[4 * gg + 1]; v1 += gv.y * wdr1[4 * gg + 1];
            v0 += gv.z * wdr0[4 * gg + 2]; v1 += gv.z * wdr1[4 * gg + 2];
            v0 += gv.w * wdr0[4 * gg + 3]; v1 += gv.w * wdr1[4 * gg + 3];
        }
        float pv = fmaxf(v0, 0.f) * aw0 + fmaxf(v1, 0.f) * aw1v;
        for (int o = 1; o < 64; o <<= 1) pv += __shfl_xor(pv, o);
        if (lane == 0) sbuf[ij] = pv + b2;
    }
}

// ---------------- row softmax (Av-guarded) -> decay ----------------
__global__ __launch_bounds__(256) void k_decay(const float* sbuf, const unsigned char* Av, float* decay) {
    __shared__ float srow[K_TOP];
    __shared__ float red[256];
    int i = blockIdx.x, t = threadIdx.x;
    for (int j = t; j < K_TOP; j += 256)
        srow[j] = Av[i * K_TOP + j] ? sbuf[i * K_TOP + j] : -1e9f;
    __syncthreads();
    float mx = -1e30f;
    for (int j = t; j < K_TOP; j += 256) mx = fmaxf(mx, srow[j]);
    red[t] = mx; __syncthreads();
    for (int o = 128; o > 0; o >>= 1) { if (t < o) red[t] = fmaxf(red[t], red[t + o]); __syncthreads(); }
    mx = red[0]; __syncthreads();
    float sum = 0.f;
    for (int j = t; j < K_TOP; j += 256) sum += (srow[j] > -5e8f) ? expf(srow[j] - mx) : 0.f;
    red[t] = sum; __syncthreads();
    for (int o = 128; o > 0; o >>= 1) { if (t < o) red[t] += red[t + o]; __syncthreads(); }
    float s_total = red[0];
    float inv_s = (s_total > 0.f) ? 1.f / s_total : 0.f;
    for (int j = t; j < K_TOP; j += 256)
        decay[i * K_TOP + j] = (srow[j] > -5e8f) ? expf(srow[j] - mx) * inv_s : 0.f;
}

// ---------------- agg_d over packed pd, run-accumulated ----------------
__global__ __launch_bounds__(256) void k_aggd_p2(const float4* pd, const int* npairs,
                                                 const float* xm,
                                                 const float* mw1, const float* mb1,
                                                 const float* mw2, const float* mb2,
                                                 float* agg_m) {
    __shared__ float gbuf[4][GPAD], tbuf[4][F_DIM];
    int t = threadIdx.x, wave = t >> 6, lane = t & 63;
    float w1r[GPAD], w2r[F_DIM];
    #pragma unroll
    for (int g = 0; g < G_DIM; g++) w1r[g] = mw1[g * F_DIM + lane];
    w1r[50] = 0.f; w1r[51] = 0.f;
    #pragma unroll
    for (int k = 0; k < F_DIM; k++) w2r[k] = mw2[k * F_DIM + lane];
    float b1 = mb1[lane], b2v = mb2[lane];
    if (lane >= G_DIM && lane < GPAD) gbuf[wave][lane] = 0.f;
    int n = npairs[0];
    int nchunks = (n + PCHUNK - 1) / PCHUNK;
    int wid = blockIdx.x * 4 + wave;
    int nw = gridDim.x * 4;
    for (int c = wid; c < nchunks; c += nw) {
        int p0 = c * PCHUNK;
        int p1 = min(p0 + PCHUNK, n);
        int curJ = -1;
        float acc = 0.f;
        for (int p = p0; p < p1; p++) {
            float4 q = pd[p];
            unsigned int key = __float_as_uint(q.x);
            float dd = q.y, dec = q.z;
            int j = key >> 9, i = key & (K_TOP - 1);
            if (lane < G_DIM) { float u = dd - lane * STEP; gbuf[wave][lane] = expf(COEFF * u * u) * dec; }
            float tv = b1;
            const float4* g4 = (const float4*)gbuf[wave];
            #pragma unroll
            for (int gg = 0; gg < 13; gg++) {
                float4 gv = g4[gg];
                tv += gv.x * w1r[4 * gg + 0];
                tv += gv.y * w1r[4 * gg + 1];
                tv += gv.z * w1r[4 * gg + 2];
                tv += gv.w * w1r[4 * gg + 3];
            }
            tv = ssp_f(tv);
            tbuf[wave][lane] = tv;
            float w = b2v;
            const float4* t4v = (const float4*)tbuf[wave];
            #pragma unroll
            for (int kk = 0; kk < 16; kk++) {
                float4 tq = t4v[kk];
                w += tq.x * w2r[4 * kk + 0];
                w += tq.y * w2r[4 * kk + 1];
                w += tq.z * w2r[4 * kk + 2];
                w += tq.w * w2r[4 * kk + 3];
            }
            float contrib = xm[i * F_DIM + lane] * w * ccut_f(dd);
            if (j != curJ) {
                if (curJ >= 0) atomicAdd(&agg_m[curJ * F_DIM + lane], acc);
                acc = 0.f;
                curJ = j;
            }
            acc += contrib;
        }
        if (curJ >= 0) atomicAdd(&agg_m[curJ * F_DIM + lane], acc);
    }
}

// ---------------- valid-edge filter over packed vdat ----------------
__global__ __launch_bounds__(256) void k_aggs_p(const int4* vdat, const int* nve,
                                                const float* xm,
                                                const float* mw1, const float* mb1,
                                                const float* mw2, const float* mb2,
                                                float* agg_m) {
    __shared__ float gbuf[4][GPAD], tbuf[4][F_DIM];
    int t = threadIdx.x, wave = t >> 6, lane = t & 63;
    float w1r[GPAD], w2r[F_DIM];
    #pragma unroll
    for (int g = 0; g < G_DIM; g++) w1r[g] = mw1[g * F_DIM + lane];
    w1r[50] = 0.f; w1r[51] = 0.f;
    #pragma unroll
    for (int k = 0; k < F_DIM; k++) w2r[k] = mw2[k * F_DIM + lane];
    float b1 = mb1[lane], b2v = mb2[lane];
    if (lane >= G_DIM && lane < GPAD) gbuf[wave][lane] = 0.f;
    int n = nve[0];
    int wid = blockIdx.x * 4 + wave;
    int nw = gridDim.x * 4;
    for (int p = wid; p < n; p += nw) {
        int4 vd = vdat[p];
        int sm = vd.x, dm = vd.y;
        float d = __int_as_float(vd.z);
        if (lane < G_DIM) { float u = d - lane * STEP; gbuf[wave][lane] = expf(COEFF * u * u); }
        float tv = b1;
        const float4* g4 = (const float4*)gbuf[wave];
        #pragma unroll
        for (int gg = 0; gg < 13; gg++) {
            float4 gv = g4[gg];
            tv += gv.x * w1r[4 * gg + 0];
            tv += gv.y * w1r[4 * gg + 1];
            tv += gv.z * w1r[4 * gg + 2];
            tv += gv.w * w1r[4 * gg + 3];
        }
        tv = ssp_f(tv);
        tbuf[wave][lane] = tv;
        float w = b2v;
        const float4* t4v = (const float4*)tbuf[wave];
        #pragma unroll
        for (int kk = 0; kk < 16; kk++) {
            float4 tq = t4v[kk];
            w += tq.x * w2r[4 * kk + 0];
            w += tq.y * w2r[4 * kk + 1];
            w += tq.z * w2r[4 * kk + 2];
            w += tq.w * w2r[4 * kk + 3];
        }
        atomicAdd(&agg_m[dm * F_DIM + lane], xm[sm * F_DIM + lane] * w * ccut_f(d));
    }
}

// ---------------- blend ----------------
__global__ __launch_bounds__(256) void k_blend(const float* h_local, const float* h_hier,
                                               const int* is_m, const int* invg, const float* m,
                                               float* h_out) {
    int idx = blockIdx.x * 256 + threadIdx.x;
    int n = idx >> 7, c = idx & 127;
    float mm = m[n];
    float hh = is_m[n] ? h_hier[invg[n] * H_DIM + c] : 0.f;
    h_out[idx] = (1.f - mm) * h_local[idx] + mm * hh;
}

// ---------------- parallel segment-sum pooling ----------------
__global__ __launch_bounds__(256) void k_pool(const float* __restrict__ h, const int* __restrict__ batch,
                                              float* pooled) {
    int c = threadIdx.x & 127, a = threadIdx.x >> 7;
    int n0 = blockIdx.x * 64;
    float acc = 0.f;
    int cur = batch[n0 + a];
    for (int i = a; i < 64; i += 2) {
        int n = n0 + i;
        int b = batch[n];
        if (b != cur) { atomicAdd(&pooled[cur * H_DIM + c], acc); acc = 0.f; cur = b; }
        acc += h[n * H_DIM + c];
    }
    atomicAdd(&pooled[cur * H_DIM + c], acc);
}

// ---------------- predict MLP ----------------
__global__ __launch_bounds__(128) void k_pred2(const float* pooled,
                                               const float* w1, const float* b1,
                                               const float* w2, const float* b2,
                                               void* outv, const int* flag) {
    __shared__ float c64[64];
    int b = blockIdx.x, t = threadIdx.x;
    if (t < 64) {
        float v = b1[t];
        for (int k = 0; k < H_DIM; k++) v += pooled[b * H_DIM + k] * w1[k * 64 + t];
        c64[t] = v * sigm_f(v);
    }
    __syncthreads();
    if (t == 0) {
        float o = b2[0];
        for (int k = 0; k < 64; k++) o += c64[k] * w2[k];
        if (flag[0]) ((float*)outv)[b] = o;
        else ((__hip_bfloat16*)outv)[b] = __float2bfloat16(o);
    }
}

extern "C" void kernel_launch(void* const* d_in, const int* in_sizes, int n_in,
                              void* d_out, int out_size, void* d_ws, size_t ws_size,
                              hipStream_t stream) {
    (void)n_in; (void)out_size; (void)ws_size;
    const int* atoms = (const int*)d_in[0];
    const int* src = (const int*)d_in[2];
    const int* dst = (const int*)d_in[3];
    const int* batch = (const int*)d_in[4];

    float* W = (float*)d_ws;
    int* dflag = (int*)W; W += 16;
    int* counters = (int*)W; W += 16;  // [0]=npairs, [1]=nve

    static const int fidx[25] = {1,5,6,7,8,9,10,11,12,13,14,15,16,17,18,19,20,21,22,23,24,25,26,27,28};
    float* fin[29];
    ConvArgs ca;
    float* convBase = W;
    int off = 0;
    for (int q = 0; q < 25; q++) {
        int i = fidx[q];
        ca.p[q] = d_in[i];
        ca.off[q] = off;
        fin[i] = convBase + off;
        off += in_sizes[i];
    }
    ca.off[25] = off;
    W += off;

    k_detect<<<1, 256, 0, stream>>>((const unsigned short*)d_in[5], in_sizes[5], dflag);
    k_convert_all<<<(off + 255) / 256, 256, 0, stream>>>(ca, convBase, dflag);

    const float* posf = fin[1];
    const float* embf = fin[5];

    float* h      = W; W += N_ATOMS * H_DIM;
    float* h_loc  = W; W += N_ATOMS * H_DIM;
    float* xbuf   = W; W += N_ATOMS * F_DIM;
    float* aggbuf = W; W += N_ATOMS * F_DIM;
    float* scores = W; W += N_ATOMS;
    float* mbuf   = W; W += N_ATOMS;
    float* h_m    = W; W += K_TOP * H_DIM;
    float* pos_m  = W; W += K_TOP * 3;
    float* xm     = W; W += K_TOP * F_DIM;
    float* qm     = W; W += K_TOP * S_DIM;
    float* km     = W; W += K_TOP * S_DIM;
    float* dmat   = W; W += K_TOP * K_TOP;
    float* decay  = W; W += K_TOP * K_TOP;
    float* sbuf   = W; W += K_TOP * K_TOP;
    float* hi     = W; W += K_TOP * H_DIM;
    float* hj     = W; W += K_TOP * H_DIM;
    float* agg_m  = W; W += K_TOP * F_DIM;
    float* h_hier = W; W += K_TOP * H_DIM;
    float* pooled = W; W += B_BATCH * H_DIM;
    int* rankb  = (int*)W; W += N_ATOMS;
    int* is_m   = (int*)W; W += N_ATOMS;
    int* invg   = (int*)W; W += N_ATOMS;
    int* midx   = (int*)W; W += K_TOP;
    unsigned int* plist = (unsigned int*)W; W += K_TOP * K_TOP;
    int* velist = (int*)W; W += E_EDGES;
    int* esorted = (int*)W; W += E_EDGES;
    int* ehist  = (int*)W; W += N_ATOMS;
    int* ebase  = (int*)W; W += N_ATOMS;
    int* ecur   = (int*)W; W += N_ATOMS;
    int* bcount = (int*)W; W += 1024;
    int* boffset = (int*)W; W += 1024;
    int4* edat  = (int4*)W; W += E_EDGES * 4;
    int4* vdat  = (int4*)W; W += E_EDGES * 4;
    float2* sd  = (float2*)W; W += K_TOP * K_TOP * 2;
    float4* pd  = (float4*)W; W += K_TOP * K_TOP * 4;
    unsigned char* adj = (unsigned char*)W; W += (K_TOP * K_TOP) / 4;
    unsigned char* Av  = (unsigned char*)W; W += (K_TOP * K_TOP) / 4;

    // one-time: counting-sort edges by dst + packed edge data
    (void)hipMemsetAsync(ehist, 0, N_ATOMS * sizeof(int), stream);
    k_ehist<<<E_EDGES / 256, 256, 0, stream>>>(dst, ehist);
    k_escan<<<1, 1024, 0, stream>>>(ehist, ebase, ecur);
    k_escatter<<<E_EDGES / 256, 256, 0, stream>>>(dst, ecur, esorted);
    k_edat<<<E_EDGES / 256, 256, 0, stream>>>(esorted, src, dst, posf, edat);

    k_embed<<<(N_ATOMS * H_DIM) / 256, 256, 0, stream>>>(atoms, embf, h);

    for (int l = 0; l < L_LAYERS; l++) {
        const float* mw1 = fin[6]  + l * G_DIM * F_DIM;
        const float* mb1 = fin[7]  + l * F_DIM;
        const float* mw2 = fin[8]  + l * F_DIM * F_DIM;
        const float* mb2 = fin[9]  + l * F_DIM;
        const float* cf1 = fin[10] + l * H_DIM * F_DIM;
        const float* cf2w = fin[11] + l * F_DIM * H_DIM;
        const float* cf2b = fin[12] + l * H_DIM;
        const float* lw  = fin[13] + l * H_DIM * H_DIM;
        const float* lb  = fin[14] + l * H_DIM;
        const float* aw1 = fin[15] + l * (2 * H_DIM + G_DIM) * H_DIM;
        const float* ab1 = fin[16] + l * H_DIM;
        const float* aw2 = fin[17] + l * H_DIM;
        const float* ab2 = fin[18] + l;
        const float* msw1 = fin[19] + l * S_DIM * MH_DIM;
        const float* msb1 = fin[20] + l * MH_DIM;
        const float* msw2 = fin[21] + l * MH_DIM;
        const float* msb2 = fin[22] + l;
        const float* wq  = fin[23] + l * S_DIM * S_DIM;
        const float* wk  = fin[24] + l * S_DIM * S_DIM;

        k_x<<<N_ATOMS / 4, 256, 0, stream>>>(h, cf1, xbuf, N_ATOMS);
        (void)hipMemsetAsync(aggbuf, 0, N_ATOMS * F_DIM * sizeof(float), stream);
        k_edge_s<<<E_EDGES / (4 * EPW2), 256, 0, stream>>>(edat, xbuf, mw1, mb1, mw2, mb2, aggbuf);
        k_update<<<N_ATOMS / 4, 256, 0, stream>>>(aggbuf, h, cf2w, cf2b, lw, lb, h_loc, N_ATOMS);
        k_scores<<<N_ATOMS / 256, 256, 0, stream>>>(h_loc, msw1, msb1, msw2, msb2, scores);
        k_rank<<<N_ATOMS / 256, 256, 0, stream>>>(scores, rankb);
        k_select<<<1, 1024, 0, stream>>>(scores, rankb, is_m, invg, midx, mbuf);
        k_gather<<<(K_TOP * H_DIM) / 256, 256, 0, stream>>>(midx, h_loc, posf, h_m, pos_m);
        k_x<<<K_TOP / 4, 256, 0, stream>>>(h_m, cf1, xm, K_TOP);
        (void)hipMemsetAsync(adj, 0, K_TOP * K_TOP, stream);
        (void)hipMemsetAsync(counters, 0, 2 * sizeof(int), stream);
        k_adj<<<E_EDGES / 256, 256, 0, stream>>>(src, dst, is_m, invg, adj, velist, counters + 1);
        k_vdat<<<256, 256, 0, stream>>>(velist, counters + 1, src, dst, invg, pos_m, vdat);
        k_qk<<<(K_TOP * 32) / 256, 256, 0, stream>>>(h_m, wq, wk, qm, km);
        k_attn<<<K_TOP, 256, 0, stream>>>(qm, km, adj, Av);
        k_pcount<<<(K_TOP * K_TOP) / 256, 256, 0, stream>>>(Av, bcount);
        k_pscan<<<1, 1024, 0, stream>>>(bcount, boffset, counters);
        k_pscatter<<<(K_TOP * K_TOP) / 256, 256, 0, stream>>>(Av, boffset, plist);
        k_dmat<<<(K_TOP * K_TOP) / 256, 256, 0, stream>>>(pos_m, dmat);
        k_sdata<<<512, 256, 0, stream>>>(plist, counters, dmat, sd);
        k_hij<<<(2 * K_TOP) / 4, 256, 0, stream>>>(h_m, aw1, hi, hj);
        k_score_p<<<1024, 256, 0, stream>>>(sd, counters, hi, hj, aw1, ab1, aw2, ab2, sbuf);
        k_decay<<<K_TOP, 256, 0, stream>>>(sbuf, Av, decay);
        k_pdat<<<512, 256, 0, stream>>>(plist, counters, dmat, decay, pd);
        (void)hipMemsetAsync(agg_m, 0, K_TOP * F_DIM * sizeof(float), stream);
        k_aggd_p2<<<1024, 256, 0, stream>>>(pd, counters, xm, mw1, mb1, mw2, mb2, agg_m);
        k_aggs_p<<<256, 256, 0, stream>>>(vdat, counters + 1, xm, mw1, mb1, mw2, mb2, agg_m);
        k_update<<<K_TOP / 4, 256, 0, stream>>>(agg_m, h_m, cf2w, cf2b, lw, lb, h_hier, K_TOP);
        k_blend<<<(N_ATOMS * H_DIM) / 256, 256, 0, stream>>>(h_loc, h_hier, is_m, invg, mbuf, h);
    }

    (void)hipMemsetAsync(pooled, 0, B_BATCH * H_DIM * sizeof(float), stream);
    k_pool<<<N_ATOMS / 64, 256, 0, stream>>>(h, batch, pooled);
    k_pred2<<<B_BATCH, 128, 0, stream>>>(pooled, fin[25], fin[26], fin[27], fin[28], d_out, dflag);
}

// Round 14
// 683.371 us; speedup vs baseline: 2.3631x; 1.0929x over previous
//
#include <hip/hip_runtime.h>
#include <hip/hip_bf16.h>
#include <math.h>

#define N_ATOMS 2048
#define E_EDGES 65536
#define B_BATCH 8
#define H_DIM 128
#define G_DIM 50
#define F_DIM 64
#define S_DIM 16
#define MH_DIM 32
#define K_TOP 512
#define L_LAYERS 2
#define EPW2 16
#define PCHUNK 32
#define GPAD 52

static constexpr float STEP   = 10.0f / 49.0f;
static constexpr float COEFF  = -12.005f;
static constexpr float PI10   = 0.31415926535897931f;
static constexpr float LN2    = 0.69314718055994531f;
static constexpr float LAMBDA = 0.002f;

#define DEV static __device__ __forceinline__

DEV float ssp_f(float x) { return fmaxf(x, 0.f) + log1pf(expf(-fabsf(x))) - LN2; }
DEV float ccut_f(float d) { return 0.5f * (cosf(d * PI10) + 1.f); }
DEV float sigm_f(float x) { return 1.f / (1.f + expf(-x)); }

// fast-math variants for continuous filter paths only
DEV float fexp(float x) { return __expf(x); }
DEV float ssp_fast(float x) { return fmaxf(x, 0.f) + __logf(1.f + __expf(-fabsf(x))) - LN2; }
DEV float ccut_fast(float d) { return 0.5f * (__cosf(d * PI10) + 1.f); }

// ---------------- dtype detect ----------------
__global__ __launch_bounds__(256) void k_detect(const unsigned short* raw, int n, int* flag) {
    __shared__ int any;
    if (threadIdx.x == 0) any = 0;
    __syncthreads();
    for (int i = threadIdx.x; i < n; i += 256) {
        unsigned int bits = ((unsigned int)raw[i]) << 16;
        float f = __uint_as_float(bits);
        if (!(fabsf(f) <= 1e10f)) any = 1;
    }
    __syncthreads();
    if (threadIdx.x == 0) flag[0] = any;
}

// ---------------- fused convert ----------------
struct ConvArgs {
    const void* p[25];
    int off[26];
};

__global__ __launch_bounds__(256) void k_convert_all(ConvArgs a, float* dst, const int* flag) {
    int i = blockIdx.x * 256 + threadIdx.x;
    int total = a.off[25];
    if (i >= total) return;
    int seg = 0;
    while (i >= a.off[seg + 1]) seg++;
    int k = i - a.off[seg];
    if (flag[0]) {
        dst[i] = ((const float*)a.p[seg])[k];
    } else {
        unsigned int bits = ((unsigned int)((const unsigned short*)a.p[seg])[k]) << 16;
        dst[i] = __uint_as_float(bits);
    }
}

// ---------------- edge counting-sort by dst ----------------
__global__ __launch_bounds__(256) void k_ehist(const int* dst, int* hist) {
    int e = blockIdx.x * 256 + threadIdx.x;
    atomicAdd(&hist[dst[e]], 1);
}

__global__ __launch_bounds__(1024) void k_escan(const int* hist, int* ebase, int* ecur) {
    __shared__ int bufA[N_ATOMS], bufB[N_ATOMS];
    int t = threadIdx.x;
    for (int i = t; i < N_ATOMS; i += 1024) bufA[i] = hist[i];
    __syncthreads();
    int* in = bufA;
    int* out = bufB;
    for (int d = 1; d < N_ATOMS; d <<= 1) {
        for (int i = t; i < N_ATOMS; i += 1024) out[i] = in[i] + (i >= d ? in[i - d] : 0);
        __syncthreads();
        int* tmp = in; in = out; out = tmp;
    }
    for (int i = t; i < N_ATOMS; i += 1024) {
        int ex = in[i] - hist[i];
        ebase[i] = ex;
        ecur[i] = ex;
    }
}

__global__ __launch_bounds__(256) void k_escatter(const int* dst, int* ecur, int* esorted) {
    int e = blockIdx.x * 256 + threadIdx.x;
    int pos = atomicAdd(&ecur[dst[e]], 1);
    esorted[pos] = e;
}

// ---------------- one-time packed edge data {src, dst, dist} ----------------
__global__ __launch_bounds__(256) void k_edat(const int* esorted, const int* src, const int* dst,
                                              const float* pos, int4* edat) {
    int p = blockIdx.x * 256 + threadIdx.x;
    int e = esorted[p];
    int s = src[e], d = dst[e];
    float dx = pos[s * 3 + 0] - pos[d * 3 + 0];
    float dy = pos[s * 3 + 1] - pos[d * 3 + 1];
    float dz = pos[s * 3 + 2] - pos[d * 3 + 2];
    float dist = sqrtf(dx * dx + dy * dy + dz * dz + 1e-12f);
    edat[p] = make_int4(s, d, __float_as_int(dist), 0);
}

// ---------------- embedding ----------------
__global__ __launch_bounds__(256) void k_embed(const int* atoms, const float* emb, float* h) {
    int i = blockIdx.x * 256 + threadIdx.x;
    int n = i >> 7, c = i & 127;
    h[i] = emb[atoms[n] * H_DIM + c];
}

// ---------------- x = h @ cf1 ----------------
__global__ __launch_bounds__(256) void k_x(const float* __restrict__ h, const float* __restrict__ cf1,
                                           float* __restrict__ x, int M) {
    int wave = threadIdx.x >> 6, lane = threadIdx.x & 63;
    int n = blockIdx.x * 4 + wave;
    if (n >= M) return;
    float acc = 0.f;
    for (int k = 0; k < H_DIM; k++) acc += h[n * H_DIM + k] * cf1[k * F_DIM + lane];
    x[n * F_DIM + lane] = acc;
}

// ---------------- edge filter over packed edat, fast transcendentals ----------------
__global__ __launch_bounds__(256) void k_edge_s(const int4* edat, const float* x,
                                                const float* mw1, const float* mb1,
                                                const float* mw2, const float* mb2,
                                                float* agg) {
    __shared__ float gbuf[4][GPAD], tbuf[4][F_DIM];
    int t = threadIdx.x, wave = t >> 6, lane = t & 63;
    float w1r[GPAD], w2r[F_DIM];
    #pragma unroll
    for (int g = 0; g < G_DIM; g++) w1r[g] = mw1[g * F_DIM + lane];
    w1r[50] = 0.f; w1r[51] = 0.f;
    #pragma unroll
    for (int k = 0; k < F_DIM; k++) w2r[k] = mw2[k * F_DIM + lane];
    float b1 = mb1[lane], b2v = mb2[lane];
    if (lane >= G_DIM && lane < GPAD) gbuf[wave][lane] = 0.f;
    int p0 = (blockIdx.x * 4 + wave) * EPW2;
    int curDst = -1;
    float acc = 0.f;
    for (int ee = 0; ee < EPW2; ee++) {
        int4 ed = edat[p0 + ee];
        int sI = ed.x, dI = ed.y;
        float d = __int_as_float(ed.z);
        if (lane < G_DIM) { float u = d - lane * STEP; gbuf[wave][lane] = fexp(COEFF * u * u); }
        float tv = b1;
        const float4* g4 = (const float4*)gbuf[wave];
        #pragma unroll
        for (int gg = 0; gg < 13; gg++) {
            float4 gv = g4[gg];
            tv += gv.x * w1r[4 * gg + 0];
            tv += gv.y * w1r[4 * gg + 1];
            tv += gv.z * w1r[4 * gg + 2];
            tv += gv.w * w1r[4 * gg + 3];
        }
        tv = ssp_fast(tv);
        tbuf[wave][lane] = tv;
        float w = b2v;
        const float4* t4v = (const float4*)tbuf[wave];
        #pragma unroll
        for (int kk = 0; kk < 16; kk++) {
            float4 tq = t4v[kk];
            w += tq.x * w2r[4 * kk + 0];
            w += tq.y * w2r[4 * kk + 1];
            w += tq.z * w2r[4 * kk + 2];
            w += tq.w * w2r[4 * kk + 3];
        }
        w *= ccut_fast(d);
        float contrib = x[sI * F_DIM + lane] * w;
        if (dI != curDst) {
            if (curDst >= 0) atomicAdd(&agg[curDst * F_DIM + lane], acc);
            acc = 0.f;
            curDst = dI;
        }
        acc += contrib;
    }
    if (curDst >= 0) atomicAdd(&agg[curDst * F_DIM + lane], acc);
}

// ---------------- out = base + ssp(agg@cf2w + cf2b) @ lw + lb ----------------
__global__ __launch_bounds__(256) void k_update(const float* __restrict__ agg, const float* __restrict__ base,
                                                const float* cf2w, const float* cf2b,
                                                const float* lw, const float* lb,
                                                float* out, int M) {
    __shared__ float tbuf[4][H_DIM];
    int wave = threadIdx.x >> 6, lane = threadIdx.x & 63;
    int n = blockIdx.x * 4 + wave;
    float t0 = cf2b[lane], t1 = cf2b[lane + 64];
    if (n < M) {
        for (int f = 0; f < F_DIM; f++) {
            float a = agg[n * F_DIM + f];
            t0 += a * cf2w[f * H_DIM + lane];
            t1 += a * cf2w[f * H_DIM + lane + 64];
        }
    }
    tbuf[wave][lane] = ssp_f(t0);
    tbuf[wave][lane + 64] = ssp_f(t1);
    __syncthreads();
    if (n < M) {
        float o0 = lb[lane], o1 = lb[lane + 64];
        const float4* t4v = (const float4*)tbuf[wave];
        #pragma unroll
        for (int kk = 0; kk < 32; kk++) {
            float4 tq = t4v[kk];
            int k4 = kk * 4;
            o0 += tq.x * lw[(k4 + 0) * H_DIM + lane];
            o1 += tq.x * lw[(k4 + 0) * H_DIM + lane + 64];
            o0 += tq.y * lw[(k4 + 1) * H_DIM + lane];
            o1 += tq.y * lw[(k4 + 1) * H_DIM + lane + 64];
            o0 += tq.z * lw[(k4 + 2) * H_DIM + lane];
            o1 += tq.z * lw[(k4 + 2) * H_DIM + lane + 64];
            o0 += tq.w * lw[(k4 + 3) * H_DIM + lane];
            o1 += tq.w * lw[(k4 + 3) * H_DIM + lane + 64];
        }
        out[n * H_DIM + lane]      = base[n * H_DIM + lane] + o0;
        out[n * H_DIM + lane + 64] = base[n * H_DIM + lane + 64] + o1;
    }
}

// ---------------- node scores (exact: feeds top-K) ----------------
__global__ __launch_bounds__(256) void k_scores(const float* h_local,
                                                const float* msw1, const float* msb1,
                                                const float* msw2, const float* msb2,
                                                float* scores) {
    int n = blockIdx.x * 256 + threadIdx.x;
    if (n >= N_ATOMS) return;
    float hs[S_DIM];
    for (int s = 0; s < S_DIM; s++) hs[s] = h_local[n * H_DIM + s];
    float sc = msb2[0];
    for (int j = 0; j < MH_DIM; j++) {
        float v = msb1[j];
        for (int s = 0; s < S_DIM; s++) v += hs[s] * msw1[s * MH_DIM + j];
        sc += fmaxf(v, 0.f) * msw2[j];
    }
    scores[n] = sc;
}

// ---------------- exact rank ----------------
__global__ __launch_bounds__(256) void k_rank(const float* scores, int* rank) {
    __shared__ float s[N_ATOMS];
    for (int i = threadIdx.x; i < N_ATOMS; i += 256) s[i] = scores[i];
    __syncthreads();
    int i = blockIdx.x * 256 + threadIdx.x;
    float si = s[i];
    int r = 0;
    for (int j = 0; j < N_ATOMS; j++) {
        float sj = s[j];
        r += (sj > si) || (sj == si && j < i);
    }
    rank[i] = r;
}

// ---------------- selection, prefix, midx, m ----------------
__global__ __launch_bounds__(1024) void k_select(const float* scores, const int* rank,
                                                 int* is_m, int* invg, int* midx, float* m) {
    __shared__ int flag[N_ATOMS];
    __shared__ int bufA[N_ATOMS], bufB[N_ATOMS];
    __shared__ float kth;
    int t = threadIdx.x;
    for (int i = t; i < N_ATOMS; i += 1024) {
        int f = rank[i] < K_TOP;
        flag[i] = f;
        bufA[i] = f;
        if (rank[i] == K_TOP - 1) kth = scores[i];
    }
    __syncthreads();
    int* in = bufA;
    int* out = bufB;
    for (int d = 1; d < N_ATOMS; d <<= 1) {
        for (int i = t; i < N_ATOMS; i += 1024) out[i] = in[i] + (i >= d ? in[i - d] : 0);
        __syncthreads();
        int* tmp = in; in = out; out = tmp;
    }
    float kv = kth;
    for (int i = t; i < N_ATOMS; i += 1024) {
        int f = flag[i];
        int pos = in[i] - f;
        is_m[i] = f;
        invg[i] = f ? pos : 0;
        if (f) midx[pos] = i;
        m[i] = sigm_f(scores[i] - kv + 1e-6f);
    }
}

// ---------------- gather h_m / pos_m ----------------
__global__ __launch_bounds__(256) void k_gather(const int* midx, const float* h_local,
                                                const float* pos, float* h_m, float* pos_m) {
    int i = blockIdx.x * 256 + threadIdx.x;
    int k = i >> 7, c = i & 127;
    int n = midx[k];
    h_m[i] = h_local[n * H_DIM + c];
    if (c < 3) pos_m[k * 3 + c] = pos[n * 3 + c];
}

// ---------------- adjacency + valid-edge list ----------------
__global__ __launch_bounds__(256) void k_adj(const int* src, const int* dst, const int* is_m,
                                             const int* invg, unsigned char* adj,
                                             int* velist, int* nve) {
    int e = blockIdx.x * 256 + threadIdx.x;
    int s = src[e], d = dst[e];
    bool valid = is_m[s] && is_m[d];
    if (valid) adj[invg[s] * K_TOP + invg[d]] = 1;
    unsigned long long mask = __ballot(valid);
    int lane = threadIdx.x & 63;
    int cnt = __popcll(mask);
    int base = 0;
    if (lane == 0 && cnt) base = atomicAdd(nve, cnt);
    base = __shfl(base, 0);
    if (valid) velist[base + __popcll(mask & ((1ull << lane) - 1))] = e;
}

// ---------------- per-valid-edge packed data {sm, dm, dist} ----------------
__global__ __launch_bounds__(256) void k_vdat(const int* velist, const int* nve,
                                              const int* src, const int* dst, const int* invg,
                                              const float* pos_m, int4* vdat) {
    int n = nve[0];
    for (int p = blockIdx.x * 256 + threadIdx.x; p < n; p += gridDim.x * 256) {
        int e = velist[p];
        int sm = invg[src[e]];
        int dm = invg[dst[e]];
        float dx = pos_m[sm * 3 + 0] - pos_m[dm * 3 + 0];
        float dy = pos_m[sm * 3 + 1] - pos_m[dm * 3 + 1];
        float dz = pos_m[sm * 3 + 2] - pos_m[dm * 3 + 2];
        float dist = sqrtf(dx * dx + dy * dy + dz * dz + 1e-12f);
        vdat[p] = make_int4(sm, dm, __float_as_int(dist), 0);
    }
}

// ---------------- q/k projections ----------------
__global__ __launch_bounds__(256) void k_qk(const float* h_m, const float* wq,
                                            const float* wk, float* qm, float* km) {
    int gid = blockIdx.x * 256 + threadIdx.x;
    int r = gid >> 5, t = gid & 31;
    const float* w = (t < 16) ? wq : wk;
    int c = t & 15;
    float acc = 0.f;
    for (int s = 0; s < S_DIM; s++) acc += h_m[r * H_DIM + s] * w[s * S_DIM + c];
    if (t < 16) qm[r * S_DIM + c] = acc; else km[r * S_DIM + c] = acc;
}

// ---------------- attention softmax -> Av mask (exact: discrete threshold) ----------------
__global__ __launch_bounds__(256) void k_attn(const float* qm, const float* km,
                                              const unsigned char* adj, unsigned char* Av) {
    __shared__ float lrow[K_TOP];
    __shared__ float red[256];
    int i = blockIdx.x, t = threadIdx.x;
    float q[S_DIM];
    for (int s = 0; s < S_DIM; s++) q[s] = qm[i * S_DIM + s];
    for (int j = t; j < K_TOP; j += 256) {
        float acc = 0.f;
        for (int s = 0; s < S_DIM; s++) acc += q[s] * km[j * S_DIM + s];
        lrow[j] = acc * 0.25f;
    }
    __syncthreads();
    float mx = -1e30f;
    for (int j = t; j < K_TOP; j += 256) mx = fmaxf(mx, lrow[j]);
    red[t] = mx; __syncthreads();
    for (int o = 128; o > 0; o >>= 1) { if (t < o) red[t] = fmaxf(red[t], red[t + o]); __syncthreads(); }
    mx = red[0]; __syncthreads();
    float sum = 0.f;
    for (int j = t; j < K_TOP; j += 256) sum += expf(lrow[j] - mx);
    red[t] = sum; __syncthreads();
    for (int o = 128; o > 0; o >>= 1) { if (t < o) red[t] += red[t + o]; __syncthreads(); }
    float inv_s = 1.f / red[0];
    for (int j = t; j < K_TOP; j += 256) {
        float a = expf(lrow[j] - mx) * inv_s;
        Av[i * K_TOP + j] = (a > LAMBDA) && (!adj[i * K_TOP + j]) && (i != j);
    }
}

// ---------------- deterministic j-major pair compaction ----------------
__global__ __launch_bounds__(256) void k_pcount(const unsigned char* Av, int* bcount) {
    __shared__ int wsum[4];
    int idx = blockIdx.x * 256 + threadIdx.x;
    int j = idx >> 9, i = idx & (K_TOP - 1);
    bool act = Av[i * K_TOP + j] != 0;
    unsigned long long mask = __ballot(act);
    int lane = threadIdx.x & 63, wave = threadIdx.x >> 6;
    if (lane == 0) wsum[wave] = __popcll(mask);
    __syncthreads();
    if (threadIdx.x == 0) bcount[blockIdx.x] = wsum[0] + wsum[1] + wsum[2] + wsum[3];
}

__global__ __launch_bounds__(1024) void k_pscan(const int* bcount, int* boffset, int* total) {
    __shared__ int bufA[1024], bufB[1024];
    int t = threadIdx.x;
    bufA[t] = bcount[t];
    __syncthreads();
    int* in = bufA;
    int* out = bufB;
    for (int d = 1; d < 1024; d <<= 1) {
        out[t] = in[t] + (t >= d ? in[t - d] : 0);
        __syncthreads();
        int* tmp = in; in = out; out = tmp;
    }
    boffset[t] = in[t] - bcount[t];
    if (t == 1023) total[0] = in[1023];
}

__global__ __launch_bounds__(256) void k_pscatter(const unsigned char* Av, const int* boffset,
                                                  unsigned int* plist) {
    __shared__ int wsum[4], woff[4];
    int idx = blockIdx.x * 256 + threadIdx.x;
    int j = idx >> 9, i = idx & (K_TOP - 1);
    bool act = Av[i * K_TOP + j] != 0;
    unsigned long long mask = __ballot(act);
    int lane = threadIdx.x & 63, wave = threadIdx.x >> 6;
    if (lane == 0) wsum[wave] = __popcll(mask);
    __syncthreads();
    if (threadIdx.x == 0) {
        int s = 0;
        for (int w = 0; w < 4; w++) { woff[w] = s; s += wsum[w]; }
    }
    __syncthreads();
    if (act) {
        int pos = boffset[blockIdx.x] + woff[wave] + __popcll(mask & ((1ull << lane) - 1));
        plist[pos] = ((unsigned int)j << 9) | (unsigned int)i;
    }
}

// ---------------- pairwise distances ----------------
__global__ __launch_bounds__(256) void k_dmat(const float* pos_m, float* dmat) {
    int idx = blockIdx.x * 256 + threadIdx.x;
    int i = idx >> 9, j = idx & (K_TOP - 1);
    float dx = pos_m[i * 3 + 0] - pos_m[j * 3 + 0];
    float dy = pos_m[i * 3 + 1] - pos_m[j * 3 + 1];
    float dz = pos_m[i * 3 + 2] - pos_m[j * 3 + 2];
    dmat[idx] = sqrtf(dx * dx + dy * dy + dz * dz + 1e-12f);
}

// ---------------- packed pair data for score: {key, dd} ----------------
__global__ __launch_bounds__(256) void k_sdata(const unsigned int* plist, const int* npairs,
                                               const float* dmat, float2* sd) {
    int n = npairs[0];
    for (int p = blockIdx.x * 256 + threadIdx.x; p < n; p += gridDim.x * 256) {
        unsigned int key = plist[p];
        int j = key >> 9, i = key & (K_TOP - 1);
        sd[p] = make_float2(__uint_as_float(key), dmat[i * K_TOP + j]);
    }
}

// ---------------- packed pair data for aggd: {key, dd, dec} ----------------
__global__ __launch_bounds__(256) void k_pdat(const unsigned int* plist, const int* npairs,
                                              const float* dmat, const float* decay, float4* pd) {
    int n = npairs[0];
    for (int p = blockIdx.x * 256 + threadIdx.x; p < n; p += gridDim.x * 256) {
        unsigned int key = plist[p];
        int j = key >> 9, i = key & (K_TOP - 1);
        int ij = i * K_TOP + j;
        pd[p] = make_float4(__uint_as_float(key), dmat[ij], decay[ij], 0.f);
    }
}

// ---------------- hi = h_m@Wi, hj = h_m@Wj ----------------
__global__ __launch_bounds__(256) void k_hij(const float* h_m, const float* aw1,
                                             float* hi, float* hj) {
    int wave = threadIdx.x >> 6, lane = threadIdx.x & 63;
    int idx = blockIdx.x * 4 + wave;
    int which = idx >> 9;
    int r = idx & (K_TOP - 1);
    const float* W = aw1 + which * H_DIM * H_DIM;
    float o0 = 0.f, o1 = 0.f;
    for (int k = 0; k < H_DIM; k++) {
        float hv = h_m[r * H_DIM + k];
        o0 += hv * W[k * H_DIM + lane];
        o1 += hv * W[k * H_DIM + lane + 64];
    }
    float* out = which ? hj : hi;
    out[r * H_DIM + lane] = o0;
    out[r * H_DIM + lane + 64] = o1;
}

// ---------------- per-pair attention scores over packed sd, fast exp ----------------
__global__ __launch_bounds__(256) void k_score_p(const float2* sd, const int* npairs,
                                                 const float* hi, const float* hj,
                                                 const float* aw1, const float* ab1,
                                                 const float* aw2, const float* ab2,
                                                 float* sbuf) {
    __shared__ float gbuf[4][GPAD];
    int t = threadIdx.x, wave = t >> 6, lane = t & 63;
    const float* wd = aw1 + 2 * H_DIM * H_DIM;
    float wdr0[GPAD], wdr1[GPAD];
    #pragma unroll
    for (int g = 0; g < G_DIM; g++) {
        wdr0[g] = wd[g * H_DIM + lane];
        wdr1[g] = wd[g * H_DIM + lane + 64];
    }
    wdr0[50] = 0.f; wdr0[51] = 0.f;
    wdr1[50] = 0.f; wdr1[51] = 0.f;
    float ab0 = ab1[lane], ab1v = ab1[lane + 64];
    float aw0 = aw2[lane], aw1v = aw2[lane + 64];
    float b2 = ab2[0];
    if (lane >= G_DIM && lane < GPAD) gbuf[wave][lane] = 0.f;
    int n = npairs[0];
    int wid = blockIdx.x * 4 + wave;
    int nw = gridDim.x * 4;
    for (int p = wid; p < n; p += nw) {
        float2 s2 = sd[p];
        unsigned int key = __float_as_uint(s2.x);
        float dd = s2.y;
        int j = key >> 9, i = key & (K_TOP - 1);
        int ij = i * K_TOP + j;
        if (lane < G_DIM) { float u = dd - lane * STEP; gbuf[wave][lane] = fexp(COEFF * u * u); }
        float v0 = hi[i * H_DIM + lane] + hj[j * H_DIM + lane] + ab0;
        float v1 = hi[i * H_DIM + lane + 64] + hj[j * H_DIM + lane + 64] + ab1v;
        const float4* g4 = (const float4*)gbuf[wave];
        #pragma unroll
        for (int gg = 0; gg < 13; gg++) {
            float4 gv = g4[gg];
            v0 += gv.x * wdr0[4 * gg + 0]; v1 += gv.x * wdr1[4 * gg + 0];
            v0 += gv.y * wdr0[4 * gg + 1]; v1 += gv.y * wdr1[4 * gg + 1];
            v0 += gv.z * wdr0[4 * gg + 2]; v1 += gv.z * wdr1[4 * gg + 2];
            v0 += gv.w * wdr0[4 * gg + 3]; v1 += gv.w * wdr1[4 * gg + 3];
        }
        float pv = fmaxf(v0, 0.f) * aw0 + fmaxf(v1, 0.f) * aw1v;
        for (int o = 1; o < 64; o <<= 1) pv += __shfl_xor(pv, o);
        if (lane == 0) sbuf[ij] = pv + b2;
    }
}

// ---------------- row softmax (Av-guarded) -> decay (exact) ----------------
__global__ __launch_bounds__(256) void k_decay(const float* sbuf, const unsigned char* Av, float* decay) {
    __shared__ float srow[K_TOP];
    __shared__ float red[256];
    int i = blockIdx.x, t = threadIdx.x;
    for (int j = t; j < K_TOP; j += 256)
        srow[j] = Av[i * K_TOP + j] ? sbuf[i * K_TOP + j] : -1e9f;
    __syncthreads();
    float mx = -1e30f;
    for (int j = t; j < K_TOP; j += 256) mx = fmaxf(mx, srow[j]);
    red[t] = mx; __syncthreads();
    for (int o = 128; o > 0; o >>= 1) { if (t < o) red[t] = fmaxf(red[t], red[t + o]); __syncthreads(); }
    mx = red[0]; __syncthreads();
    float sum = 0.f;
    for (int j = t; j < K_TOP; j += 256) sum += (srow[j] > -5e8f) ? expf(srow[j] - mx) : 0.f;
    red[t] = sum; __syncthreads();
    for (int o = 128; o > 0; o >>= 1) { if (t < o) red[t] += red[t + o]; __syncthreads(); }
    float s_total = red[0];
    float inv_s = (s_total > 0.f) ? 1.f / s_total : 0.f;
    for (int j = t; j < K_TOP; j += 256)
        decay[i * K_TOP + j] = (srow[j] > -5e8f) ? expf(srow[j] - mx) * inv_s : 0.f;
}

// ---------------- agg_d over packed pd, fast transcendentals ----------------
__global__ __launch_bounds__(256) void k_aggd_p2(const float4* pd, const int* npairs,
                                                 const float* xm,
                                                 const float* mw1, const float* mb1,
                                                 const float* mw2, const float* mb2,
                                                 float* agg_m) {
    __shared__ float gbuf[4][GPAD], tbuf[4][F_DIM];
    int t = threadIdx.x, wave = t >> 6, lane = t & 63;
    float w1r[GPAD], w2r[F_DIM];
    #pragma unroll
    for (int g = 0; g < G_DIM; g++) w1r[g] = mw1[g * F_DIM + lane];
    w1r[50] = 0.f; w1r[51] = 0.f;
    #pragma unroll
    for (int k = 0; k < F_DIM; k++) w2r[k] = mw2[k * F_DIM + lane];
    float b1 = mb1[lane], b2v = mb2[lane];
    if (lane >= G_DIM && lane < GPAD) gbuf[wave][lane] = 0.f;
    int n = npairs[0];
    int nchunks = (n + PCHUNK - 1) / PCHUNK;
    int wid = blockIdx.x * 4 + wave;
    int nw = gridDim.x * 4;
    for (int c = wid; c < nchunks; c += nw) {
        int p0 = c * PCHUNK;
        int p1 = min(p0 + PCHUNK, n);
        int curJ = -1;
        float acc = 0.f;
        for (int p = p0; p < p1; p++) {
            float4 q = pd[p];
            unsigned int key = __float_as_uint(q.x);
            float dd = q.y, dec = q.z;
            int j = key >> 9, i = key & (K_TOP - 1);
            if (lane < G_DIM) { float u = dd - lane * STEP; gbuf[wave][lane] = fexp(COEFF * u * u) * dec; }
            float tv = b1;
            const float4* g4 = (const float4*)gbuf[wave];
            #pragma unroll
            for (int gg = 0; gg < 13; gg++) {
                float4 gv = g4[gg];
                tv += gv.x * w1r[4 * gg + 0];
                tv += gv.y * w1r[4 * gg + 1];
                tv += gv.z * w1r[4 * gg + 2];
                tv += gv.w * w1r[4 * gg + 3];
            }
            tv = ssp_fast(tv);
            tbuf[wave][lane] = tv;
            float w = b2v;
            const float4* t4v = (const float4*)tbuf[wave];
            #pragma unroll
            for (int kk = 0; kk < 16; kk++) {
                float4 tq = t4v[kk];
                w += tq.x * w2r[4 * kk + 0];
                w += tq.y * w2r[4 * kk + 1];
                w += tq.z * w2r[4 * kk + 2];
                w += tq.w * w2r[4 * kk + 3];
            }
            float contrib = xm[i * F_DIM + lane] * w * ccut_fast(dd);
            if (j != curJ) {
                if (curJ >= 0) atomicAdd(&agg_m[curJ * F_DIM + lane], acc);
                acc = 0.f;
                curJ = j;
            }
            acc += contrib;
        }
        if (curJ >= 0) atomicAdd(&agg_m[curJ * F_DIM + lane], acc);
    }
}

// ---------------- valid-edge filter over packed vdat, fast transcendentals ----------------
__global__ __launch_bounds__(256) void k_aggs_p(const int4* vdat, const int* nve,
                                                const float* xm,
                                                const float* mw1, const float* mb1,
                                                const float* mw2, const float* mb2,
                                                float* agg_m) {
    __shared__ float gbuf[4][GPAD], tbuf[4][F_DIM];
    int t = threadIdx.x, wave = t >> 6, lane = t & 63;
    float w1r[GPAD], w2r[F_DIM];
    #pragma unroll
    for (int g = 0; g < G_DIM; g++) w1r[g] = mw1[g * F_DIM + lane];
    w1r[50] = 0.f; w1r[51] = 0.f;
    #pragma unroll
    for (int k = 0; k < F_DIM; k++) w2r[k] = mw2[k * F_DIM + lane];
    float b1 = mb1[lane], b2v = mb2[lane];
    if (lane >= G_DIM && lane < GPAD) gbuf[wave][lane] = 0.f;
    int n = nve[0];
    int wid = blockIdx.x * 4 + wave;
    int nw = gridDim.x * 4;
    for (int p = wid; p < n; p += nw) {
        int4 vd = vdat[p];
        int sm = vd.x, dm = vd.y;
        float d = __int_as_float(vd.z);
        if (lane < G_DIM) { float u = d - lane * STEP; gbuf[wave][lane] = fexp(COEFF * u * u); }
        float tv = b1;
        const float4* g4 = (const float4*)gbuf[wave];
        #pragma unroll
        for (int gg = 0; gg < 13; gg++) {
            float4 gv = g4[gg];
            tv += gv.x * w1r[4 * gg + 0];
            tv += gv.y * w1r[4 * gg + 1];
            tv += gv.z * w1r[4 * gg + 2];
            tv += gv.w * w1r[4 * gg + 3];
        }
        tv = ssp_fast(tv);
        tbuf[wave][lane] = tv;
        float w = b2v;
        const float4* t4v = (const float4*)tbuf[wave];
        #pragma unroll
        for (int kk = 0; kk < 16; kk++) {
            float4 tq = t4v[kk];
            w += tq.x * w2r[4 * kk + 0];
            w += tq.y * w2r[4 * kk + 1];
            w += tq.z * w2r[4 * kk + 2];
            w += tq.w * w2r[4 * kk + 3];
        }
        atomicAdd(&agg_m[dm * F_DIM + lane], xm[sm * F_DIM + lane] * w * ccut_fast(d));
    }
}

// ---------------- blend ----------------
__global__ __launch_bounds__(256) void k_blend(const float* h_local, const float* h_hier,
                                               const int* is_m, const int* invg, const float* m,
                                               float* h_out) {
    int idx = blockIdx.x * 256 + threadIdx.x;
    int n = idx >> 7, c = idx & 127;
    float mm = m[n];
    float hh = is_m[n] ? h_hier[invg[n] * H_DIM + c] : 0.f;
    h_out[idx] = (1.f - mm) * h_local[idx] + mm * hh;
}

// ---------------- parallel segment-sum pooling ----------------
__global__ __launch_bounds__(256) void k_pool(const float* __restrict__ h, const int* __restrict__ batch,
                                              float* pooled) {
    int c = threadIdx.x & 127, a = threadIdx.x >> 7;
    int n0 = blockIdx.x * 64;
    float acc = 0.f;
    int cur = batch[n0 + a];
    for (int i = a; i < 64; i += 2) {
        int n = n0 + i;
        int b = batch[n];
        if (b != cur) { atomicAdd(&pooled[cur * H_DIM + c], acc); acc = 0.f; cur = b; }
        acc += h[n * H_DIM + c];
    }
    atomicAdd(&pooled[cur * H_DIM + c], acc);
}

// ---------------- predict MLP ----------------
__global__ __launch_bounds__(128) void k_pred2(const float* pooled,
                                               const float* w1, const float* b1,
                                               const float* w2, const float* b2,
                                               void* outv, const int* flag) {
    __shared__ float c64[64];
    int b = blockIdx.x, t = threadIdx.x;
    if (t < 64) {
        float v = b1[t];
        for (int k = 0; k < H_DIM; k++) v += pooled[b * H_DIM + k] * w1[k * 64 + t];
        c64[t] = v * sigm_f(v);
    }
    __syncthreads();
    if (t == 0) {
        float o = b2[0];
        for (int k = 0; k < 64; k++) o += c64[k] * w2[k];
        if (flag[0]) ((float*)outv)[b] = o;
        else ((__hip_bfloat16*)outv)[b] = __float2bfloat16(o);
    }
}

extern "C" void kernel_launch(void* const* d_in, const int* in_sizes, int n_in,
                              void* d_out, int out_size, void* d_ws, size_t ws_size,
                              hipStream_t stream) {
    (void)n_in; (void)out_size; (void)ws_size;
    const int* atoms = (const int*)d_in[0];
    const int* src = (const int*)d_in[2];
    const int* dst = (const int*)d_in[3];
    const int* batch = (const int*)d_in[4];

    float* W = (float*)d_ws;
    int* dflag = (int*)W; W += 16;
    int* counters = (int*)W; W += 16;  // [0]=npairs, [1]=nve

    static const int fidx[25] = {1,5,6,7,8,9,10,11,12,13,14,15,16,17,18,19,20,21,22,23,24,25,26,27,28};
    float* fin[29];
    ConvArgs ca;
    float* convBase = W;
    int off = 0;
    for (int q = 0; q < 25; q++) {
        int i = fidx[q];
        ca.p[q] = d_in[i];
        ca.off[q] = off;
        fin[i] = convBase + off;
        off += in_sizes[i];
    }
    ca.off[25] = off;
    W += off;

    k_detect<<<1, 256, 0, stream>>>((const unsigned short*)d_in[5], in_sizes[5], dflag);
    k_convert_all<<<(off + 255) / 256, 256, 0, stream>>>(ca, convBase, dflag);

    const float* posf = fin[1];
    const float* embf = fin[5];

    float* h      = W; W += N_ATOMS * H_DIM;
    float* h_loc  = W; W += N_ATOMS * H_DIM;
    float* xbuf   = W; W += N_ATOMS * F_DIM;
    float* aggbuf = W; W += N_ATOMS * F_DIM;
    float* scores = W; W += N_ATOMS;
    float* mbuf   = W; W += N_ATOMS;
    float* h_m    = W; W += K_TOP * H_DIM;
    float* pos_m  = W; W += K_TOP * 3;
    float* xm     = W; W += K_TOP * F_DIM;
    float* qm     = W; W += K_TOP * S_DIM;
    float* km     = W; W += K_TOP * S_DIM;
    float* dmat   = W; W += K_TOP * K_TOP;
    float* decay  = W; W += K_TOP * K_TOP;
    float* sbuf   = W; W += K_TOP * K_TOP;
    float* hi     = W; W += K_TOP * H_DIM;
    float* hj     = W; W += K_TOP * H_DIM;
    float* agg_m  = W; W += K_TOP * F_DIM;
    float* h_hier = W; W += K_TOP * H_DIM;
    float* pooled = W; W += B_BATCH * H_DIM;
    int* rankb  = (int*)W; W += N_ATOMS;
    int* is_m   = (int*)W; W += N_ATOMS;
    int* invg   = (int*)W; W += N_ATOMS;
    int* midx   = (int*)W; W += K_TOP;
    unsigned int* plist = (unsigned int*)W; W += K_TOP * K_TOP;
    int* velist = (int*)W; W += E_EDGES;
    int* esorted = (int*)W; W += E_EDGES;
    int* ehist  = (int*)W; W += N_ATOMS;
    int* ebase  = (int*)W; W += N_ATOMS;
    int* ecur   = (int*)W; W += N_ATOMS;
    int* bcount = (int*)W; W += 1024;
    int* boffset = (int*)W; W += 1024;
    int4* edat  = (int4*)W; W += E_EDGES * 4;
    int4* vdat  = (int4*)W; W += E_EDGES * 4;
    float2* sd  = (float2*)W; W += K_TOP * K_TOP * 2;
    float4* pd  = (float4*)W; W += K_TOP * K_TOP * 4;
    unsigned char* adj = (unsigned char*)W; W += (K_TOP * K_TOP) / 4;
    unsigned char* Av  = (unsigned char*)W; W += (K_TOP * K_TOP) / 4;

    // one-time: counting-sort edges by dst + packed edge data
    (void)hipMemsetAsync(ehist, 0, N_ATOMS * sizeof(int), stream);
    k_ehist<<<E_EDGES / 256, 256, 0, stream>>>(dst, ehist);
    k_escan<<<1, 1024, 0, stream>>>(ehist, ebase, ecur);
    k_escatter<<<E_EDGES / 256, 256, 0, stream>>>(dst, ecur, esorted);
    k_edat<<<E_EDGES / 256, 256, 0, stream>>>(esorted, src, dst, posf, edat);

    k_embed<<<(N_ATOMS * H_DIM) / 256, 256, 0, stream>>>(atoms, embf, h);

    for (int l = 0; l < L_LAYERS; l++) {
        const float* mw1 = fin[6]  + l * G_DIM * F_DIM;
        const float* mb1 = fin[7]  + l * F_DIM;
        const float* mw2 = fin[8]  + l * F_DIM * F_DIM;
        const float* mb2 = fin[9]  + l * F_DIM;
        const float* cf1 = fin[10] + l * H_DIM * F_DIM;
        const float* cf2w = fin[11] + l * F_DIM * H_DIM;
        const float* cf2b = fin[12] + l * H_DIM;
        const float* lw  = fin[13] + l * H_DIM * H_DIM;
        const float* lb  = fin[14] + l * H_DIM;
        const float* aw1 = fin[15] + l * (2 * H_DIM + G_DIM) * H_DIM;
        const float* ab1 = fin[16] + l * H_DIM;
        const float* aw2 = fin[17] + l * H_DIM;
        const float* ab2 = fin[18] + l;
        const float* msw1 = fin[19] + l * S_DIM * MH_DIM;
        const float* msb1 = fin[20] + l * MH_DIM;
        const float* msw2 = fin[21] + l * MH_DIM;
        const float* msb2 = fin[22] + l;
        const float* wq  = fin[23] + l * S_DIM * S_DIM;
        const float* wk  = fin[24] + l * S_DIM * S_DIM;

        k_x<<<N_ATOMS / 4, 256, 0, stream>>>(h, cf1, xbuf, N_ATOMS);
        (void)hipMemsetAsync(aggbuf, 0, N_ATOMS * F_DIM * sizeof(float), stream);
        k_edge_s<<<E_EDGES / (4 * EPW2), 256, 0, stream>>>(edat, xbuf, mw1, mb1, mw2, mb2, aggbuf);
        k_update<<<N_ATOMS / 4, 256, 0, stream>>>(aggbuf, h, cf2w, cf2b, lw, lb, h_loc, N_ATOMS);
        k_scores<<<N_ATOMS / 256, 256, 0, stream>>>(h_loc, msw1, msb1, msw2, msb2, scores);
        k_rank<<<N_ATOMS / 256, 256, 0, stream>>>(scores, rankb);
        k_select<<<1, 1024, 0, stream>>>(scores, rankb, is_m, invg, midx, mbuf);
        k_gather<<<(K_TOP * H_DIM) / 256, 256, 0, stream>>>(midx, h_loc, posf, h_m, pos_m);
        k_x<<<K_TOP / 4, 256, 0, stream>>>(h_m, cf1, xm, K_TOP);
        (void)hipMemsetAsync(adj, 0, K_TOP * K_TOP, stream);
        (void)hipMemsetAsync(counters, 0, 2 * sizeof(int), stream);
        k_adj<<<E_EDGES / 256, 256, 0, stream>>>(src, dst, is_m, invg, adj, velist, counters + 1);
        k_vdat<<<256, 256, 0, stream>>>(velist, counters + 1, src, dst, invg, pos_m, vdat);
        k_qk<<<(K_TOP * 32) / 256, 256, 0, stream>>>(h_m, wq, wk, qm, km);
        k_attn<<<K_TOP, 256, 0, stream>>>(qm, km, adj, Av);
        k_pcount<<<(K_TOP * K_TOP) / 256, 256, 0, stream>>>(Av, bcount);
        k_pscan<<<1, 1024, 0, stream>>>(bcount, boffset, counters);
        k_pscatter<<<(K_TOP * K_TOP) / 256, 256, 0, stream>>>(Av, boffset, plist);
        k_dmat<<<(K_TOP * K_TOP) / 256, 256, 0, stream>>>(pos_m, dmat);
        k_sdata<<<512, 256, 0, stream>>>(plist, counters, dmat, sd);
        k_hij<<<(2 * K_TOP) / 4, 256, 0, stream>>>(h_m, aw1, hi, hj);
        k_score_p<<<1024, 256, 0, stream>>>(sd, counters, hi, hj, aw1, ab1, aw2, ab2, sbuf);
        k_decay<<<K_TOP, 256, 0, stream>>>(sbuf, Av, decay);
        k_pdat<<<512, 256, 0, stream>>>(plist, counters, dmat, decay, pd);
        (void)hipMemsetAsync(agg_m, 0, K_TOP * F_DIM * sizeof(float), stream);
        k_aggd_p2<<<1024, 256, 0, stream>>>(pd, counters, xm, mw1, mb1, mw2, mb2, agg_m);
        k_aggs_p<<<256, 256, 0, stream>>>(vdat, counters + 1, xm, mw1, mb1, mw2, mb2, agg_m);
        k_update<<<K_TOP / 4, 256, 0, stream>>>(agg_m, h_m, cf2w, cf2b, lw, lb, h_hier, K_TOP);
        k_blend<<<(N_ATOMS * H_DIM) / 256, 256, 0, stream>>>(h_loc, h_hier, is_m, invg, mbuf, h);
    }

    (void)hipMemsetAsync(pooled, 0, B_BATCH * H_DIM * sizeof(float), stream);
    k_pool<<<N_ATOMS / 64, 256, 0, stream>>>(h, batch, pooled);
    k_pred2<<<B_BATCH, 128, 0, stream>>>(pooled, fin[25], fin[26], fin[27], fin[28], d_out, dflag);
}

// Round 15
// 579.180 us; speedup vs baseline: 2.7882x; 1.1799x over previous
//
#include <hip/hip_runtime.h>
#include <hip/hip_bf16.h>
#include <math.h>

#define N_ATOMS 2048
#define E_EDGES 65536
#define B_BATCH 8
#define H_DIM 128
#define G_DIM 50
#define F_DIM 64
#define S_DIM 16
#define MH_DIM 32
#define K_TOP 512
#define L_LAYERS 2
#define EPW2 16
#define PCHUNK 32
#define NB 4096
#define DD 0.015625f        // 64/4096
#define INV_DD 64.0f

static constexpr float STEP   = 10.0f / 49.0f;
static constexpr float COEFF  = -12.005f;
static constexpr float PI10   = 0.31415926535897931f;
static constexpr float LN2    = 0.69314718055994531f;
static constexpr float LAMBDA = 0.002f;

#define DEV static __device__ __forceinline__

DEV float ssp_f(float x) { return fmaxf(x, 0.f) + log1pf(expf(-fabsf(x))) - LN2; }
DEV float ccut_f(float d) { return 0.5f * (cosf(d * PI10) + 1.f); }
DEV float sigm_f(float x) { return 1.f / (1.f + expf(-x)); }
DEV float ssp_fast(float x) { return fmaxf(x, 0.f) + __logf(1.f + __expf(-fabsf(x))) - LN2; }
DEV float ccut_fast(float d) { return 0.5f * (__cosf(d * PI10) + 1.f); }

// ---------------- dtype detect ----------------
__global__ __launch_bounds__(256) void k_detect(const unsigned short* raw, int n, int* flag) {
    __shared__ int any;
    if (threadIdx.x == 0) any = 0;
    __syncthreads();
    for (int i = threadIdx.x; i < n; i += 256) {
        unsigned int bits = ((unsigned int)raw[i]) << 16;
        float f = __uint_as_float(bits);
        if (!(fabsf(f) <= 1e10f)) any = 1;
    }
    __syncthreads();
    if (threadIdx.x == 0) flag[0] = any;
}

// ---------------- fused convert ----------------
struct ConvArgs {
    const void* p[25];
    int off[26];
};

__global__ __launch_bounds__(256) void k_convert_all(ConvArgs a, float* dst, const int* flag) {
    int i = blockIdx.x * 256 + threadIdx.x;
    int total = a.off[25];
    if (i >= total) return;
    int seg = 0;
    while (i >= a.off[seg + 1]) seg++;
    int k = i - a.off[seg];
    if (flag[0]) {
        dst[i] = ((const float*)a.p[seg])[k];
    } else {
        unsigned int bits = ((unsigned int)((const unsigned short*)a.p[seg])[k]) << 16;
        dst[i] = __uint_as_float(bits);
    }
}

// ---------------- edge counting-sort by dst ----------------
__global__ __launch_bounds__(256) void k_ehist(const int* dst, int* hist) {
    int e = blockIdx.x * 256 + threadIdx.x;
    atomicAdd(&hist[dst[e]], 1);
}

__global__ __launch_bounds__(1024) void k_escan(const int* hist, int* ebase, int* ecur) {
    __shared__ int bufA[N_ATOMS], bufB[N_ATOMS];
    int t = threadIdx.x;
    for (int i = t; i < N_ATOMS; i += 1024) bufA[i] = hist[i];
    __syncthreads();
    int* in = bufA;
    int* out = bufB;
    for (int d = 1; d < N_ATOMS; d <<= 1) {
        for (int i = t; i < N_ATOMS; i += 1024) out[i] = in[i] + (i >= d ? in[i - d] : 0);
        __syncthreads();
        int* tmp = in; in = out; out = tmp;
    }
    for (int i = t; i < N_ATOMS; i += 1024) {
        int ex = in[i] - hist[i];
        ebase[i] = ex;
        ecur[i] = ex;
    }
}

__global__ __launch_bounds__(256) void k_escatter(const int* dst, int* ecur, int* esorted) {
    int e = blockIdx.x * 256 + threadIdx.x;
    int pos = atomicAdd(&ecur[dst[e]], 1);
    esorted[pos] = e;
}

// ---------------- one-time packed edge data {src, dst, dist} ----------------
__global__ __launch_bounds__(256) void k_edat(const int* esorted, const int* src, const int* dst,
                                              const float* pos, int4* edat) {
    int p = blockIdx.x * 256 + threadIdx.x;
    int e = esorted[p];
    int s = src[e], d = dst[e];
    float dx = pos[s * 3 + 0] - pos[d * 3 + 0];
    float dy = pos[s * 3 + 1] - pos[d * 3 + 1];
    float dz = pos[s * 3 + 2] - pos[d * 3 + 2];
    float dist = sqrtf(dx * dx + dy * dy + dz * dz + 1e-12f);
    edat[p] = make_int4(s, d, __float_as_int(dist), 0);
}

// ---------------- per-layer filter tables (exact math, 4096 bins) ----------------
// z1tab[b][f] = gauss(d_b) @ mw1     (64)
// wtab[b][f]  = full filter W(d_b) incl. ccut (64)
// ztabS[b][c] = gauss(d_b) @ Wd      (128)
__global__ __launch_bounds__(128) void k_ftab(const float* mw1, const float* mb1,
                                              const float* mw2, const float* mb2,
                                              const float* aw1,
                                              float* z1tab, float* wtab, float* ztabS) {
    __shared__ float gs[G_DIM];
    __shared__ float tb[F_DIM];
    int b = blockIdx.x, t = threadIdx.x;
    float d = b * DD;
    if (t < G_DIM) { float u = d - t * STEP; gs[t] = expf(COEFF * u * u); }
    __syncthreads();
    const float* wd = aw1 + 2 * H_DIM * H_DIM;
    float zs = 0.f;
    for (int g = 0; g < G_DIM; g++) zs += gs[g] * wd[g * H_DIM + t];
    ztabS[b * H_DIM + t] = zs;
    if (t < F_DIM) {
        float z1 = 0.f;
        for (int g = 0; g < G_DIM; g++) z1 += gs[g] * mw1[g * F_DIM + t];
        z1tab[b * F_DIM + t] = z1;
        tb[t] = ssp_f(z1 + mb1[t]);
    }
    __syncthreads();
    if (t < F_DIM) {
        float w = mb2[t];
        for (int k = 0; k < F_DIM; k++) w += tb[k] * mw2[k * F_DIM + t];
        wtab[b * F_DIM + t] = w * ccut_f(d);
    }
}

// ---------------- embedding ----------------
__global__ __launch_bounds__(256) void k_embed(const int* atoms, const float* emb, float* h) {
    int i = blockIdx.x * 256 + threadIdx.x;
    int n = i >> 7, c = i & 127;
    h[i] = emb[atoms[n] * H_DIM + c];
}

// ---------------- x = h @ cf1 ----------------
__global__ __launch_bounds__(256) void k_x(const float* __restrict__ h, const float* __restrict__ cf1,
                                           float* __restrict__ x, int M) {
    int wave = threadIdx.x >> 6, lane = threadIdx.x & 63;
    int n = blockIdx.x * 4 + wave;
    if (n >= M) return;
    float acc = 0.f;
    for (int k = 0; k < H_DIM; k++) acc += h[n * H_DIM + k] * cf1[k * F_DIM + lane];
    x[n * F_DIM + lane] = acc;
}

// ---------------- edge filter: table lookup ----------------
__global__ __launch_bounds__(256) void k_edge_s(const int4* edat, const float* x,
                                                const float* __restrict__ wtab,
                                                float* agg) {
    int t = threadIdx.x, wave = t >> 6, lane = t & 63;
    int p0 = (blockIdx.x * 4 + wave) * EPW2;
    int curDst = -1;
    float acc = 0.f;
    for (int ee = 0; ee < EPW2; ee++) {
        int4 ed = edat[p0 + ee];
        int sI = ed.x, dI = ed.y;
        float d = __int_as_float(ed.z);
        float s = d * INV_DD;
        int b0 = min((int)s, NB - 2);
        float fr = s - b0;
        float w0 = wtab[b0 * F_DIM + lane];
        float w1 = wtab[(b0 + 1) * F_DIM + lane];
        float w = w0 + fr * (w1 - w0);
        float contrib = x[sI * F_DIM + lane] * w;
        if (dI != curDst) {
            if (curDst >= 0) atomicAdd(&agg[curDst * F_DIM + lane], acc);
            acc = 0.f;
            curDst = dI;
        }
        acc += contrib;
    }
    if (curDst >= 0) atomicAdd(&agg[curDst * F_DIM + lane], acc);
}

// ---------------- out = base + ssp(agg@cf2w + cf2b) @ lw + lb ----------------
__global__ __launch_bounds__(256) void k_update(const float* __restrict__ agg, const float* __restrict__ base,
                                                const float* cf2w, const float* cf2b,
                                                const float* lw, const float* lb,
                                                float* out, int M) {
    __shared__ float tbuf[4][H_DIM];
    int wave = threadIdx.x >> 6, lane = threadIdx.x & 63;
    int n = blockIdx.x * 4 + wave;
    float t0 = cf2b[lane], t1 = cf2b[lane + 64];
    if (n < M) {
        for (int f = 0; f < F_DIM; f++) {
            float a = agg[n * F_DIM + f];
            t0 += a * cf2w[f * H_DIM + lane];
            t1 += a * cf2w[f * H_DIM + lane + 64];
        }
    }
    tbuf[wave][lane] = ssp_f(t0);
    tbuf[wave][lane + 64] = ssp_f(t1);
    __syncthreads();
    if (n < M) {
        float o0 = lb[lane], o1 = lb[lane + 64];
        const float4* t4v = (const float4*)tbuf[wave];
        #pragma unroll
        for (int kk = 0; kk < 32; kk++) {
            float4 tq = t4v[kk];
            int k4 = kk * 4;
            o0 += tq.x * lw[(k4 + 0) * H_DIM + lane];
            o1 += tq.x * lw[(k4 + 0) * H_DIM + lane + 64];
            o0 += tq.y * lw[(k4 + 1) * H_DIM + lane];
            o1 += tq.y * lw[(k4 + 1) * H_DIM + lane + 64];
            o0 += tq.z * lw[(k4 + 2) * H_DIM + lane];
            o1 += tq.z * lw[(k4 + 2) * H_DIM + lane + 64];
            o0 += tq.w * lw[(k4 + 3) * H_DIM + lane];
            o1 += tq.w * lw[(k4 + 3) * H_DIM + lane + 64];
        }
        out[n * H_DIM + lane]      = base[n * H_DIM + lane] + o0;
        out[n * H_DIM + lane + 64] = base[n * H_DIM + lane + 64] + o1;
    }
}

// ---------------- node scores (exact: feeds top-K) ----------------
__global__ __launch_bounds__(256) void k_scores(const float* h_local,
                                                const float* msw1, const float* msb1,
                                                const float* msw2, const float* msb2,
                                                float* scores) {
    int n = blockIdx.x * 256 + threadIdx.x;
    if (n >= N_ATOMS) return;
    float hs[S_DIM];
    for (int s = 0; s < S_DIM; s++) hs[s] = h_local[n * H_DIM + s];
    float sc = msb2[0];
    for (int j = 0; j < MH_DIM; j++) {
        float v = msb1[j];
        for (int s = 0; s < S_DIM; s++) v += hs[s] * msw1[s * MH_DIM + j];
        sc += fmaxf(v, 0.f) * msw2[j];
    }
    scores[n] = sc;
}

// ---------------- exact rank ----------------
__global__ __launch_bounds__(256) void k_rank(const float* scores, int* rank) {
    __shared__ float s[N_ATOMS];
    for (int i = threadIdx.x; i < N_ATOMS; i += 256) s[i] = scores[i];
    __syncthreads();
    int i = blockIdx.x * 256 + threadIdx.x;
    float si = s[i];
    int r = 0;
    for (int j = 0; j < N_ATOMS; j++) {
        float sj = s[j];
        r += (sj > si) || (sj == si && j < i);
    }
    rank[i] = r;
}

// ---------------- selection, prefix, midx, m ----------------
__global__ __launch_bounds__(1024) void k_select(const float* scores, const int* rank,
                                                 int* is_m, int* invg, int* midx, float* m) {
    __shared__ int flag[N_ATOMS];
    __shared__ int bufA[N_ATOMS], bufB[N_ATOMS];
    __shared__ float kth;
    int t = threadIdx.x;
    for (int i = t; i < N_ATOMS; i += 1024) {
        int f = rank[i] < K_TOP;
        flag[i] = f;
        bufA[i] = f;
        if (rank[i] == K_TOP - 1) kth = scores[i];
    }
    __syncthreads();
    int* in = bufA;
    int* out = bufB;
    for (int d = 1; d < N_ATOMS; d <<= 1) {
        for (int i = t; i < N_ATOMS; i += 1024) out[i] = in[i] + (i >= d ? in[i - d] : 0);
        __syncthreads();
        int* tmp = in; in = out; out = tmp;
    }
    float kv = kth;
    for (int i = t; i < N_ATOMS; i += 1024) {
        int f = flag[i];
        int pos = in[i] - f;
        is_m[i] = f;
        invg[i] = f ? pos : 0;
        if (f) midx[pos] = i;
        m[i] = sigm_f(scores[i] - kv + 1e-6f);
    }
}

// ---------------- gather h_m / pos_m ----------------
__global__ __launch_bounds__(256) void k_gather(const int* midx, const float* h_local,
                                                const float* pos, float* h_m, float* pos_m) {
    int i = blockIdx.x * 256 + threadIdx.x;
    int k = i >> 7, c = i & 127;
    int n = midx[k];
    h_m[i] = h_local[n * H_DIM + c];
    if (c < 3) pos_m[k * 3 + c] = pos[n * 3 + c];
}

// ---------------- adjacency + valid-edge list ----------------
__global__ __launch_bounds__(256) void k_adj(const int* src, const int* dst, const int* is_m,
                                             const int* invg, unsigned char* adj,
                                             int* velist, int* nve) {
    int e = blockIdx.x * 256 + threadIdx.x;
    int s = src[e], d = dst[e];
    bool valid = is_m[s] && is_m[d];
    if (valid) adj[invg[s] * K_TOP + invg[d]] = 1;
    unsigned long long mask = __ballot(valid);
    int lane = threadIdx.x & 63;
    int cnt = __popcll(mask);
    int base = 0;
    if (lane == 0 && cnt) base = atomicAdd(nve, cnt);
    base = __shfl(base, 0);
    if (valid) velist[base + __popcll(mask & ((1ull << lane) - 1))] = e;
}

// ---------------- per-valid-edge packed data {sm, dm, dist} ----------------
__global__ __launch_bounds__(256) void k_vdat(const int* velist, const int* nve,
                                              const int* src, const int* dst, const int* invg,
                                              const float* pos_m, int4* vdat) {
    int n = nve[0];
    for (int p = blockIdx.x * 256 + threadIdx.x; p < n; p += gridDim.x * 256) {
        int e = velist[p];
        int sm = invg[src[e]];
        int dm = invg[dst[e]];
        float dx = pos_m[sm * 3 + 0] - pos_m[dm * 3 + 0];
        float dy = pos_m[sm * 3 + 1] - pos_m[dm * 3 + 1];
        float dz = pos_m[sm * 3 + 2] - pos_m[dm * 3 + 2];
        float dist = sqrtf(dx * dx + dy * dy + dz * dz + 1e-12f);
        vdat[p] = make_int4(sm, dm, __float_as_int(dist), 0);
    }
}

// ---------------- q/k projections ----------------
__global__ __launch_bounds__(256) void k_qk(const float* h_m, const float* wq,
                                            const float* wk, float* qm, float* km) {
    int gid = blockIdx.x * 256 + threadIdx.x;
    int r = gid >> 5, t = gid & 31;
    const float* w = (t < 16) ? wq : wk;
    int c = t & 15;
    float acc = 0.f;
    for (int s = 0; s < S_DIM; s++) acc += h_m[r * H_DIM + s] * w[s * S_DIM + c];
    if (t < 16) qm[r * S_DIM + c] = acc; else km[r * S_DIM + c] = acc;
}

// ---------------- attention softmax -> Av mask (exact) ----------------
__global__ __launch_bounds__(256) void k_attn(const float* qm, const float* km,
                                              const unsigned char* adj, unsigned char* Av) {
    __shared__ float lrow[K_TOP];
    __shared__ float red[256];
    int i = blockIdx.x, t = threadIdx.x;
    float q[S_DIM];
    for (int s = 0; s < S_DIM; s++) q[s] = qm[i * S_DIM + s];
    for (int j = t; j < K_TOP; j += 256) {
        float acc = 0.f;
        for (int s = 0; s < S_DIM; s++) acc += q[s] * km[j * S_DIM + s];
        lrow[j] = acc * 0.25f;
    }
    __syncthreads();
    float mx = -1e30f;
    for (int j = t; j < K_TOP; j += 256) mx = fmaxf(mx, lrow[j]);
    red[t] = mx; __syncthreads();
    for (int o = 128; o > 0; o >>= 1) { if (t < o) red[t] = fmaxf(red[t], red[t + o]); __syncthreads(); }
    mx = red[0]; __syncthreads();
    float sum = 0.f;
    for (int j = t; j < K_TOP; j += 256) sum += expf(lrow[j] - mx);
    red[t] = sum; __syncthreads();
    for (int o = 128; o > 0; o >>= 1) { if (t < o) red[t] += red[t + o]; __syncthreads(); }
    float inv_s = 1.f / red[0];
    for (int j = t; j < K_TOP; j += 256) {
        float a = expf(lrow[j] - mx) * inv_s;
        Av[i * K_TOP + j] = (a > LAMBDA) && (!adj[i * K_TOP + j]) && (i != j);
    }
}

// ---------------- deterministic j-major pair compaction ----------------
__global__ __launch_bounds__(256) void k_pcount(const unsigned char* Av, int* bcount) {
    __shared__ int wsum[4];
    int idx = blockIdx.x * 256 + threadIdx.x;
    int j = idx >> 9, i = idx & (K_TOP - 1);
    bool act = Av[i * K_TOP + j] != 0;
    unsigned long long mask = __ballot(act);
    int lane = threadIdx.x & 63, wave = threadIdx.x >> 6;
    if (lane == 0) wsum[wave] = __popcll(mask);
    __syncthreads();
    if (threadIdx.x == 0) bcount[blockIdx.x] = wsum[0] + wsum[1] + wsum[2] + wsum[3];
}

__global__ __launch_bounds__(1024) void k_pscan(const int* bcount, int* boffset, int* total) {
    __shared__ int bufA[1024], bufB[1024];
    int t = threadIdx.x;
    bufA[t] = bcount[t];
    __syncthreads();
    int* in = bufA;
    int* out = bufB;
    for (int d = 1; d < 1024; d <<= 1) {
        out[t] = in[t] + (t >= d ? in[t - d] : 0);
        __syncthreads();
        int* tmp = in; in = out; out = tmp;
    }
    boffset[t] = in[t] - bcount[t];
    if (t == 1023) total[0] = in[1023];
}

__global__ __launch_bounds__(256) void k_pscatter(const unsigned char* Av, const int* boffset,
                                                  unsigned int* plist) {
    __shared__ int wsum[4], woff[4];
    int idx = blockIdx.x * 256 + threadIdx.x;
    int j = idx >> 9, i = idx & (K_TOP - 1);
    bool act = Av[i * K_TOP + j] != 0;
    unsigned long long mask = __ballot(act);
    int lane = threadIdx.x & 63, wave = threadIdx.x >> 6;
    if (lane == 0) wsum[wave] = __popcll(mask);
    __syncthreads();
    if (threadIdx.x == 0) {
        int s = 0;
        for (int w = 0; w < 4; w++) { woff[w] = s; s += wsum[w]; }
    }
    __syncthreads();
    if (act) {
        int pos = boffset[blockIdx.x] + woff[wave] + __popcll(mask & ((1ull << lane) - 1));
        plist[pos] = ((unsigned int)j << 9) | (unsigned int)i;
    }
}

// ---------------- pairwise distances ----------------
__global__ __launch_bounds__(256) void k_dmat(const float* pos_m, float* dmat) {
    int idx = blockIdx.x * 256 + threadIdx.x;
    int i = idx >> 9, j = idx & (K_TOP - 1);
    float dx = pos_m[i * 3 + 0] - pos_m[j * 3 + 0];
    float dy = pos_m[i * 3 + 1] - pos_m[j * 3 + 1];
    float dz = pos_m[i * 3 + 2] - pos_m[j * 3 + 2];
    dmat[idx] = sqrtf(dx * dx + dy * dy + dz * dz + 1e-12f);
}

// ---------------- packed pair data for score: {key, dd} ----------------
__global__ __launch_bounds__(256) void k_sdata(const unsigned int* plist, const int* npairs,
                                               const float* dmat, float2* sd) {
    int n = npairs[0];
    for (int p = blockIdx.x * 256 + threadIdx.x; p < n; p += gridDim.x * 256) {
        unsigned int key = plist[p];
        int j = key >> 9, i = key & (K_TOP - 1);
        sd[p] = make_float2(__uint_as_float(key), dmat[i * K_TOP + j]);
    }
}

// ---------------- packed pair data for aggd: {key, dd, dec} ----------------
__global__ __launch_bounds__(256) void k_pdat(const unsigned int* plist, const int* npairs,
                                              const float* dmat, const float* decay, float4* pd) {
    int n = npairs[0];
    for (int p = blockIdx.x * 256 + threadIdx.x; p < n; p += gridDim.x * 256) {
        unsigned int key = plist[p];
        int j = key >> 9, i = key & (K_TOP - 1);
        int ij = i * K_TOP + j;
        pd[p] = make_float4(__uint_as_float(key), dmat[ij], decay[ij], 0.f);
    }
}

// ---------------- hi = h_m@Wi, hj = h_m@Wj ----------------
__global__ __launch_bounds__(256) void k_hij(const float* h_m, const float* aw1,
                                             float* hi, float* hj) {
    int wave = threadIdx.x >> 6, lane = threadIdx.x & 63;
    int idx = blockIdx.x * 4 + wave;
    int which = idx >> 9;
    int r = idx & (K_TOP - 1);
    const float* W = aw1 + which * H_DIM * H_DIM;
    float o0 = 0.f, o1 = 0.f;
    for (int k = 0; k < H_DIM; k++) {
        float hv = h_m[r * H_DIM + k];
        o0 += hv * W[k * H_DIM + lane];
        o1 += hv * W[k * H_DIM + lane + 64];
    }
    float* out = which ? hj : hi;
    out[r * H_DIM + lane] = o0;
    out[r * H_DIM + lane + 64] = o1;
}

// ---------------- per-pair attention scores: ztabS lookup ----------------
__global__ __launch_bounds__(256) void k_score_p(const float2* sd, const int* npairs,
                                                 const float* hi, const float* hj,
                                                 const float* __restrict__ ztabS,
                                                 const float* ab1, const float* aw2, const float* ab2,
                                                 float* sbuf) {
    int t = threadIdx.x, wave = t >> 6, lane = t & 63;
    float ab0 = ab1[lane], ab1v = ab1[lane + 64];
    float aw0 = aw2[lane], aw1v = aw2[lane + 64];
    float b2 = ab2[0];
    int n = npairs[0];
    int wid = blockIdx.x * 4 + wave;
    int nw = gridDim.x * 4;
    for (int p = wid; p < n; p += nw) {
        float2 s2 = sd[p];
        unsigned int key = __float_as_uint(s2.x);
        float dd = s2.y;
        int j = key >> 9, i = key & (K_TOP - 1);
        int ij = i * K_TOP + j;
        float s = dd * INV_DD;
        int b0 = min((int)s, NB - 2);
        float fr = s - b0;
        const float* r0 = ztabS + b0 * H_DIM;
        const float* r1 = r0 + H_DIM;
        float z0a = r0[lane],      z1a = r1[lane];
        float z0b = r0[lane + 64], z1b = r1[lane + 64];
        float zs0 = z0a + fr * (z1a - z0a);
        float zs1 = z0b + fr * (z1b - z0b);
        float v0 = hi[i * H_DIM + lane] + hj[j * H_DIM + lane] + ab0 + zs0;
        float v1 = hi[i * H_DIM + lane + 64] + hj[j * H_DIM + lane + 64] + ab1v + zs1;
        float pv = fmaxf(v0, 0.f) * aw0 + fmaxf(v1, 0.f) * aw1v;
        for (int o = 1; o < 64; o <<= 1) pv += __shfl_xor(pv, o);
        if (lane == 0) sbuf[ij] = pv + b2;
    }
}

// ---------------- row softmax (Av-guarded) -> decay (exact) ----------------
__global__ __launch_bounds__(256) void k_decay(const float* sbuf, const unsigned char* Av, float* decay) {
    __shared__ float srow[K_TOP];
    __shared__ float red[256];
    int i = blockIdx.x, t = threadIdx.x;
    for (int j = t; j < K_TOP; j += 256)
        srow[j] = Av[i * K_TOP + j] ? sbuf[i * K_TOP + j] : -1e9f;
    __syncthreads();
    float mx = -1e30f;
    for (int j = t; j < K_TOP; j += 256) mx = fmaxf(mx, srow[j]);
    red[t] = mx; __syncthreads();
    for (int o = 128; o > 0; o >>= 1) { if (t < o) red[t] = fmaxf(red[t], red[t + o]); __syncthreads(); }
    mx = red[0]; __syncthreads();
    float sum = 0.f;
    for (int j = t; j < K_TOP; j += 256) sum += (srow[j] > -5e8f) ? expf(srow[j] - mx) : 0.f;
    red[t] = sum; __syncthreads();
    for (int o = 128; o > 0; o >>= 1) { if (t < o) red[t] += red[t + o]; __syncthreads(); }
    float s_total = red[0];
    float inv_s = (s_total > 0.f) ? 1.f / s_total : 0.f;
    for (int j = t; j < K_TOP; j += 256)
        decay[i * K_TOP + j] = (srow[j] > -5e8f) ? expf(srow[j] - mx) * inv_s : 0.f;
}

// ---------------- agg_d: z1 table + second layer ----------------
__global__ __launch_bounds__(256) void k_aggd_p2(const float4* pd, const int* npairs,
                                                 const float* xm,
                                                 const float* __restrict__ z1tab,
                                                 const float* mb1,
                                                 const float* mw2, const float* mb2,
                                                 float* agg_m) {
    __shared__ float tbuf[4][F_DIM];
    int t = threadIdx.x, wave = t >> 6, lane = t & 63;
    float w2r[F_DIM];
    #pragma unroll
    for (int k = 0; k < F_DIM; k++) w2r[k] = mw2[k * F_DIM + lane];
    float b1 = mb1[lane], b2v = mb2[lane];
    int n = npairs[0];
    int nchunks = (n + PCHUNK - 1) / PCHUNK;
    int wid = blockIdx.x * 4 + wave;
    int nw = gridDim.x * 4;
    for (int c = wid; c < nchunks; c += nw) {
        int p0 = c * PCHUNK;
        int p1 = min(p0 + PCHUNK, n);
        int curJ = -1;
        float acc = 0.f;
        for (int p = p0; p < p1; p++) {
            float4 q = pd[p];
            unsigned int key = __float_as_uint(q.x);
            float dd = q.y, dec = q.z;
            int j = key >> 9, i = key & (K_TOP - 1);
            float s = dd * INV_DD;
            int b0 = min((int)s, NB - 2);
            float fr = s - b0;
            float z0 = z1tab[b0 * F_DIM + lane];
            float z1 = z1tab[(b0 + 1) * F_DIM + lane];
            float z1v = z0 + fr * (z1 - z0);
            float tv = ssp_fast(dec * z1v + b1);
            tbuf[wave][lane] = tv;
            float w = b2v;
            const float4* t4v = (const float4*)tbuf[wave];
            #pragma unroll
            for (int kk = 0; kk < 16; kk++) {
                float4 tq = t4v[kk];
                w += tq.x * w2r[4 * kk + 0];
                w += tq.y * w2r[4 * kk + 1];
                w += tq.z * w2r[4 * kk + 2];
                w += tq.w * w2r[4 * kk + 3];
            }
            float contrib = xm[i * F_DIM + lane] * w * ccut_fast(dd);
            if (j != curJ) {
                if (curJ >= 0) atomicAdd(&agg_m[curJ * F_DIM + lane], acc);
                acc = 0.f;
                curJ = j;
            }
            acc += contrib;
        }
        if (curJ >= 0) atomicAdd(&agg_m[curJ * F_DIM + lane], acc);
    }
}

// ---------------- valid-edge filter: table lookup ----------------
__global__ __launch_bounds__(256) void k_aggs_p(const int4* vdat, const int* nve,
                                                const float* xm,
                                                const float* __restrict__ wtab,
                                                float* agg_m) {
    int t = threadIdx.x, wave = t >> 6, lane = t & 63;
    int n = nve[0];
    int wid = blockIdx.x * 4 + wave;
    int nw = gridDim.x * 4;
    for (int p = wid; p < n; p += nw) {
        int4 vd = vdat[p];
        int sm = vd.x, dm = vd.y;
        float d = __int_as_float(vd.z);
        float s = d * INV_DD;
        int b0 = min((int)s, NB - 2);
        float fr = s - b0;
        float w0 = wtab[b0 * F_DIM + lane];
        float w1 = wtab[(b0 + 1) * F_DIM + lane];
        float w = w0 + fr * (w1 - w0);
        atomicAdd(&agg_m[dm * F_DIM + lane], xm[sm * F_DIM + lane] * w);
    }
}

// ---------------- blend ----------------
__global__ __launch_bounds__(256) void k_blend(const float* h_local, const float* h_hier,
                                               const int* is_m, const int* invg, const float* m,
                                               float* h_out) {
    int idx = blockIdx.x * 256 + threadIdx.x;
    int n = idx >> 7, c = idx & 127;
    float mm = m[n];
    float hh = is_m[n] ? h_hier[invg[n] * H_DIM + c] : 0.f;
    h_out[idx] = (1.f - mm) * h_local[idx] + mm * hh;
}

// ---------------- parallel segment-sum pooling ----------------
__global__ __launch_bounds__(256) void k_pool(const float* __restrict__ h, const int* __restrict__ batch,
                                              float* pooled) {
    int c = threadIdx.x & 127, a = threadIdx.x >> 7;
    int n0 = blockIdx.x * 64;
    float acc = 0.f;
    int cur = batch[n0 + a];
    for (int i = a; i < 64; i += 2) {
        int n = n0 + i;
        int b = batch[n];
        if (b != cur) { atomicAdd(&pooled[cur * H_DIM + c], acc); acc = 0.f; cur = b; }
        acc += h[n * H_DIM + c];
    }
    atomicAdd(&pooled[cur * H_DIM + c], acc);
}

// ---------------- predict MLP ----------------
__global__ __launch_bounds__(128) void k_pred2(const float* pooled,
                                               const float* w1, const float* b1,
                                               const float* w2, const float* b2,
                                               void* outv, const int* flag) {
    __shared__ float c64[64];
    int b = blockIdx.x, t = threadIdx.x;
    if (t < 64) {
        float v = b1[t];
        for (int k = 0; k < H_DIM; k++) v += pooled[b * H_DIM + k] * w1[k * 64 + t];
        c64[t] = v * sigm_f(v);
    }
    __syncthreads();
    if (t == 0) {
        float o = b2[0];
        for (int k = 0; k < 64; k++) o += c64[k] * w2[k];
        if (flag[0]) ((float*)outv)[b] = o;
        else ((__hip_bfloat16*)outv)[b] = __float2bfloat16(o);
    }
}

extern "C" void kernel_launch(void* const* d_in, const int* in_sizes, int n_in,
                              void* d_out, int out_size, void* d_ws, size_t ws_size,
                              hipStream_t stream) {
    (void)n_in; (void)out_size; (void)ws_size;
    const int* atoms = (const int*)d_in[0];
    const int* src = (const int*)d_in[2];
    const int* dst = (const int*)d_in[3];
    const int* batch = (const int*)d_in[4];

    float* W = (float*)d_ws;
    int* dflag = (int*)W; W += 16;
    int* counters = (int*)W; W += 16;  // [0]=npairs, [1]=nve

    static const int fidx[25] = {1,5,6,7,8,9,10,11,12,13,14,15,16,17,18,19,20,21,22,23,24,25,26,27,28};
    float* fin[29];
    ConvArgs ca;
    float* convBase = W;
    int off = 0;
    for (int q = 0; q < 25; q++) {
        int i = fidx[q];
        ca.p[q] = d_in[i];
        ca.off[q] = off;
        fin[i] = convBase + off;
        off += in_sizes[i];
    }
    ca.off[25] = off;
    W += off;

    k_detect<<<1, 256, 0, stream>>>((const unsigned short*)d_in[5], in_sizes[5], dflag);
    k_convert_all<<<(off + 255) / 256, 256, 0, stream>>>(ca, convBase, dflag);

    const float* posf = fin[1];
    const float* embf = fin[5];

    float* h      = W; W += N_ATOMS * H_DIM;
    float* h_loc  = W; W += N_ATOMS * H_DIM;
    float* xbuf   = W; W += N_ATOMS * F_DIM;
    float* aggbuf = W; W += N_ATOMS * F_DIM;
    float* scores = W; W += N_ATOMS;
    float* mbuf   = W; W += N_ATOMS;
    float* h_m    = W; W += K_TOP * H_DIM;
    float* pos_m  = W; W += K_TOP * 3;
    float* xm     = W; W += K_TOP * F_DIM;
    float* qm     = W; W += K_TOP * S_DIM;
    float* km     = W; W += K_TOP * S_DIM;
    float* dmat   = W; W += K_TOP * K_TOP;
    float* decay  = W; W += K_TOP * K_TOP;
    float* sbuf   = W; W += K_TOP * K_TOP;
    float* hi     = W; W += K_TOP * H_DIM;
    float* hj     = W; W += K_TOP * H_DIM;
    float* agg_m  = W; W += K_TOP * F_DIM;
    float* h_hier = W; W += K_TOP * H_DIM;
    float* pooled = W; W += B_BATCH * H_DIM;
    float* z1tab  = W; W += NB * F_DIM;
    float* wtab   = W; W += NB * F_DIM;
    float* ztabS  = W; W += NB * H_DIM;
    int* rankb  = (int*)W; W += N_ATOMS;
    int* is_m   = (int*)W; W += N_ATOMS;
    int* invg   = (int*)W; W += N_ATOMS;
    int* midx   = (int*)W; W += K_TOP;
    unsigned int* plist = (unsigned int*)W; W += K_TOP * K_TOP;
    int* velist = (int*)W; W += E_EDGES;
    int* esorted = (int*)W; W += E_EDGES;
    int* ehist  = (int*)W; W += N_ATOMS;
    int* ebase  = (int*)W; W += N_ATOMS;
    int* ecur   = (int*)W; W += N_ATOMS;
    int* bcount = (int*)W; W += 1024;
    int* boffset = (int*)W; W += 1024;
    int4* edat  = (int4*)W; W += E_EDGES * 4;
    int4* vdat  = (int4*)W; W += E_EDGES * 4;
    float2* sd  = (float2*)W; W += K_TOP * K_TOP * 2;
    float4* pd  = (float4*)W; W += K_TOP * K_TOP * 4;
    unsigned char* adj = (unsigned char*)W; W += (K_TOP * K_TOP) / 4;
    unsigned char* Av  = (unsigned char*)W; W += (K_TOP * K_TOP) / 4;

    // one-time: counting-sort edges by dst + packed edge data
    (void)hipMemsetAsync(ehist, 0, N_ATOMS * sizeof(int), stream);
    k_ehist<<<E_EDGES / 256, 256, 0, stream>>>(dst, ehist);
    k_escan<<<1, 1024, 0, stream>>>(ehist, ebase, ecur);
    k_escatter<<<E_EDGES / 256, 256, 0, stream>>>(dst, ecur, esorted);
    k_edat<<<E_EDGES / 256, 256, 0, stream>>>(esorted, src, dst, posf, edat);

    k_embed<<<(N_ATOMS * H_DIM) / 256, 256, 0, stream>>>(atoms, embf, h);

    for (int l = 0; l < L_LAYERS; l++) {
        const float* mw1 = fin[6]  + l * G_DIM * F_DIM;
        const float* mb1 = fin[7]  + l * F_DIM;
        const float* mw2 = fin[8]  + l * F_DIM * F_DIM;
        const float* mb2 = fin[9]  + l * F_DIM;
        const float* cf1 = fin[10] + l * H_DIM * F_DIM;
        const float* cf2w = fin[11] + l * F_DIM * H_DIM;
        const float* cf2b = fin[12] + l * H_DIM;
        const float* lw  = fin[13] + l * H_DIM * H_DIM;
        const float* lb  = fin[14] + l * H_DIM;
        const float* aw1 = fin[15] + l * (2 * H_DIM + G_DIM) * H_DIM;
        const float* ab1 = fin[16] + l * H_DIM;
        const float* aw2 = fin[17] + l * H_DIM;
        const float* ab2 = fin[18] + l;
        const float* msw1 = fin[19] + l * S_DIM * MH_DIM;
        const float* msb1 = fin[20] + l * MH_DIM;
        const float* msw2 = fin[21] + l * MH_DIM;
        const float* msb2 = fin[22] + l;
        const float* wq  = fin[23] + l * S_DIM * S_DIM;
        const float* wk  = fin[24] + l * S_DIM * S_DIM;

        k_ftab<<<NB, 128, 0, stream>>>(mw1, mb1, mw2, mb2, aw1, z1tab, wtab, ztabS);
        k_x<<<N_ATOMS / 4, 256, 0, stream>>>(h, cf1, xbuf, N_ATOMS);
        (void)hipMemsetAsync(aggbuf, 0, N_ATOMS * F_DIM * sizeof(float), stream);
        k_edge_s<<<E_EDGES / (4 * EPW2), 256, 0, stream>>>(edat, xbuf, wtab, aggbuf);
        k_update<<<N_ATOMS / 4, 256, 0, stream>>>(aggbuf, h, cf2w, cf2b, lw, lb, h_loc, N_ATOMS);
        k_scores<<<N_ATOMS / 256, 256, 0, stream>>>(h_loc, msw1, msb1, msw2, msb2, scores);
        k_rank<<<N_ATOMS / 256, 256, 0, stream>>>(scores, rankb);
        k_select<<<1, 1024, 0, stream>>>(scores, rankb, is_m, invg, midx, mbuf);
        k_gather<<<(K_TOP * H_DIM) / 256, 256, 0, stream>>>(midx, h_loc, posf, h_m, pos_m);
        k_x<<<K_TOP / 4, 256, 0, stream>>>(h_m, cf1, xm, K_TOP);
        (void)hipMemsetAsync(adj, 0, K_TOP * K_TOP, stream);
        (void)hipMemsetAsync(counters, 0, 2 * sizeof(int), stream);
        k_adj<<<E_EDGES / 256, 256, 0, stream>>>(src, dst, is_m, invg, adj, velist, counters + 1);
        k_vdat<<<256, 256, 0, stream>>>(velist, counters + 1, src, dst, invg, pos_m, vdat);
        k_qk<<<(K_TOP * 32) / 256, 256, 0, stream>>>(h_m, wq, wk, qm, km);
        k_attn<<<K_TOP, 256, 0, stream>>>(qm, km, adj, Av);
        k_pcount<<<(K_TOP * K_TOP) / 256, 256, 0, stream>>>(Av, bcount);
        k_pscan<<<1, 1024, 0, stream>>>(bcount, boffset, counters);
        k_pscatter<<<(K_TOP * K_TOP) / 256, 256, 0, stream>>>(Av, boffset, plist);
        k_dmat<<<(K_TOP * K_TOP) / 256, 256, 0, stream>>>(pos_m, dmat);
        k_sdata<<<512, 256, 0, stream>>>(plist, counters, dmat, sd);
        k_hij<<<(2 * K_TOP) / 4, 256, 0, stream>>>(h_m, aw1, hi, hj);
        k_score_p<<<1024, 256, 0, stream>>>(sd, counters, hi, hj, ztabS, ab1, aw2, ab2, sbuf);
        k_decay<<<K_TOP, 256, 0, stream>>>(sbuf, Av, decay);
        k_pdat<<<512, 256, 0, stream>>>(plist, counters, dmat, decay, pd);
        (void)hipMemsetAsync(agg_m, 0, K_TOP * F_DIM * sizeof(float), stream);
        k_aggd_p2<<<1024, 256, 0, stream>>>(pd, counters, xm, z1tab, mb1, mw2, mb2, agg_m);
        k_aggs_p<<<256, 256, 0, stream>>>(vdat, counters + 1, xm, wtab, agg_m);
        k_update<<<K_TOP / 4, 256, 0, stream>>>(agg_m, h_m, cf2w, cf2b, lw, lb, h_hier, K_TOP);
        k_blend<<<(N_ATOMS * H_DIM) / 256, 256, 0, stream>>>(h_loc, h_hier, is_m, invg, mbuf, h);
    }

    (void)hipMemsetAsync(pooled, 0, B_BATCH * H_DIM * sizeof(float), stream);
    k_pool<<<N_ATOMS / 64, 256, 0, stream>>>(h, batch, pooled);
    k_pred2<<<B_BATCH, 128, 0, stream>>>(pooled, fin[25], fin[26], fin[27], fin[28], d_out, dflag);
}

// Round 16
// 487.170 us; speedup vs baseline: 3.3148x; 1.1889x over previous
//
#include <hip/hip_runtime.h>
#include <hip/hip_bf16.h>
#include <math.h>

#define N_ATOMS 2048
#define E_EDGES 65536
#define B_BATCH 8
#define H_DIM 128
#define G_DIM 50
#define F_DIM 64
#define S_DIM 16
#define MH_DIM 32
#define K_TOP 512
#define L_LAYERS 2
#define EPW2 16
#define PCHUNK 32
#define NB 4096
#define DD 0.015625f        // 64/4096
#define INV_DD 64.0f

static constexpr float STEP   = 10.0f / 49.0f;
static constexpr float COEFF  = -12.005f;
static constexpr float PI10   = 0.31415926535897931f;
static constexpr float LN2    = 0.69314718055994531f;
static constexpr float LAMBDA = 0.002f;

#define DEV static __device__ __forceinline__

DEV float ssp_f(float x) { return fmaxf(x, 0.f) + log1pf(expf(-fabsf(x))) - LN2; }
DEV float ccut_f(float d) { return 0.5f * (cosf(d * PI10) + 1.f); }
DEV float sigm_f(float x) { return 1.f / (1.f + expf(-x)); }
DEV float ssp_fast(float x) { return fmaxf(x, 0.f) + __logf(1.f + __expf(-fabsf(x))) - LN2; }
DEV float ccut_fast(float d) { return 0.5f * (__cosf(d * PI10) + 1.f); }

// ---------------- dtype detect ----------------
__global__ __launch_bounds__(256) void k_detect(const unsigned short* raw, int n, int* flag) {
    __shared__ int any;
    if (threadIdx.x == 0) any = 0;
    __syncthreads();
    for (int i = threadIdx.x; i < n; i += 256) {
        unsigned int bits = ((unsigned int)raw[i]) << 16;
        float f = __uint_as_float(bits);
        if (!(fabsf(f) <= 1e10f)) any = 1;
    }
    __syncthreads();
    if (threadIdx.x == 0) flag[0] = any;
}

// ---------------- fused convert ----------------
struct ConvArgs {
    const void* p[25];
    int off[26];
};

__global__ __launch_bounds__(256) void k_convert_all(ConvArgs a, float* dst, const int* flag) {
    int i = blockIdx.x * 256 + threadIdx.x;
    int total = a.off[25];
    if (i >= total) return;
    int seg = 0;
    while (i >= a.off[seg + 1]) seg++;
    int k = i - a.off[seg];
    if (flag[0]) {
        dst[i] = ((const float*)a.p[seg])[k];
    } else {
        unsigned int bits = ((unsigned int)((const unsigned short*)a.p[seg])[k]) << 16;
        dst[i] = __uint_as_float(bits);
    }
}

// ---------------- edge counting-sort by dst ----------------
__global__ __launch_bounds__(256) void k_ehist(const int* dst, int* hist) {
    int e = blockIdx.x * 256 + threadIdx.x;
    atomicAdd(&hist[dst[e]], 1);
}

__global__ __launch_bounds__(1024) void k_escan(const int* hist, int* ebase, int* ecur) {
    __shared__ int bufA[N_ATOMS], bufB[N_ATOMS];
    int t = threadIdx.x;
    for (int i = t; i < N_ATOMS; i += 1024) bufA[i] = hist[i];
    __syncthreads();
    int* in = bufA;
    int* out = bufB;
    for (int d = 1; d < N_ATOMS; d <<= 1) {
        for (int i = t; i < N_ATOMS; i += 1024) out[i] = in[i] + (i >= d ? in[i - d] : 0);
        __syncthreads();
        int* tmp = in; in = out; out = tmp;
    }
    for (int i = t; i < N_ATOMS; i += 1024) {
        int ex = in[i] - hist[i];
        ebase[i] = ex;
        ecur[i] = ex;
    }
}

__global__ __launch_bounds__(256) void k_escatter(const int* dst, int* ecur, int* esorted) {
    int e = blockIdx.x * 256 + threadIdx.x;
    int pos = atomicAdd(&ecur[dst[e]], 1);
    esorted[pos] = e;
}

// ---------------- one-time packed edge data {src, dst, dist} ----------------
__global__ __launch_bounds__(256) void k_edat(const int* esorted, const int* src, const int* dst,
                                              const float* pos, int4* edat) {
    int p = blockIdx.x * 256 + threadIdx.x;
    int e = esorted[p];
    int s = src[e], d = dst[e];
    float dx = pos[s * 3 + 0] - pos[d * 3 + 0];
    float dy = pos[s * 3 + 1] - pos[d * 3 + 1];
    float dz = pos[s * 3 + 2] - pos[d * 3 + 2];
    float dist = sqrtf(dx * dx + dy * dy + dz * dz + 1e-12f);
    edat[p] = make_int4(s, d, __float_as_int(dist), 0);
}

// ---------------- per-layer filter tables (exact math, 4096 bins) ----------------
__global__ __launch_bounds__(128) void k_ftab(const float* mw1, const float* mb1,
                                              const float* mw2, const float* mb2,
                                              const float* aw1,
                                              float* z1tab, float* wtab, float* ztabS) {
    __shared__ float gs[G_DIM];
    __shared__ float tb[F_DIM];
    int b = blockIdx.x, t = threadIdx.x;
    float d = b * DD;
    if (t < G_DIM) { float u = d - t * STEP; gs[t] = expf(COEFF * u * u); }
    __syncthreads();
    const float* wd = aw1 + 2 * H_DIM * H_DIM;
    float zs = 0.f;
    for (int g = 0; g < G_DIM; g++) zs += gs[g] * wd[g * H_DIM + t];
    ztabS[b * H_DIM + t] = zs;
    if (t < F_DIM) {
        float z1 = 0.f;
        for (int g = 0; g < G_DIM; g++) z1 += gs[g] * mw1[g * F_DIM + t];
        z1tab[b * F_DIM + t] = z1;
        tb[t] = ssp_f(z1 + mb1[t]);
    }
    __syncthreads();
    if (t < F_DIM) {
        float w = mb2[t];
        for (int k = 0; k < F_DIM; k++) w += tb[k] * mw2[k * F_DIM + t];
        wtab[b * F_DIM + t] = w * ccut_f(d);
    }
}

// ---------------- embedding ----------------
__global__ __launch_bounds__(256) void k_embed(const int* atoms, const float* emb, float* h) {
    int i = blockIdx.x * 256 + threadIdx.x;
    int n = i >> 7, c = i & 127;
    h[i] = emb[atoms[n] * H_DIM + c];
}

// ---------------- x = h @ cf1 ----------------
__global__ __launch_bounds__(256) void k_x(const float* __restrict__ h, const float* __restrict__ cf1,
                                           float* __restrict__ x, int M) {
    int wave = threadIdx.x >> 6, lane = threadIdx.x & 63;
    int n = blockIdx.x * 4 + wave;
    if (n >= M) return;
    float acc = 0.f;
    for (int k = 0; k < H_DIM; k++) acc += h[n * H_DIM + k] * cf1[k * F_DIM + lane];
    x[n * F_DIM + lane] = acc;
}

// ---------------- edge filter: table lookup ----------------
__global__ __launch_bounds__(256) void k_edge_s(const int4* edat, const float* x,
                                                const float* __restrict__ wtab,
                                                float* agg) {
    int t = threadIdx.x, wave = t >> 6, lane = t & 63;
    int p0 = (blockIdx.x * 4 + wave) * EPW2;
    int curDst = -1;
    float acc = 0.f;
    for (int ee = 0; ee < EPW2; ee++) {
        int4 ed = edat[p0 + ee];
        int sI = ed.x, dI = ed.y;
        float d = __int_as_float(ed.z);
        float s = d * INV_DD;
        int b0 = min((int)s, NB - 2);
        float fr = s - b0;
        float w0 = wtab[b0 * F_DIM + lane];
        float w1 = wtab[(b0 + 1) * F_DIM + lane];
        float w = w0 + fr * (w1 - w0);
        float contrib = x[sI * F_DIM + lane] * w;
        if (dI != curDst) {
            if (curDst >= 0) atomicAdd(&agg[curDst * F_DIM + lane], acc);
            acc = 0.f;
            curDst = dI;
        }
        acc += contrib;
    }
    if (curDst >= 0) atomicAdd(&agg[curDst * F_DIM + lane], acc);
}

// ---------------- out = base + ssp(agg@cf2w + cf2b) @ lw + lb ----------------
__global__ __launch_bounds__(256) void k_update(const float* __restrict__ agg, const float* __restrict__ base,
                                                const float* cf2w, const float* cf2b,
                                                const float* lw, const float* lb,
                                                float* out, int M) {
    __shared__ float tbuf[4][H_DIM];
    int wave = threadIdx.x >> 6, lane = threadIdx.x & 63;
    int n = blockIdx.x * 4 + wave;
    float t0 = cf2b[lane], t1 = cf2b[lane + 64];
    if (n < M) {
        for (int f = 0; f < F_DIM; f++) {
            float a = agg[n * F_DIM + f];
            t0 += a * cf2w[f * H_DIM + lane];
            t1 += a * cf2w[f * H_DIM + lane + 64];
        }
    }
    tbuf[wave][lane] = ssp_f(t0);
    tbuf[wave][lane + 64] = ssp_f(t1);
    __syncthreads();
    if (n < M) {
        float o0 = lb[lane], o1 = lb[lane + 64];
        const float4* t4v = (const float4*)tbuf[wave];
        #pragma unroll
        for (int kk = 0; kk < 32; kk++) {
            float4 tq = t4v[kk];
            int k4 = kk * 4;
            o0 += tq.x * lw[(k4 + 0) * H_DIM + lane];
            o1 += tq.x * lw[(k4 + 0) * H_DIM + lane + 64];
            o0 += tq.y * lw[(k4 + 1) * H_DIM + lane];
            o1 += tq.y * lw[(k4 + 1) * H_DIM + lane + 64];
            o0 += tq.z * lw[(k4 + 2) * H_DIM + lane];
            o1 += tq.z * lw[(k4 + 2) * H_DIM + lane + 64];
            o0 += tq.w * lw[(k4 + 3) * H_DIM + lane];
            o1 += tq.w * lw[(k4 + 3) * H_DIM + lane + 64];
        }
        out[n * H_DIM + lane]      = base[n * H_DIM + lane] + o0;
        out[n * H_DIM + lane + 64] = base[n * H_DIM + lane + 64] + o1;
    }
}

// ---------------- node scores (exact: feeds top-K) ----------------
__global__ __launch_bounds__(256) void k_scores(const float* h_local,
                                                const float* msw1, const float* msb1,
                                                const float* msw2, const float* msb2,
                                                float* scores) {
    int n = blockIdx.x * 256 + threadIdx.x;
    if (n >= N_ATOMS) return;
    float hs[S_DIM];
    for (int s = 0; s < S_DIM; s++) hs[s] = h_local[n * H_DIM + s];
    float sc = msb2[0];
    for (int j = 0; j < MH_DIM; j++) {
        float v = msb1[j];
        for (int s = 0; s < S_DIM; s++) v += hs[s] * msw1[s * MH_DIM + j];
        sc += fmaxf(v, 0.f) * msw2[j];
    }
    scores[n] = sc;
}

// ---------------- parallel exact rank: 128 blocks, 16 i x 16 j-chunks ----------------
__global__ __launch_bounds__(256) void k_rank(const float* scores, int* rank) {
    __shared__ float s[N_ATOMS];
    __shared__ int pc[16][17];
    int t = threadIdx.x;
    for (int i = t; i < N_ATOMS; i += 256) s[i] = scores[i];
    __syncthreads();
    int ii = t & 15, chunk = t >> 4;
    int i = blockIdx.x * 16 + ii;
    float si = s[i];
    int cnt = 0;
    int j0 = chunk * (N_ATOMS / 16);
    #pragma unroll 4
    for (int j = j0; j < j0 + N_ATOMS / 16; j++) {
        float sj = s[j];
        cnt += (sj > si) || (sj == si && j < i);
    }
    pc[chunk][ii] = cnt;
    __syncthreads();
    if (chunk == 0) {
        int r = 0;
        #pragma unroll
        for (int c = 0; c < 16; c++) r += pc[c][ii];
        rank[i] = r;
    }
}

// ---------------- selection, prefix, midx, m ----------------
__global__ __launch_bounds__(1024) void k_select(const float* scores, const int* rank,
                                                 int* is_m, int* invg, int* midx, float* m) {
    __shared__ int flag[N_ATOMS];
    __shared__ int bufA[N_ATOMS], bufB[N_ATOMS];
    __shared__ float kth;
    int t = threadIdx.x;
    for (int i = t; i < N_ATOMS; i += 1024) {
        int f = rank[i] < K_TOP;
        flag[i] = f;
        bufA[i] = f;
        if (rank[i] == K_TOP - 1) kth = scores[i];
    }
    __syncthreads();
    int* in = bufA;
    int* out = bufB;
    for (int d = 1; d < N_ATOMS; d <<= 1) {
        for (int i = t; i < N_ATOMS; i += 1024) out[i] = in[i] + (i >= d ? in[i - d] : 0);
        __syncthreads();
        int* tmp = in; in = out; out = tmp;
    }
    float kv = kth;
    for (int i = t; i < N_ATOMS; i += 1024) {
        int f = flag[i];
        int pos = in[i] - f;
        is_m[i] = f;
        invg[i] = f ? pos : 0;
        if (f) midx[pos] = i;
        m[i] = sigm_f(scores[i] - kv + 1e-6f);
    }
}

// ---------------- gather h_m / pos_m ----------------
__global__ __launch_bounds__(256) void k_gather(const int* midx, const float* h_local,
                                                const float* pos, float* h_m, float* pos_m) {
    int i = blockIdx.x * 256 + threadIdx.x;
    int k = i >> 7, c = i & 127;
    int n = midx[k];
    h_m[i] = h_local[n * H_DIM + c];
    if (c < 3) pos_m[k * 3 + c] = pos[n * 3 + c];
}

// ---------------- adjacency + valid-edge list ----------------
__global__ __launch_bounds__(256) void k_adj(const int* src, const int* dst, const int* is_m,
                                             const int* invg, unsigned char* adj,
                                             int* velist, int* nve) {
    int e = blockIdx.x * 256 + threadIdx.x;
    int s = src[e], d = dst[e];
    bool valid = is_m[s] && is_m[d];
    if (valid) adj[invg[s] * K_TOP + invg[d]] = 1;
    unsigned long long mask = __ballot(valid);
    int lane = threadIdx.x & 63;
    int cnt = __popcll(mask);
    int base = 0;
    if (lane == 0 && cnt) base = atomicAdd(nve, cnt);
    base = __shfl(base, 0);
    if (valid) velist[base + __popcll(mask & ((1ull << lane) - 1))] = e;
}

// ---------------- per-valid-edge packed data {sm, dm, dist} ----------------
__global__ __launch_bounds__(256) void k_vdat(const int* velist, const int* nve,
                                              const int* src, const int* dst, const int* invg,
                                              const float* pos_m, int4* vdat) {
    int n = nve[0];
    for (int p = blockIdx.x * 256 + threadIdx.x; p < n; p += gridDim.x * 256) {
        int e = velist[p];
        int sm = invg[src[e]];
        int dm = invg[dst[e]];
        float dx = pos_m[sm * 3 + 0] - pos_m[dm * 3 + 0];
        float dy = pos_m[sm * 3 + 1] - pos_m[dm * 3 + 1];
        float dz = pos_m[sm * 3 + 2] - pos_m[dm * 3 + 2];
        float dist = sqrtf(dx * dx + dy * dy + dz * dz + 1e-12f);
        vdat[p] = make_int4(sm, dm, __float_as_int(dist), 0);
    }
}

// ---------------- q/k projections ----------------
__global__ __launch_bounds__(256) void k_qk(const float* h_m, const float* wq,
                                            const float* wk, float* qm, float* km) {
    int gid = blockIdx.x * 256 + threadIdx.x;
    int r = gid >> 5, t = gid & 31;
    const float* w = (t < 16) ? wq : wk;
    int c = t & 15;
    float acc = 0.f;
    for (int s = 0; s < S_DIM; s++) acc += h_m[r * H_DIM + s] * w[s * S_DIM + c];
    if (t < 16) qm[r * S_DIM + c] = acc; else km[r * S_DIM + c] = acc;
}

// ---------------- attention softmax -> Av mask (exact) ----------------
__global__ __launch_bounds__(256) void k_attn(const float* qm, const float* km,
                                              const unsigned char* adj, unsigned char* Av) {
    __shared__ float lrow[K_TOP];
    __shared__ float red[256];
    int i = blockIdx.x, t = threadIdx.x;
    float q[S_DIM];
    for (int s = 0; s < S_DIM; s++) q[s] = qm[i * S_DIM + s];
    for (int j = t; j < K_TOP; j += 256) {
        float acc = 0.f;
        for (int s = 0; s < S_DIM; s++) acc += q[s] * km[j * S_DIM + s];
        lrow[j] = acc * 0.25f;
    }
    __syncthreads();
    float mx = -1e30f;
    for (int j = t; j < K_TOP; j += 256) mx = fmaxf(mx, lrow[j]);
    red[t] = mx; __syncthreads();
    for (int o = 128; o > 0; o >>= 1) { if (t < o) red[t] = fmaxf(red[t], red[t + o]); __syncthreads(); }
    mx = red[0]; __syncthreads();
    float sum = 0.f;
    for (int j = t; j < K_TOP; j += 256) sum += expf(lrow[j] - mx);
    red[t] = sum; __syncthreads();
    for (int o = 128; o > 0; o >>= 1) { if (t < o) red[t] += red[t + o]; __syncthreads(); }
    float inv_s = 1.f / red[0];
    for (int j = t; j < K_TOP; j += 256) {
        float a = expf(lrow[j] - mx) * inv_s;
        Av[i * K_TOP + j] = (a > LAMBDA) && (!adj[i * K_TOP + j]) && (i != j);
    }
}

// ---------------- deterministic j-major pair compaction ----------------
__global__ __launch_bounds__(256) void k_pcount(const unsigned char* Av, int* bcount) {
    __shared__ int wsum[4];
    int idx = blockIdx.x * 256 + threadIdx.x;
    int j = idx >> 9, i = idx & (K_TOP - 1);
    bool act = Av[i * K_TOP + j] != 0;
    unsigned long long mask = __ballot(act);
    int lane = threadIdx.x & 63, wave = threadIdx.x >> 6;
    if (lane == 0) wsum[wave] = __popcll(mask);
    __syncthreads();
    if (threadIdx.x == 0) bcount[blockIdx.x] = wsum[0] + wsum[1] + wsum[2] + wsum[3];
}

__global__ __launch_bounds__(1024) void k_pscan(const int* bcount, int* boffset, int* total) {
    __shared__ int bufA[1024], bufB[1024];
    int t = threadIdx.x;
    bufA[t] = bcount[t];
    __syncthreads();
    int* in = bufA;
    int* out = bufB;
    for (int d = 1; d < 1024; d <<= 1) {
        out[t] = in[t] + (t >= d ? in[t - d] : 0);
        __syncthreads();
        int* tmp = in; in = out; out = tmp;
    }
    boffset[t] = in[t] - bcount[t];
    if (t == 1023) total[0] = in[1023];
}

__global__ __launch_bounds__(256) void k_pscatter(const unsigned char* Av, const int* boffset,
                                                  unsigned int* plist) {
    __shared__ int wsum[4], woff[4];
    int idx = blockIdx.x * 256 + threadIdx.x;
    int j = idx >> 9, i = idx & (K_TOP - 1);
    bool act = Av[i * K_TOP + j] != 0;
    unsigned long long mask = __ballot(act);
    int lane = threadIdx.x & 63, wave = threadIdx.x >> 6;
    if (lane == 0) wsum[wave] = __popcll(mask);
    __syncthreads();
    if (threadIdx.x == 0) {
        int s = 0;
        for (int w = 0; w < 4; w++) { woff[w] = s; s += wsum[w]; }
    }
    __syncthreads();
    if (act) {
        int pos = boffset[blockIdx.x] + woff[wave] + __popcll(mask & ((1ull << lane) - 1));
        plist[pos] = ((unsigned int)j << 9) | (unsigned int)i;
    }
}

// ---------------- pairwise distances ----------------
__global__ __launch_bounds__(256) void k_dmat(const float* pos_m, float* dmat) {
    int idx = blockIdx.x * 256 + threadIdx.x;
    int i = idx >> 9, j = idx & (K_TOP - 1);
    float dx = pos_m[i * 3 + 0] - pos_m[j * 3 + 0];
    float dy = pos_m[i * 3 + 1] - pos_m[j * 3 + 1];
    float dz = pos_m[i * 3 + 2] - pos_m[j * 3 + 2];
    dmat[idx] = sqrtf(dx * dx + dy * dy + dz * dz + 1e-12f);
}

// ---------------- packed pair data for score: {key, dd} ----------------
__global__ __launch_bounds__(256) void k_sdata(const unsigned int* plist, const int* npairs,
                                               const float* dmat, float2* sd) {
    int n = npairs[0];
    for (int p = blockIdx.x * 256 + threadIdx.x; p < n; p += gridDim.x * 256) {
        unsigned int key = plist[p];
        int j = key >> 9, i = key & (K_TOP - 1);
        sd[p] = make_float2(__uint_as_float(key), dmat[i * K_TOP + j]);
    }
}

// ---------------- packed pair data for aggd: {key, dd, dec} ----------------
__global__ __launch_bounds__(256) void k_pdat(const unsigned int* plist, const int* npairs,
                                              const float* dmat, const float* decay, float4* pd) {
    int n = npairs[0];
    for (int p = blockIdx.x * 256 + threadIdx.x; p < n; p += gridDim.x * 256) {
        unsigned int key = plist[p];
        int j = key >> 9, i = key & (K_TOP - 1);
        int ij = i * K_TOP + j;
        pd[p] = make_float4(__uint_as_float(key), dmat[ij], decay[ij], 0.f);
    }
}

// ---------------- hi = h_m@Wi, hj = h_m@Wj ----------------
__global__ __launch_bounds__(256) void k_hij(const float* h_m, const float* aw1,
                                             float* hi, float* hj) {
    int wave = threadIdx.x >> 6, lane = threadIdx.x & 63;
    int idx = blockIdx.x * 4 + wave;
    int which = idx >> 9;
    int r = idx & (K_TOP - 1);
    const float* W = aw1 + which * H_DIM * H_DIM;
    float o0 = 0.f, o1 = 0.f;
    for (int k = 0; k < H_DIM; k++) {
        float hv = h_m[r * H_DIM + k];
        o0 += hv * W[k * H_DIM + lane];
        o1 += hv * W[k * H_DIM + lane + 64];
    }
    float* out = which ? hj : hi;
    out[r * H_DIM + lane] = o0;
    out[r * H_DIM + lane + 64] = o1;
}

// ---------------- per-pair attention scores: ztabS lookup ----------------
__global__ __launch_bounds__(256) void k_score_p(const float2* sd, const int* npairs,
                                                 const float* hi, const float* hj,
                                                 const float* __restrict__ ztabS,
                                                 const float* ab1, const float* aw2, const float* ab2,
                                                 float* sbuf) {
    int t = threadIdx.x, wave = t >> 6, lane = t & 63;
    float ab0 = ab1[lane], ab1v = ab1[lane + 64];
    float aw0 = aw2[lane], aw1v = aw2[lane + 64];
    float b2 = ab2[0];
    int n = npairs[0];
    int wid = blockIdx.x * 4 + wave;
    int nw = gridDim.x * 4;
    for (int p = wid; p < n; p += nw) {
        float2 s2 = sd[p];
        unsigned int key = __float_as_uint(s2.x);
        float dd = s2.y;
        int j = key >> 9, i = key & (K_TOP - 1);
        int ij = i * K_TOP + j;
        float s = dd * INV_DD;
        int b0 = min((int)s, NB - 2);
        float fr = s - b0;
        const float* r0 = ztabS + b0 * H_DIM;
        const float* r1 = r0 + H_DIM;
        float z0a = r0[lane],      z1a = r1[lane];
        float z0b = r0[lane + 64], z1b = r1[lane + 64];
        float zs0 = z0a + fr * (z1a - z0a);
        float zs1 = z0b + fr * (z1b - z0b);
        float v0 = hi[i * H_DIM + lane] + hj[j * H_DIM + lane] + ab0 + zs0;
        float v1 = hi[i * H_DIM + lane + 64] + hj[j * H_DIM + lane + 64] + ab1v + zs1;
        float pv = fmaxf(v0, 0.f) * aw0 + fmaxf(v1, 0.f) * aw1v;
        for (int o = 1; o < 64; o <<= 1) pv += __shfl_xor(pv, o);
        if (lane == 0) sbuf[ij] = pv + b2;
    }
}

// ---------------- row softmax (Av-guarded) -> decay (exact) ----------------
__global__ __launch_bounds__(256) void k_decay(const float* sbuf, const unsigned char* Av, float* decay) {
    __shared__ float srow[K_TOP];
    __shared__ float red[256];
    int i = blockIdx.x, t = threadIdx.x;
    for (int j = t; j < K_TOP; j += 256)
        srow[j] = Av[i * K_TOP + j] ? sbuf[i * K_TOP + j] : -1e9f;
    __syncthreads();
    float mx = -1e30f;
    for (int j = t; j < K_TOP; j += 256) mx = fmaxf(mx, srow[j]);
    red[t] = mx; __syncthreads();
    for (int o = 128; o > 0; o >>= 1) { if (t < o) red[t] = fmaxf(red[t], red[t + o]); __syncthreads(); }
    mx = red[0]; __syncthreads();
    float sum = 0.f;
    for (int j = t; j < K_TOP; j += 256) sum += (srow[j] > -5e8f) ? expf(srow[j] - mx) : 0.f;
    red[t] = sum; __syncthreads();
    for (int o = 128; o > 0; o >>= 1) { if (t < o) red[t] += red[t + o]; __syncthreads(); }
    float s_total = red[0];
    float inv_s = (s_total > 0.f) ? 1.f / s_total : 0.f;
    for (int j = t; j < K_TOP; j += 256)
        decay[i * K_TOP + j] = (srow[j] > -5e8f) ? expf(srow[j] - mx) * inv_s : 0.f;
}

// ---------------- agg_d: z1 table + second layer ----------------
__global__ __launch_bounds__(256) void k_aggd_p2(const float4* pd, const int* npairs,
                                                 const float* xm,
                                                 const float* __restrict__ z1tab,
                                                 const float* mb1,
                                                 const float* mw2, const float* mb2,
                                                 float* agg_m) {
    __shared__ float tbuf[4][F_DIM];
    int t = threadIdx.x, wave = t >> 6, lane = t & 63;
    float w2r[F_DIM];
    #pragma unroll
    for (int k = 0; k < F_DIM; k++) w2r[k] = mw2[k * F_DIM + lane];
    float b1 = mb1[lane], b2v = mb2[lane];
    int n = npairs[0];
    int nchunks = (n + PCHUNK - 1) / PCHUNK;
    int wid = blockIdx.x * 4 + wave;
    int nw = gridDim.x * 4;
    for (int c = wid; c < nchunks; c += nw) {
        int p0 = c * PCHUNK;
        int p1 = min(p0 + PCHUNK, n);
        int curJ = -1;
        float acc = 0.f;
        for (int p = p0; p < p1; p++) {
            float4 q = pd[p];
            unsigned int key = __float_as_uint(q.x);
            float dd = q.y, dec = q.z;
            int j = key >> 9, i = key & (K_TOP - 1);
            float s = dd * INV_DD;
            int b0 = min((int)s, NB - 2);
            float fr = s - b0;
            float z0 = z1tab[b0 * F_DIM + lane];
            float z1 = z1tab[(b0 + 1) * F_DIM + lane];
            float z1v = z0 + fr * (z1 - z0);
            float tv = ssp_fast(dec * z1v + b1);
            tbuf[wave][lane] = tv;
            float w = b2v;
            const float4* t4v = (const float4*)tbuf[wave];
            #pragma unroll
            for (int kk = 0; kk < 16; kk++) {
                float4 tq = t4v[kk];
                w += tq.x * w2r[4 * kk + 0];
                w += tq.y * w2r[4 * kk + 1];
                w += tq.z * w2r[4 * kk + 2];
                w += tq.w * w2r[4 * kk + 3];
            }
            float contrib = xm[i * F_DIM + lane] * w * ccut_fast(dd);
            if (j != curJ) {
                if (curJ >= 0) atomicAdd(&agg_m[curJ * F_DIM + lane], acc);
                acc = 0.f;
                curJ = j;
            }
            acc += contrib;
        }
        if (curJ >= 0) atomicAdd(&agg_m[curJ * F_DIM + lane], acc);
    }
}

// ---------------- valid-edge filter: table lookup ----------------
__global__ __launch_bounds__(256) void k_aggs_p(const int4* vdat, const int* nve,
                                                const float* xm,
                                                const float* __restrict__ wtab,
                                                float* agg_m) {
    int t = threadIdx.x, wave = t >> 6, lane = t & 63;
    int n = nve[0];
    int wid = blockIdx.x * 4 + wave;
    int nw = gridDim.x * 4;
    for (int p = wid; p < n; p += nw) {
        int4 vd = vdat[p];
        int sm = vd.x, dm = vd.y;
        float d = __int_as_float(vd.z);
        float s = d * INV_DD;
        int b0 = min((int)s, NB - 2);
        float fr = s - b0;
        float w0 = wtab[b0 * F_DIM + lane];
        float w1 = wtab[(b0 + 1) * F_DIM + lane];
        float w = w0 + fr * (w1 - w0);
        atomicAdd(&agg_m[dm * F_DIM + lane], xm[sm * F_DIM + lane] * w);
    }
}

// ---------------- blend ----------------
__global__ __launch_bounds__(256) void k_blend(const float* h_local, const float* h_hier,
                                               const int* is_m, const int* invg, const float* m,
                                               float* h_out) {
    int idx = blockIdx.x * 256 + threadIdx.x;
    int n = idx >> 7, c = idx & 127;
    float mm = m[n];
    float hh = is_m[n] ? h_hier[invg[n] * H_DIM + c] : 0.f;
    h_out[idx] = (1.f - mm) * h_local[idx] + mm * hh;
}

// ---------------- parallel segment-sum pooling ----------------
__global__ __launch_bounds__(256) void k_pool(const float* __restrict__ h, const int* __restrict__ batch,
                                              float* pooled) {
    int c = threadIdx.x & 127, a = threadIdx.x >> 7;
    int n0 = blockIdx.x * 64;
    float acc = 0.f;
    int cur = batch[n0 + a];
    for (int i = a; i < 64; i += 2) {
        int n = n0 + i;
        int b = batch[n];
        if (b != cur) { atomicAdd(&pooled[cur * H_DIM + c], acc); acc = 0.f; cur = b; }
        acc += h[n * H_DIM + c];
    }
    atomicAdd(&pooled[cur * H_DIM + c], acc);
}

// ---------------- predict MLP ----------------
__global__ __launch_bounds__(128) void k_pred2(const float* pooled,
                                               const float* w1, const float* b1,
                                               const float* w2, const float* b2,
                                               void* outv, const int* flag) {
    __shared__ float c64[64];
    int b = blockIdx.x, t = threadIdx.x;
    if (t < 64) {
        float v = b1[t];
        for (int k = 0; k < H_DIM; k++) v += pooled[b * H_DIM + k] * w1[k * 64 + t];
        c64[t] = v * sigm_f(v);
    }
    __syncthreads();
    if (t == 0) {
        float o = b2[0];
        for (int k = 0; k < 64; k++) o += c64[k] * w2[k];
        if (flag[0]) ((float*)outv)[b] = o;
        else ((__hip_bfloat16*)outv)[b] = __float2bfloat16(o);
    }
}

extern "C" void kernel_launch(void* const* d_in, const int* in_sizes, int n_in,
                              void* d_out, int out_size, void* d_ws, size_t ws_size,
                              hipStream_t stream) {
    (void)n_in; (void)out_size; (void)ws_size;
    const int* atoms = (const int*)d_in[0];
    const int* src = (const int*)d_in[2];
    const int* dst = (const int*)d_in[3];
    const int* batch = (const int*)d_in[4];

    float* W = (float*)d_ws;
    int* dflag = (int*)W; W += 16;
    int* counters = (int*)W; W += 16;  // [0]=npairs, [1]=nve

    static const int fidx[25] = {1,5,6,7,8,9,10,11,12,13,14,15,16,17,18,19,20,21,22,23,24,25,26,27,28};
    float* fin[29];
    ConvArgs ca;
    float* convBase = W;
    int off = 0;
    for (int q = 0; q < 25; q++) {
        int i = fidx[q];
        ca.p[q] = d_in[i];
        ca.off[q] = off;
        fin[i] = convBase + off;
        off += in_sizes[i];
    }
    ca.off[25] = off;
    W += off;

    k_detect<<<1, 256, 0, stream>>>((const unsigned short*)d_in[5], in_sizes[5], dflag);
    k_convert_all<<<(off + 255) / 256, 256, 0, stream>>>(ca, convBase, dflag);

    const float* posf = fin[1];
    const float* embf = fin[5];

    float* h      = W; W += N_ATOMS * H_DIM;
    float* h_loc  = W; W += N_ATOMS * H_DIM;
    float* xbuf   = W; W += N_ATOMS * F_DIM;
    float* aggbuf = W; W += N_ATOMS * F_DIM;
    float* scores = W; W += N_ATOMS;
    float* mbuf   = W; W += N_ATOMS;
    float* h_m    = W; W += K_TOP * H_DIM;
    float* pos_m  = W; W += K_TOP * 3;
    float* xm     = W; W += K_TOP * F_DIM;
    float* qm     = W; W += K_TOP * S_DIM;
    float* km     = W; W += K_TOP * S_DIM;
    float* dmat   = W; W += K_TOP * K_TOP;
    float* decay  = W; W += K_TOP * K_TOP;
    float* sbuf   = W; W += K_TOP * K_TOP;
    float* hi     = W; W += K_TOP * H_DIM;
    float* hj     = W; W += K_TOP * H_DIM;
    float* agg_m  = W; W += K_TOP * F_DIM;
    float* h_hier = W; W += K_TOP * H_DIM;
    float* pooled = W; W += B_BATCH * H_DIM;
    float* z1tab  = W; W += NB * F_DIM;
    float* wtab   = W; W += NB * F_DIM;
    float* ztabS  = W; W += NB * H_DIM;
    int* rankb  = (int*)W; W += N_ATOMS;
    int* is_m   = (int*)W; W += N_ATOMS;
    int* invg   = (int*)W; W += N_ATOMS;
    int* midx   = (int*)W; W += K_TOP;
    unsigned int* plist = (unsigned int*)W; W += K_TOP * K_TOP;
    int* velist = (int*)W; W += E_EDGES;
    int* esorted = (int*)W; W += E_EDGES;
    int* ehist  = (int*)W; W += N_ATOMS;
    int* ebase  = (int*)W; W += N_ATOMS;
    int* ecur   = (int*)W; W += N_ATOMS;
    int* bcount = (int*)W; W += 1024;
    int* boffset = (int*)W; W += 1024;
    int4* edat  = (int4*)W; W += E_EDGES * 4;
    int4* vdat  = (int4*)W; W += E_EDGES * 4;
    float2* sd  = (float2*)W; W += K_TOP * K_TOP * 2;
    float4* pd  = (float4*)W; W += K_TOP * K_TOP * 4;
    unsigned char* adj = (unsigned char*)W; W += (K_TOP * K_TOP) / 4;
    unsigned char* Av  = (unsigned char*)W; W += (K_TOP * K_TOP) / 4;

    // one-time: counting-sort edges by dst + packed edge data
    (void)hipMemsetAsync(ehist, 0, N_ATOMS * sizeof(int), stream);
    k_ehist<<<E_EDGES / 256, 256, 0, stream>>>(dst, ehist);
    k_escan<<<1, 1024, 0, stream>>>(ehist, ebase, ecur);
    k_escatter<<<E_EDGES / 256, 256, 0, stream>>>(dst, ecur, esorted);
    k_edat<<<E_EDGES / 256, 256, 0, stream>>>(esorted, src, dst, posf, edat);

    k_embed<<<(N_ATOMS * H_DIM) / 256, 256, 0, stream>>>(atoms, embf, h);

    for (int l = 0; l < L_LAYERS; l++) {
        const float* mw1 = fin[6]  + l * G_DIM * F_DIM;
        const float* mb1 = fin[7]  + l * F_DIM;
        const float* mw2 = fin[8]  + l * F_DIM * F_DIM;
        const float* mb2 = fin[9]  + l * F_DIM;
        const float* cf1 = fin[10] + l * H_DIM * F_DIM;
        const float* cf2w = fin[11] + l * F_DIM * H_DIM;
        const float* cf2b = fin[12] + l * H_DIM;
        const float* lw  = fin[13] + l * H_DIM * H_DIM;
        const float* lb  = fin[14] + l * H_DIM;
        const float* aw1 = fin[15] + l * (2 * H_DIM + G_DIM) * H_DIM;
        const float* ab1 = fin[16] + l * H_DIM;
        const float* aw2 = fin[17] + l * H_DIM;
        const float* ab2 = fin[18] + l;
        const float* msw1 = fin[19] + l * S_DIM * MH_DIM;
        const float* msb1 = fin[20] + l * MH_DIM;
        const float* msw2 = fin[21] + l * MH_DIM;
        const float* msb2 = fin[22] + l;
        const float* wq  = fin[23] + l * S_DIM * S_DIM;
        const float* wk  = fin[24] + l * S_DIM * S_DIM;

        k_ftab<<<NB, 128, 0, stream>>>(mw1, mb1, mw2, mb2, aw1, z1tab, wtab, ztabS);
        k_x<<<N_ATOMS / 4, 256, 0, stream>>>(h, cf1, xbuf, N_ATOMS);
        (void)hipMemsetAsync(aggbuf, 0, N_ATOMS * F_DIM * sizeof(float), stream);
        k_edge_s<<<E_EDGES / (4 * EPW2), 256, 0, stream>>>(edat, xbuf, wtab, aggbuf);
        k_update<<<N_ATOMS / 4, 256, 0, stream>>>(aggbuf, h, cf2w, cf2b, lw, lb, h_loc, N_ATOMS);
        k_scores<<<N_ATOMS / 256, 256, 0, stream>>>(h_loc, msw1, msb1, msw2, msb2, scores);
        k_rank<<<N_ATOMS / 16, 256, 0, stream>>>(scores, rankb);
        k_select<<<1, 1024, 0, stream>>>(scores, rankb, is_m, invg, midx, mbuf);
        k_gather<<<(K_TOP * H_DIM) / 256, 256, 0, stream>>>(midx, h_loc, posf, h_m, pos_m);
        k_x<<<K_TOP / 4, 256, 0, stream>>>(h_m, cf1, xm, K_TOP);
        (void)hipMemsetAsync(adj, 0, K_TOP * K_TOP, stream);
        (void)hipMemsetAsync(counters, 0, 2 * sizeof(int), stream);
        k_adj<<<E_EDGES / 256, 256, 0, stream>>>(src, dst, is_m, invg, adj, velist, counters + 1);
        k_vdat<<<256, 256, 0, stream>>>(velist, counters + 1, src, dst, invg, pos_m, vdat);
        k_qk<<<(K_TOP * 32) / 256, 256, 0, stream>>>(h_m, wq, wk, qm, km);
        k_attn<<<K_TOP, 256, 0, stream>>>(qm, km, adj, Av);
        k_pcount<<<(K_TOP * K_TOP) / 256, 256, 0, stream>>>(Av, bcount);
        k_pscan<<<1, 1024, 0, stream>>>(bcount, boffset, counters);
        k_pscatter<<<(K_TOP * K_TOP) / 256, 256, 0, stream>>>(Av, boffset, plist);
        k_dmat<<<(K_TOP * K_TOP) / 256, 256, 0, stream>>>(pos_m, dmat);
        k_sdata<<<512, 256, 0, stream>>>(plist, counters, dmat, sd);
        k_hij<<<(2 * K_TOP) / 4, 256, 0, stream>>>(h_m, aw1, hi, hj);
        k_score_p<<<1024, 256, 0, stream>>>(sd, counters, hi, hj, ztabS, ab1, aw2, ab2, sbuf);
        k_decay<<<K_TOP, 256, 0, stream>>>(sbuf, Av, decay);
        k_pdat<<<512, 256, 0, stream>>>(plist, counters, dmat, decay, pd);
        (void)hipMemsetAsync(agg_m, 0, K_TOP * F_DIM * sizeof(float), stream);
        k_aggd_p2<<<1024, 256, 0, stream>>>(pd, counters, xm, z1tab, mb1, mw2, mb2, agg_m);
        k_aggs_p<<<256, 256, 0, stream>>>(vdat, counters + 1, xm, wtab, agg_m);
        k_update<<<K_TOP / 4, 256, 0, stream>>>(agg_m, h_m, cf2w, cf2b, lw, lb, h_hier, K_TOP);
        k_blend<<<(N_ATOMS * H_DIM) / 256, 256, 0, stream>>>(h_loc, h_hier, is_m, invg, mbuf, h);
    }

    (void)hipMemsetAsync(pooled, 0, B_BATCH * H_DIM * sizeof(float), stream);
    k_pool<<<N_ATOMS / 64, 256, 0, stream>>>(h, batch, pooled);
    k_pred2<<<B_BATCH, 128, 0, stream>>>(pooled, fin[25], fin[26], fin[27], fin[28], d_out, dflag);
}

// Round 17
// 486.945 us; speedup vs baseline: 3.3164x; 1.0005x over previous
//
#include <hip/hip_runtime.h>
#include <hip/hip_bf16.h>
#include <math.h>

#define N_ATOMS 2048
#define E_EDGES 65536
#define B_BATCH 8
#define H_DIM 128
#define G_DIM 50
#define F_DIM 64
#define S_DIM 16
#define MH_DIM 32
#define K_TOP 512
#define L_LAYERS 2
#define EPW2 16
#define PCHUNK 32
#define NB 4096
#define DD 0.015625f        // 64/4096
#define INV_DD 64.0f

static constexpr float STEP   = 10.0f / 49.0f;
static constexpr float COEFF  = -12.005f;
static constexpr float PI10   = 0.31415926535897931f;
static constexpr float LN2    = 0.69314718055994531f;
static constexpr float LAMBDA = 0.002f;

#define DEV static __device__ __forceinline__

DEV float ssp_f(float x) { return fmaxf(x, 0.f) + log1pf(expf(-fabsf(x))) - LN2; }
DEV float ccut_f(float d) { return 0.5f * (cosf(d * PI10) + 1.f); }
DEV float sigm_f(float x) { return 1.f / (1.f + expf(-x)); }
DEV float ssp_fast(float x) { return fmaxf(x, 0.f) + __logf(1.f + __expf(-fabsf(x))) - LN2; }
DEV float ccut_fast(float d) { return 0.5f * (__cosf(d * PI10) + 1.f); }

// ---------------- dtype detect ----------------
__global__ __launch_bounds__(256) void k_detect(const unsigned short* raw, int n, int* flag) {
    __shared__ int any;
    if (threadIdx.x == 0) any = 0;
    __syncthreads();
    for (int i = threadIdx.x; i < n; i += 256) {
        unsigned int bits = ((unsigned int)raw[i]) << 16;
        float f = __uint_as_float(bits);
        if (!(fabsf(f) <= 1e10f)) any = 1;
    }
    __syncthreads();
    if (threadIdx.x == 0) flag[0] = any;
}

// ---------------- fused convert ----------------
struct ConvArgs {
    const void* p[25];
    int off[26];
};

__global__ __launch_bounds__(256) void k_convert_all(ConvArgs a, float* dst, const int* flag) {
    int i = blockIdx.x * 256 + threadIdx.x;
    int total = a.off[25];
    if (i >= total) return;
    int seg = 0;
    while (i >= a.off[seg + 1]) seg++;
    int k = i - a.off[seg];
    if (flag[0]) {
        dst[i] = ((const float*)a.p[seg])[k];
    } else {
        unsigned int bits = ((unsigned int)((const unsigned short*)a.p[seg])[k]) << 16;
        dst[i] = __uint_as_float(bits);
    }
}

// ---------------- edge counting-sort by dst ----------------
__global__ __launch_bounds__(256) void k_ehist(const int* dst, int* hist) {
    int e = blockIdx.x * 256 + threadIdx.x;
    atomicAdd(&hist[dst[e]], 1);
}

__global__ __launch_bounds__(1024) void k_escan(const int* hist, int* ebase, int* ecur) {
    __shared__ int bufA[N_ATOMS], bufB[N_ATOMS];
    int t = threadIdx.x;
    for (int i = t; i < N_ATOMS; i += 1024) bufA[i] = hist[i];
    __syncthreads();
    int* in = bufA;
    int* out = bufB;
    for (int d = 1; d < N_ATOMS; d <<= 1) {
        for (int i = t; i < N_ATOMS; i += 1024) out[i] = in[i] + (i >= d ? in[i - d] : 0);
        __syncthreads();
        int* tmp = in; in = out; out = tmp;
    }
    for (int i = t; i < N_ATOMS; i += 1024) {
        int ex = in[i] - hist[i];
        ebase[i] = ex;
        ecur[i] = ex;
    }
}

__global__ __launch_bounds__(256) void k_escatter(const int* dst, int* ecur, int* esorted) {
    int e = blockIdx.x * 256 + threadIdx.x;
    int pos = atomicAdd(&ecur[dst[e]], 1);
    esorted[pos] = e;
}

// ---------------- one-time packed edge data {src, dst, dist} ----------------
__global__ __launch_bounds__(256) void k_edat(const int* esorted, const int* src, const int* dst,
                                              const float* pos, int4* edat) {
    int p = blockIdx.x * 256 + threadIdx.x;
    int e = esorted[p];
    int s = src[e], d = dst[e];
    float dx = pos[s * 3 + 0] - pos[d * 3 + 0];
    float dy = pos[s * 3 + 1] - pos[d * 3 + 1];
    float dz = pos[s * 3 + 2] - pos[d * 3 + 2];
    float dist = sqrtf(dx * dx + dy * dy + dz * dz + 1e-12f);
    edat[p] = make_int4(s, d, __float_as_int(dist), 0);
}

// ---------------- per-layer filter tables (exact math, 4096 bins) ----------------
__global__ __launch_bounds__(128) void k_ftab(const float* mw1, const float* mb1,
                                              const float* mw2, const float* mb2,
                                              const float* aw1,
                                              float* z1tab, float* wtab, float* ztabS) {
    __shared__ float gs[G_DIM];
    __shared__ float tb[F_DIM];
    int b = blockIdx.x, t = threadIdx.x;
    float d = b * DD;
    if (t < G_DIM) { float u = d - t * STEP; gs[t] = expf(COEFF * u * u); }
    __syncthreads();
    const float* wd = aw1 + 2 * H_DIM * H_DIM;
    float zs = 0.f;
    for (int g = 0; g < G_DIM; g++) zs += gs[g] * wd[g * H_DIM + t];
    ztabS[b * H_DIM + t] = zs;
    if (t < F_DIM) {
        float z1 = 0.f;
        for (int g = 0; g < G_DIM; g++) z1 += gs[g] * mw1[g * F_DIM + t];
        z1tab[b * F_DIM + t] = z1;
        tb[t] = ssp_f(z1 + mb1[t]);
    }
    __syncthreads();
    if (t < F_DIM) {
        float w = mb2[t];
        for (int k = 0; k < F_DIM; k++) w += tb[k] * mw2[k * F_DIM + t];
        wtab[b * F_DIM + t] = w * ccut_f(d);
    }
}

// ---------------- embedding ----------------
__global__ __launch_bounds__(256) void k_embed(const int* atoms, const float* emb, float* h) {
    int i = blockIdx.x * 256 + threadIdx.x;
    int n = i >> 7, c = i & 127;
    h[i] = emb[atoms[n] * H_DIM + c];
}

// ---------------- x = h @ cf1 ----------------
__global__ __launch_bounds__(256) void k_x(const float* __restrict__ h, const float* __restrict__ cf1,
                                           float* __restrict__ x, int M) {
    int wave = threadIdx.x >> 6, lane = threadIdx.x & 63;
    int n = blockIdx.x * 4 + wave;
    if (n >= M) return;
    float acc = 0.f;
    for (int k = 0; k < H_DIM; k++) acc += h[n * H_DIM + k] * cf1[k * F_DIM + lane];
    x[n * F_DIM + lane] = acc;
}

// ---------------- edge filter: table lookup ----------------
__global__ __launch_bounds__(256) void k_edge_s(const int4* edat, const float* x,
                                                const float* __restrict__ wtab,
                                                float* agg) {
    int t = threadIdx.x, wave = t >> 6, lane = t & 63;
    int p0 = (blockIdx.x * 4 + wave) * EPW2;
    int curDst = -1;
    float acc = 0.f;
    for (int ee = 0; ee < EPW2; ee++) {
        int4 ed = edat[p0 + ee];
        int sI = ed.x, dI = ed.y;
        float d = __int_as_float(ed.z);
        float s = d * INV_DD;
        int b0 = min((int)s, NB - 2);
        float fr = s - b0;
        float w0 = wtab[b0 * F_DIM + lane];
        float w1 = wtab[(b0 + 1) * F_DIM + lane];
        float w = w0 + fr * (w1 - w0);
        float contrib = x[sI * F_DIM + lane] * w;
        if (dI != curDst) {
            if (curDst >= 0) atomicAdd(&agg[curDst * F_DIM + lane], acc);
            acc = 0.f;
            curDst = dI;
        }
        acc += contrib;
    }
    if (curDst >= 0) atomicAdd(&agg[curDst * F_DIM + lane], acc);
}

// ---------------- out = base + ssp(agg@cf2w + cf2b) @ lw + lb ----------------
__global__ __launch_bounds__(256) void k_update(const float* __restrict__ agg, const float* __restrict__ base,
                                                const float* cf2w, const float* cf2b,
                                                const float* lw, const float* lb,
                                                float* out, int M) {
    __shared__ float tbuf[4][H_DIM];
    int wave = threadIdx.x >> 6, lane = threadIdx.x & 63;
    int n = blockIdx.x * 4 + wave;
    float t0 = cf2b[lane], t1 = cf2b[lane + 64];
    if (n < M) {
        for (int f = 0; f < F_DIM; f++) {
            float a = agg[n * F_DIM + f];
            t0 += a * cf2w[f * H_DIM + lane];
            t1 += a * cf2w[f * H_DIM + lane + 64];
        }
    }
    tbuf[wave][lane] = ssp_f(t0);
    tbuf[wave][lane + 64] = ssp_f(t1);
    __syncthreads();
    if (n < M) {
        float o0 = lb[lane], o1 = lb[lane + 64];
        const float4* t4v = (const float4*)tbuf[wave];
        #pragma unroll
        for (int kk = 0; kk < 32; kk++) {
            float4 tq = t4v[kk];
            int k4 = kk * 4;
            o0 += tq.x * lw[(k4 + 0) * H_DIM + lane];
            o1 += tq.x * lw[(k4 + 0) * H_DIM + lane + 64];
            o0 += tq.y * lw[(k4 + 1) * H_DIM + lane];
            o1 += tq.y * lw[(k4 + 1) * H_DIM + lane + 64];
            o0 += tq.z * lw[(k4 + 2) * H_DIM + lane];
            o1 += tq.z * lw[(k4 + 2) * H_DIM + lane + 64];
            o0 += tq.w * lw[(k4 + 3) * H_DIM + lane];
            o1 += tq.w * lw[(k4 + 3) * H_DIM + lane + 64];
        }
        out[n * H_DIM + lane]      = base[n * H_DIM + lane] + o0;
        out[n * H_DIM + lane + 64] = base[n * H_DIM + lane + 64] + o1;
    }
}

// ---------------- node scores (exact: feeds top-K) ----------------
__global__ __launch_bounds__(256) void k_scores(const float* h_local,
                                                const float* msw1, const float* msb1,
                                                const float* msw2, const float* msb2,
                                                float* scores) {
    int n = blockIdx.x * 256 + threadIdx.x;
    if (n >= N_ATOMS) return;
    float hs[S_DIM];
    for (int s = 0; s < S_DIM; s++) hs[s] = h_local[n * H_DIM + s];
    float sc = msb2[0];
    for (int j = 0; j < MH_DIM; j++) {
        float v = msb1[j];
        for (int s = 0; s < S_DIM; s++) v += hs[s] * msw1[s * MH_DIM + j];
        sc += fmaxf(v, 0.f) * msw2[j];
    }
    scores[n] = sc;
}

// ---------------- parallel exact rank ----------------
__global__ __launch_bounds__(256) void k_rank(const float* scores, int* rank) {
    __shared__ float s[N_ATOMS];
    __shared__ int pc[16][17];
    int t = threadIdx.x;
    for (int i = t; i < N_ATOMS; i += 256) s[i] = scores[i];
    __syncthreads();
    int ii = t & 15, chunk = t >> 4;
    int i = blockIdx.x * 16 + ii;
    float si = s[i];
    int cnt = 0;
    int j0 = chunk * (N_ATOMS / 16);
    #pragma unroll 4
    for (int j = j0; j < j0 + N_ATOMS / 16; j++) {
        float sj = s[j];
        cnt += (sj > si) || (sj == si && j < i);
    }
    pc[chunk][ii] = cnt;
    __syncthreads();
    if (chunk == 0) {
        int r = 0;
        #pragma unroll
        for (int c = 0; c < 16; c++) r += pc[c][ii];
        rank[i] = r;
    }
}

// ---------------- selection, prefix, midx, m ----------------
__global__ __launch_bounds__(1024) void k_select(const float* scores, const int* rank,
                                                 int* is_m, int* invg, int* midx, float* m) {
    __shared__ int flag[N_ATOMS];
    __shared__ int bufA[N_ATOMS], bufB[N_ATOMS];
    __shared__ float kth;
    int t = threadIdx.x;
    for (int i = t; i < N_ATOMS; i += 1024) {
        int f = rank[i] < K_TOP;
        flag[i] = f;
        bufA[i] = f;
        if (rank[i] == K_TOP - 1) kth = scores[i];
    }
    __syncthreads();
    int* in = bufA;
    int* out = bufB;
    for (int d = 1; d < N_ATOMS; d <<= 1) {
        for (int i = t; i < N_ATOMS; i += 1024) out[i] = in[i] + (i >= d ? in[i - d] : 0);
        __syncthreads();
        int* tmp = in; in = out; out = tmp;
    }
    float kv = kth;
    for (int i = t; i < N_ATOMS; i += 1024) {
        int f = flag[i];
        int pos = in[i] - f;
        is_m[i] = f;
        invg[i] = f ? pos : 0;
        if (f) midx[pos] = i;
        m[i] = sigm_f(scores[i] - kv + 1e-6f);
    }
}

// ---------------- gather h_m / pos_m ----------------
__global__ __launch_bounds__(256) void k_gather(const int* midx, const float* h_local,
                                                const float* pos, float* h_m, float* pos_m) {
    int i = blockIdx.x * 256 + threadIdx.x;
    int k = i >> 7, c = i & 127;
    int n = midx[k];
    h_m[i] = h_local[n * H_DIM + c];
    if (c < 3) pos_m[k * 3 + c] = pos[n * 3 + c];
}

// ---------------- adjacency + valid-edge list ----------------
__global__ __launch_bounds__(256) void k_adj(const int* src, const int* dst, const int* is_m,
                                             const int* invg, unsigned char* adj,
                                             int* velist, int* nve) {
    int e = blockIdx.x * 256 + threadIdx.x;
    int s = src[e], d = dst[e];
    bool valid = is_m[s] && is_m[d];
    if (valid) adj[invg[s] * K_TOP + invg[d]] = 1;
    unsigned long long mask = __ballot(valid);
    int lane = threadIdx.x & 63;
    int cnt = __popcll(mask);
    int base = 0;
    if (lane == 0 && cnt) base = atomicAdd(nve, cnt);
    base = __shfl(base, 0);
    if (valid) velist[base + __popcll(mask & ((1ull << lane) - 1))] = e;
}

// ---------------- per-valid-edge packed data {sm, dm, dist} ----------------
__global__ __launch_bounds__(256) void k_vdat(const int* velist, const int* nve,
                                              const int* src, const int* dst, const int* invg,
                                              const float* pos_m, int4* vdat) {
    int n = nve[0];
    for (int p = blockIdx.x * 256 + threadIdx.x; p < n; p += gridDim.x * 256) {
        int e = velist[p];
        int sm = invg[src[e]];
        int dm = invg[dst[e]];
        float dx = pos_m[sm * 3 + 0] - pos_m[dm * 3 + 0];
        float dy = pos_m[sm * 3 + 1] - pos_m[dm * 3 + 1];
        float dz = pos_m[sm * 3 + 2] - pos_m[dm * 3 + 2];
        float dist = sqrtf(dx * dx + dy * dy + dz * dz + 1e-12f);
        vdat[p] = make_int4(sm, dm, __float_as_int(dist), 0);
    }
}

// ---------------- q/k projections ----------------
__global__ __launch_bounds__(256) void k_qk(const float* h_m, const float* wq,
                                            const float* wk, float* qm, float* km) {
    int gid = blockIdx.x * 256 + threadIdx.x;
    int r = gid >> 5, t = gid & 31;
    const float* w = (t < 16) ? wq : wk;
    int c = t & 15;
    float acc = 0.f;
    for (int s = 0; s < S_DIM; s++) acc += h_m[r * H_DIM + s] * w[s * S_DIM + c];
    if (t < 16) qm[r * S_DIM + c] = acc; else km[r * S_DIM + c] = acc;
}

// ---------------- attention softmax -> Av mask (exact) ----------------
__global__ __launch_bounds__(256) void k_attn(const float* qm, const float* km,
                                              const unsigned char* adj, unsigned char* Av) {
    __shared__ float lrow[K_TOP];
    __shared__ float red[256];
    int i = blockIdx.x, t = threadIdx.x;
    float q[S_DIM];
    for (int s = 0; s < S_DIM; s++) q[s] = qm[i * S_DIM + s];
    for (int j = t; j < K_TOP; j += 256) {
        float acc = 0.f;
        for (int s = 0; s < S_DIM; s++) acc += q[s] * km[j * S_DIM + s];
        lrow[j] = acc * 0.25f;
    }
    __syncthreads();
    float mx = -1e30f;
    for (int j = t; j < K_TOP; j += 256) mx = fmaxf(mx, lrow[j]);
    red[t] = mx; __syncthreads();
    for (int o = 128; o > 0; o >>= 1) { if (t < o) red[t] = fmaxf(red[t], red[t + o]); __syncthreads(); }
    mx = red[0]; __syncthreads();
    float sum = 0.f;
    for (int j = t; j < K_TOP; j += 256) sum += expf(lrow[j] - mx);
    red[t] = sum; __syncthreads();
    for (int o = 128; o > 0; o >>= 1) { if (t < o) red[t] += red[t + o]; __syncthreads(); }
    float inv_s = 1.f / red[0];
    for (int j = t; j < K_TOP; j += 256) {
        float a = expf(lrow[j] - mx) * inv_s;
        Av[i * K_TOP + j] = (a > LAMBDA) && (!adj[i * K_TOP + j]) && (i != j);
    }
}

// ---------------- deterministic j-major pair compaction ----------------
__global__ __launch_bounds__(256) void k_pcount(const unsigned char* Av, int* bcount) {
    __shared__ int wsum[4];
    int idx = blockIdx.x * 256 + threadIdx.x;
    int j = idx >> 9, i = idx & (K_TOP - 1);
    bool act = Av[i * K_TOP + j] != 0;
    unsigned long long mask = __ballot(act);
    int lane = threadIdx.x & 63, wave = threadIdx.x >> 6;
    if (lane == 0) wsum[wave] = __popcll(mask);
    __syncthreads();
    if (threadIdx.x == 0) bcount[blockIdx.x] = wsum[0] + wsum[1] + wsum[2] + wsum[3];
}

__global__ __launch_bounds__(1024) void k_pscan(const int* bcount, int* boffset, int* total) {
    __shared__ int bufA[1024], bufB[1024];
    int t = threadIdx.x;
    bufA[t] = bcount[t];
    __syncthreads();
    int* in = bufA;
    int* out = bufB;
    for (int d = 1; d < 1024; d <<= 1) {
        out[t] = in[t] + (t >= d ? in[t - d] : 0);
        __syncthreads();
        int* tmp = in; in = out; out = tmp;
    }
    boffset[t] = in[t] - bcount[t];
    if (t == 1023) total[0] = in[1023];
}

__global__ __launch_bounds__(256) void k_pscatter(const unsigned char* Av, const int* boffset,
                                                  unsigned int* plist) {
    __shared__ int wsum[4], woff[4];
    int idx = blockIdx.x * 256 + threadIdx.x;
    int j = idx >> 9, i = idx & (K_TOP - 1);
    bool act = Av[i * K_TOP + j] != 0;
    unsigned long long mask = __ballot(act);
    int lane = threadIdx.x & 63, wave = threadIdx.x >> 6;
    if (lane == 0) wsum[wave] = __popcll(mask);
    __syncthreads();
    if (threadIdx.x == 0) {
        int s = 0;
        for (int w = 0; w < 4; w++) { woff[w] = s; s += wsum[w]; }
    }
    __syncthreads();
    if (act) {
        int pos = boffset[blockIdx.x] + woff[wave] + __popcll(mask & ((1ull << lane) - 1));
        plist[pos] = ((unsigned int)j << 9) | (unsigned int)i;
    }
}

// ---------------- packed pair data for score: {key, dd} (dist from pos_m) ----------------
__global__ __launch_bounds__(256) void k_sdata(const unsigned int* plist, const int* npairs,
                                               const float* pos_m, float2* sd) {
    int n = npairs[0];
    for (int p = blockIdx.x * 256 + threadIdx.x; p < n; p += gridDim.x * 256) {
        unsigned int key = plist[p];
        int j = key >> 9, i = key & (K_TOP - 1);
        float dx = pos_m[i * 3 + 0] - pos_m[j * 3 + 0];
        float dy = pos_m[i * 3 + 1] - pos_m[j * 3 + 1];
        float dz = pos_m[i * 3 + 2] - pos_m[j * 3 + 2];
        float dd = sqrtf(dx * dx + dy * dy + dz * dz + 1e-12f);
        sd[p] = make_float2(__uint_as_float(key), dd);
    }
}

// ---------------- packed pair data for aggd: {key, dd, dec} ----------------
__global__ __launch_bounds__(256) void k_pdat(const unsigned int* plist, const int* npairs,
                                              const float* pos_m, const float* decay, float4* pd) {
    int n = npairs[0];
    for (int p = blockIdx.x * 256 + threadIdx.x; p < n; p += gridDim.x * 256) {
        unsigned int key = plist[p];
        int j = key >> 9, i = key & (K_TOP - 1);
        float dx = pos_m[i * 3 + 0] - pos_m[j * 3 + 0];
        float dy = pos_m[i * 3 + 1] - pos_m[j * 3 + 1];
        float dz = pos_m[i * 3 + 2] - pos_m[j * 3 + 2];
        float dd = sqrtf(dx * dx + dy * dy + dz * dz + 1e-12f);
        pd[p] = make_float4(__uint_as_float(key), dd, decay[i * K_TOP + j], 0.f);
    }
}

// ---------------- hi = h_m@Wi, hj = h_m@Wj ----------------
__global__ __launch_bounds__(256) void k_hij(const float* h_m, const float* aw1,
                                             float* hi, float* hj) {
    int wave = threadIdx.x >> 6, lane = threadIdx.x & 63;
    int idx = blockIdx.x * 4 + wave;
    int which = idx >> 9;
    int r = idx & (K_TOP - 1);
    const float* W = aw1 + which * H_DIM * H_DIM;
    float o0 = 0.f, o1 = 0.f;
    for (int k = 0; k < H_DIM; k++) {
        float hv = h_m[r * H_DIM + k];
        o0 += hv * W[k * H_DIM + lane];
        o1 += hv * W[k * H_DIM + lane + 64];
    }
    float* out = which ? hj : hi;
    out[r * H_DIM + lane] = o0;
    out[r * H_DIM + lane + 64] = o1;
}

// ---------------- per-pair attention scores: ztabS lookup ----------------
__global__ __launch_bounds__(256) void k_score_p(const float2* sd, const int* npairs,
                                                 const float* hi, const float* hj,
                                                 const float* __restrict__ ztabS,
                                                 const float* ab1, const float* aw2, const float* ab2,
                                                 float* sbuf) {
    int t = threadIdx.x, wave = t >> 6, lane = t & 63;
    float ab0 = ab1[lane], ab1v = ab1[lane + 64];
    float aw0 = aw2[lane], aw1v = aw2[lane + 64];
    float b2 = ab2[0];
    int n = npairs[0];
    int wid = blockIdx.x * 4 + wave;
    int nw = gridDim.x * 4;
    for (int p = wid; p < n; p += nw) {
        float2 s2 = sd[p];
        unsigned int key = __float_as_uint(s2.x);
        float dd = s2.y;
        int j = key >> 9, i = key & (K_TOP - 1);
        int ij = i * K_TOP + j;
        float s = dd * INV_DD;
        int b0 = min((int)s, NB - 2);
        float fr = s - b0;
        const float* r0 = ztabS + b0 * H_DIM;
        const float* r1 = r0 + H_DIM;
        float z0a = r0[lane],      z1a = r1[lane];
        float z0b = r0[lane + 64], z1b = r1[lane + 64];
        float zs0 = z0a + fr * (z1a - z0a);
        float zs1 = z0b + fr * (z1b - z0b);
        float v0 = hi[i * H_DIM + lane] + hj[j * H_DIM + lane] + ab0 + zs0;
        float v1 = hi[i * H_DIM + lane + 64] + hj[j * H_DIM + lane + 64] + ab1v + zs1;
        float pv = fmaxf(v0, 0.f) * aw0 + fmaxf(v1, 0.f) * aw1v;
        for (int o = 1; o < 64; o <<= 1) pv += __shfl_xor(pv, o);
        if (lane == 0) sbuf[ij] = pv + b2;
    }
}

// ---------------- row softmax (Av-guarded) -> decay (exact) ----------------
__global__ __launch_bounds__(256) void k_decay(const float* sbuf, const unsigned char* Av, float* decay) {
    __shared__ float srow[K_TOP];
    __shared__ float red[256];
    int i = blockIdx.x, t = threadIdx.x;
    for (int j = t; j < K_TOP; j += 256)
        srow[j] = Av[i * K_TOP + j] ? sbuf[i * K_TOP + j] : -1e9f;
    __syncthreads();
    float mx = -1e30f;
    for (int j = t; j < K_TOP; j += 256) mx = fmaxf(mx, srow[j]);
    red[t] = mx; __syncthreads();
    for (int o = 128; o > 0; o >>= 1) { if (t < o) red[t] = fmaxf(red[t], red[t + o]); __syncthreads(); }
    mx = red[0]; __syncthreads();
    float sum = 0.f;
    for (int j = t; j < K_TOP; j += 256) sum += (srow[j] > -5e8f) ? expf(srow[j] - mx) : 0.f;
    red[t] = sum; __syncthreads();
    for (int o = 128; o > 0; o >>= 1) { if (t < o) red[t] += red[t + o]; __syncthreads(); }
    float s_total = red[0];
    float inv_s = (s_total > 0.f) ? 1.f / s_total : 0.f;
    for (int j = t; j < K_TOP; j += 256)
        decay[i * K_TOP + j] = (srow[j] > -5e8f) ? expf(srow[j] - mx) * inv_s : 0.f;
}

// ---------------- agg_d: z1 table + second layer, 2-pair pipeline ----------------
__global__ __launch_bounds__(256) void k_aggd_p2(const float4* pd, const int* npairs,
                                                 const float* xm,
                                                 const float* __restrict__ z1tab,
                                                 const float* mb1,
                                                 const float* mw2, const float* mb2,
                                                 float* agg_m) {
    __shared__ float tbuf[4][2][F_DIM];
    int t = threadIdx.x, wave = t >> 6, lane = t & 63;
    float w2r[F_DIM];
    #pragma unroll
    for (int k = 0; k < F_DIM; k++) w2r[k] = mw2[k * F_DIM + lane];
    float b1 = mb1[lane], b2v = mb2[lane];
    int n = npairs[0];
    int nchunks = (n + PCHUNK - 1) / PCHUNK;
    int wid = blockIdx.x * 4 + wave;
    int nw = gridDim.x * 4;
    for (int c = wid; c < nchunks; c += nw) {
        int p0 = c * PCHUNK;
        int p1 = min(p0 + PCHUNK, n);
        int curJ = -1;
        float acc = 0.f;
        for (int p = p0; p < p1; p += 2) {
            bool hasB = (p + 1) < p1;
            float4 qA = pd[p];
            float4 qB = pd[hasB ? p + 1 : p];
            unsigned int keyA = __float_as_uint(qA.x);
            unsigned int keyB = __float_as_uint(qB.x);
            float ddA = qA.y, decA = qA.z;
            float ddB = qB.y, decB = qB.z;
            int jA = keyA >> 9, iA = keyA & (K_TOP - 1);
            int jB = keyB >> 9, iB = keyB & (K_TOP - 1);
            float sA = ddA * INV_DD, sB = ddB * INV_DD;
            int bA = min((int)sA, NB - 2), bB = min((int)sB, NB - 2);
            float frA = sA - bA, frB = sB - bB;
            float zA0 = z1tab[bA * F_DIM + lane];
            float zA1 = z1tab[(bA + 1) * F_DIM + lane];
            float zB0 = z1tab[bB * F_DIM + lane];
            float zB1 = z1tab[(bB + 1) * F_DIM + lane];
            float z1A = zA0 + frA * (zA1 - zA0);
            float z1B = zB0 + frB * (zB1 - zB0);
            float tvA = ssp_fast(decA * z1A + b1);
            float tvB = ssp_fast(decB * z1B + b1);
            tbuf[wave][0][lane] = tvA;
            tbuf[wave][1][lane] = tvB;
            float wA = b2v, wB = 0.f;
            const float4* tA4 = (const float4*)tbuf[wave][0];
            const float4* tB4 = (const float4*)tbuf[wave][1];
            #pragma unroll
            for (int kk = 0; kk < 16; kk++) {
                float4 ta = tA4[kk];
                float4 tb = tB4[kk];
                wA += ta.x * w2r[4 * kk + 0];
                wB += tb.x * w2r[4 * kk + 0];
                wA += ta.y * w2r[4 * kk + 1];
                wB += tb.y * w2r[4 * kk + 1];
                wA += ta.z * w2r[4 * kk + 2];
                wB += tb.z * w2r[4 * kk + 2];
                wA += ta.w * w2r[4 * kk + 3];
                wB += tb.w * w2r[4 * kk + 3];
            }
            wB += b2v;
            float contribA = xm[iA * F_DIM + lane] * wA * ccut_fast(ddA);
            if (jA != curJ) {
                if (curJ >= 0) atomicAdd(&agg_m[curJ * F_DIM + lane], acc);
                acc = 0.f;
                curJ = jA;
            }
            acc += contribA;
            if (hasB) {
                float contribB = xm[iB * F_DIM + lane] * wB * ccut_fast(ddB);
                if (jB != curJ) {
                    atomicAdd(&agg_m[curJ * F_DIM + lane], acc);
                    acc = 0.f;
                    curJ = jB;
                }
                acc += contribB;
            }
        }
        if (curJ >= 0) atomicAdd(&agg_m[curJ * F_DIM + lane], acc);
    }
}

// ---------------- valid-edge filter: table lookup ----------------
__global__ __launch_bounds__(256) void k_aggs_p(const int4* vdat, const int* nve,
                                                const float* xm,
                                                const float* __restrict__ wtab,
                                                float* agg_m) {
    int t = threadIdx.x, wave = t >> 6, lane = t & 63;
    int n = nve[0];
    int wid = blockIdx.x * 4 + wave;
    int nw = gridDim.x * 4;
    for (int p = wid; p < n; p += nw) {
        int4 vd = vdat[p];
        int sm = vd.x, dm = vd.y;
        float d = __int_as_float(vd.z);
        float s = d * INV_DD;
        int b0 = min((int)s, NB - 2);
        float fr = s - b0;
        float w0 = wtab[b0 * F_DIM + lane];
        float w1 = wtab[(b0 + 1) * F_DIM + lane];
        float w = w0 + fr * (w1 - w0);
        atomicAdd(&agg_m[dm * F_DIM + lane], xm[sm * F_DIM + lane] * w);
    }
}

// ---------------- blend ----------------
__global__ __launch_bounds__(256) void k_blend(const float* h_local, const float* h_hier,
                                               const int* is_m, const int* invg, const float* m,
                                               float* h_out) {
    int idx = blockIdx.x * 256 + threadIdx.x;
    int n = idx >> 7, c = idx & 127;
    float mm = m[n];
    float hh = is_m[n] ? h_hier[invg[n] * H_DIM + c] : 0.f;
    h_out[idx] = (1.f - mm) * h_local[idx] + mm * hh;
}

// ---------------- parallel segment-sum pooling ----------------
__global__ __launch_bounds__(256) void k_pool(const float* __restrict__ h, const int* __restrict__ batch,
                                              float* pooled) {
    int c = threadIdx.x & 127, a = threadIdx.x >> 7;
    int n0 = blockIdx.x * 64;
    float acc = 0.f;
    int cur = batch[n0 + a];
    for (int i = a; i < 64; i += 2) {
        int n = n0 + i;
        int b = batch[n];
        if (b != cur) { atomicAdd(&pooled[cur * H_DIM + c], acc); acc = 0.f; cur = b; }
        acc += h[n * H_DIM + c];
    }
    atomicAdd(&pooled[cur * H_DIM + c], acc);
}

// ---------------- predict MLP ----------------
__global__ __launch_bounds__(128) void k_pred2(const float* pooled,
                                               const float* w1, const float* b1,
                                               const float* w2, const float* b2,
                                               void* outv, const int* flag) {
    __shared__ float c64[64];
    int b = blockIdx.x, t = threadIdx.x;
    if (t < 64) {
        float v = b1[t];
        for (int k = 0; k < H_DIM; k++) v += pooled[b * H_DIM + k] * w1[k * 64 + t];
        c64[t] = v * sigm_f(v);
    }
    __syncthreads();
    if (t == 0) {
        float o = b2[0];
        for (int k = 0; k < 64; k++) o += c64[k] * w2[k];
        if (flag[0]) ((float*)outv)[b] = o;
        else ((__hip_bfloat16*)outv)[b] = __float2bfloat16(o);
    }
}

extern "C" void kernel_launch(void* const* d_in, const int* in_sizes, int n_in,
                              void* d_out, int out_size, void* d_ws, size_t ws_size,
                              hipStream_t stream) {
    (void)n_in; (void)out_size; (void)ws_size;
    const int* atoms = (const int*)d_in[0];
    const int* src = (const int*)d_in[2];
    const int* dst = (const int*)d_in[3];
    const int* batch = (const int*)d_in[4];

    float* W = (float*)d_ws;
    int* dflag = (int*)W; W += 16;
    int* counters = (int*)W; W += 16;  // [0]=npairs, [1]=nve

    static const int fidx[25] = {1,5,6,7,8,9,10,11,12,13,14,15,16,17,18,19,20,21,22,23,24,25,26,27,28};
    float* fin[29];
    ConvArgs ca;
    float* convBase = W;
    int off = 0;
    for (int q = 0; q < 25; q++) {
        int i = fidx[q];
        ca.p[q] = d_in[i];
        ca.off[q] = off;
        fin[i] = convBase + off;
        off += in_sizes[i];
    }
    ca.off[25] = off;
    W += off;

    k_detect<<<1, 256, 0, stream>>>((const unsigned short*)d_in[5], in_sizes[5], dflag);
    k_convert_all<<<(off + 255) / 256, 256, 0, stream>>>(ca, convBase, dflag);

    const float* posf = fin[1];
    const float* embf = fin[5];

    float* h      = W; W += N_ATOMS * H_DIM;
    float* h_loc  = W; W += N_ATOMS * H_DIM;
    float* xbuf   = W; W += N_ATOMS * F_DIM;
    float* aggbuf = W; W += N_ATOMS * F_DIM;
    float* scores = W; W += N_ATOMS;
    float* mbuf   = W; W += N_ATOMS;
    float* h_m    = W; W += K_TOP * H_DIM;
    float* pos_m  = W; W += K_TOP * 3;
    float* xm     = W; W += K_TOP * F_DIM;
    float* qm     = W; W += K_TOP * S_DIM;
    float* km     = W; W += K_TOP * S_DIM;
    float* decay  = W; W += K_TOP * K_TOP;
    float* sbuf   = W; W += K_TOP * K_TOP;
    float* hi     = W; W += K_TOP * H_DIM;
    float* hj     = W; W += K_TOP * H_DIM;
    float* agg_m  = W; W += K_TOP * F_DIM;
    float* h_hier = W; W += K_TOP * H_DIM;
    float* pooled = W; W += B_BATCH * H_DIM;
    float* z1tab  = W; W += NB * F_DIM;
    float* wtab   = W; W += NB * F_DIM;
    float* ztabS  = W; W += NB * H_DIM;
    int* rankb  = (int*)W; W += N_ATOMS;
    int* is_m   = (int*)W; W += N_ATOMS;
    int* invg   = (int*)W; W += N_ATOMS;
    int* midx   = (int*)W; W += K_TOP;
    unsigned int* plist = (unsigned int*)W; W += K_TOP * K_TOP;
    int* velist = (int*)W; W += E_EDGES;
    int* esorted = (int*)W; W += E_EDGES;
    int* ehist  = (int*)W; W += N_ATOMS;
    int* ebase  = (int*)W; W += N_ATOMS;
    int* ecur   = (int*)W; W += N_ATOMS;
    int* bcount = (int*)W; W += 1024;
    int* boffset = (int*)W; W += 1024;
    int4* edat  = (int4*)W; W += E_EDGES * 4;
    int4* vdat  = (int4*)W; W += E_EDGES * 4;
    float2* sd  = (float2*)W; W += K_TOP * K_TOP * 2;
    float4* pd  = (float4*)W; W += K_TOP * K_TOP * 4;
    unsigned char* adj = (unsigned char*)W; W += (K_TOP * K_TOP) / 4;
    unsigned char* Av  = (unsigned char*)W; W += (K_TOP * K_TOP) / 4;

    // one-time: counting-sort edges by dst + packed edge data
    (void)hipMemsetAsync(ehist, 0, N_ATOMS * sizeof(int), stream);
    k_ehist<<<E_EDGES / 256, 256, 0, stream>>>(dst, ehist);
    k_escan<<<1, 1024, 0, stream>>>(ehist, ebase, ecur);
    k_escatter<<<E_EDGES / 256, 256, 0, stream>>>(dst, ecur, esorted);
    k_edat<<<E_EDGES / 256, 256, 0, stream>>>(esorted, src, dst, posf, edat);

    k_embed<<<(N_ATOMS * H_DIM) / 256, 256, 0, stream>>>(atoms, embf, h);

    for (int l = 0; l < L_LAYERS; l++) {
        const float* mw1 = fin[6]  + l * G_DIM * F_DIM;
        const float* mb1 = fin[7]  + l * F_DIM;
        const float* mw2 = fin[8]  + l * F_DIM * F_DIM;
        const float* mb2 = fin[9]  + l * F_DIM;
        const float* cf1 = fin[10] + l * H_DIM * F_DIM;
        const float* cf2w = fin[11] + l * F_DIM * H_DIM;
        const float* cf2b = fin[12] + l * H_DIM;
        const float* lw  = fin[13] + l * H_DIM * H_DIM;
        const float* lb  = fin[14] + l * H_DIM;
        const float* aw1 = fin[15] + l * (2 * H_DIM + G_DIM) * H_DIM;
        const float* ab1 = fin[16] + l * H_DIM;
        const float* aw2 = fin[17] + l * H_DIM;
        const float* ab2 = fin[18] + l;
        const float* msw1 = fin[19] + l * S_DIM * MH_DIM;
        const float* msb1 = fin[20] + l * MH_DIM;
        const float* msw2 = fin[21] + l * MH_DIM;
        const float* msb2 = fin[22] + l;
        const float* wq  = fin[23] + l * S_DIM * S_DIM;
        const float* wk  = fin[24] + l * S_DIM * S_DIM;

        k_ftab<<<NB, 128, 0, stream>>>(mw1, mb1, mw2, mb2, aw1, z1tab, wtab, ztabS);
        k_x<<<N_ATOMS / 4, 256, 0, stream>>>(h, cf1, xbuf, N_ATOMS);
        (void)hipMemsetAsync(aggbuf, 0, N_ATOMS * F_DIM * sizeof(float), stream);
        k_edge_s<<<E_EDGES / (4 * EPW2), 256, 0, stream>>>(edat, xbuf, wtab, aggbuf);
        k_update<<<N_ATOMS / 4, 256, 0, stream>>>(aggbuf, h, cf2w, cf2b, lw, lb, h_loc, N_ATOMS);
        k_scores<<<N_ATOMS / 256, 256, 0, stream>>>(h_loc, msw1, msb1, msw2, msb2, scores);
        k_rank<<<N_ATOMS / 16, 256, 0, stream>>>(scores, rankb);
        k_select<<<1, 1024, 0, stream>>>(scores, rankb, is_m, invg, midx, mbuf);
        k_gather<<<(K_TOP * H_DIM) / 256, 256, 0, stream>>>(midx, h_loc, posf, h_m, pos_m);
        k_x<<<K_TOP / 4, 256, 0, stream>>>(h_m, cf1, xm, K_TOP);
        (void)hipMemsetAsync(adj, 0, K_TOP * K_TOP, stream);
        (void)hipMemsetAsync(counters, 0, 2 * sizeof(int), stream);
        k_adj<<<E_EDGES / 256, 256, 0, stream>>>(src, dst, is_m, invg, adj, velist, counters + 1);
        k_vdat<<<256, 256, 0, stream>>>(velist, counters + 1, src, dst, invg, pos_m, vdat);
        k_qk<<<(K_TOP * 32) / 256, 256, 0, stream>>>(h_m, wq, wk, qm, km);
        k_attn<<<K_TOP, 256, 0, stream>>>(qm, km, adj, Av);
        k_pcount<<<(K_TOP * K_TOP) / 256, 256, 0, stream>>>(Av, bcount);
        k_pscan<<<1, 1024, 0, stream>>>(bcount, boffset, counters);
        k_pscatter<<<(K_TOP * K_TOP) / 256, 256, 0, stream>>>(Av, boffset, plist);
        k_sdata<<<512, 256, 0, stream>>>(plist, counters, pos_m, sd);
        k_hij<<<(2 * K_TOP) / 4, 256, 0, stream>>>(h_m, aw1, hi, hj);
        k_score_p<<<1024, 256, 0, stream>>>(sd, counters, hi, hj, ztabS, ab1, aw2, ab2, sbuf);
        k_decay<<<K_TOP, 256, 0, stream>>>(sbuf, Av, decay);
        k_pdat<<<512, 256, 0, stream>>>(plist, counters, pos_m, decay, pd);
        (void)hipMemsetAsync(agg_m, 0, K_TOP * F_DIM * sizeof(float), stream);
        k_aggd_p2<<<1024, 256, 0, stream>>>(pd, counters, xm, z1tab, mb1, mw2, mb2, agg_m);
        k_aggs_p<<<256, 256, 0, stream>>>(vdat, counters + 1, xm, wtab, agg_m);
        k_update<<<K_TOP / 4, 256, 0, stream>>>(agg_m, h_m, cf2w, cf2b, lw, lb, h_hier, K_TOP);
        k_blend<<<(N_ATOMS * H_DIM) / 256, 256, 0, stream>>>(h_loc, h_hier, is_m, invg, mbuf, h);
    }

    (void)hipMemsetAsync(pooled, 0, B_BATCH * H_DIM * sizeof(float), stream);
    k_pool<<<N_ATOMS / 64, 256, 0, stream>>>(h, batch, pooled);
    k_pred2<<<B_BATCH, 128, 0, stream>>>(pooled, fin[25], fin[26], fin[27], fin[28], d_out, dflag);
}

// Round 18
// 368.935 us; speedup vs baseline: 4.3772x; 1.3199x over previous
//
#include <hip/hip_runtime.h>
#include <hip/hip_bf16.h>
#include <math.h>

#define N_ATOMS 2048
#define E_EDGES 65536
#define B_BATCH 8
#define H_DIM 128
#define G_DIM 50
#define F_DIM 64
#define S_DIM 16
#define MH_DIM 32
#define K_TOP 512
#define L_LAYERS 2
#define EPW2 8
#define PCHUNK 8
#define NB 4096
#define DD 0.015625f        // 64/4096
#define INV_DD 64.0f

static constexpr float STEP   = 10.0f / 49.0f;
static constexpr float COEFF  = -12.005f;
static constexpr float PI10   = 0.31415926535897931f;
static constexpr float LN2    = 0.69314718055994531f;
static constexpr float LAMBDA = 0.002f;

#define DEV static __device__ __forceinline__

DEV float ssp_f(float x) { return fmaxf(x, 0.f) + log1pf(expf(-fabsf(x))) - LN2; }
DEV float ccut_f(float d) { return 0.5f * (cosf(d * PI10) + 1.f); }
DEV float sigm_f(float x) { return 1.f / (1.f + expf(-x)); }
DEV float ssp_fast(float x) { return fmaxf(x, 0.f) + __logf(1.f + __expf(-fabsf(x))) - LN2; }
DEV float ccut_fast(float d) { return 0.5f * (__cosf(d * PI10) + 1.f); }

// ---------------- dtype detect ----------------
__global__ __launch_bounds__(256) void k_detect(const unsigned short* raw, int n, int* flag) {
    __shared__ int any;
    if (threadIdx.x == 0) any = 0;
    __syncthreads();
    for (int i = threadIdx.x; i < n; i += 256) {
        unsigned int bits = ((unsigned int)raw[i]) << 16;
        float f = __uint_as_float(bits);
        if (!(fabsf(f) <= 1e10f)) any = 1;
    }
    __syncthreads();
    if (threadIdx.x == 0) flag[0] = any;
}

// ---------------- fused convert ----------------
struct ConvArgs {
    const void* p[25];
    int off[26];
};

__global__ __launch_bounds__(256) void k_convert_all(ConvArgs a, float* dst, const int* flag) {
    int i = blockIdx.x * 256 + threadIdx.x;
    int total = a.off[25];
    if (i >= total) return;
    int seg = 0;
    while (i >= a.off[seg + 1]) seg++;
    int k = i - a.off[seg];
    if (flag[0]) {
        dst[i] = ((const float*)a.p[seg])[k];
    } else {
        unsigned int bits = ((unsigned int)((const unsigned short*)a.p[seg])[k]) << 16;
        dst[i] = __uint_as_float(bits);
    }
}

// ---------------- edge counting-sort by dst ----------------
__global__ __launch_bounds__(256) void k_ehist(const int* dst, int* hist) {
    int e = blockIdx.x * 256 + threadIdx.x;
    atomicAdd(&hist[dst[e]], 1);
}

__global__ __launch_bounds__(1024) void k_escan(const int* hist, int* ebase, int* ecur) {
    __shared__ int bufA[N_ATOMS], bufB[N_ATOMS];
    int t = threadIdx.x;
    for (int i = t; i < N_ATOMS; i += 1024) bufA[i] = hist[i];
    __syncthreads();
    int* in = bufA;
    int* out = bufB;
    for (int d = 1; d < N_ATOMS; d <<= 1) {
        for (int i = t; i < N_ATOMS; i += 1024) out[i] = in[i] + (i >= d ? in[i - d] : 0);
        __syncthreads();
        int* tmp = in; in = out; out = tmp;
    }
    for (int i = t; i < N_ATOMS; i += 1024) {
        int ex = in[i] - hist[i];
        ebase[i] = ex;
        ecur[i] = ex;
    }
}

__global__ __launch_bounds__(256) void k_escatter(const int* dst, int* ecur, int* esorted) {
    int e = blockIdx.x * 256 + threadIdx.x;
    int pos = atomicAdd(&ecur[dst[e]], 1);
    esorted[pos] = e;
}

// ---------------- one-time packed edge data {src, dst, dist} ----------------
__global__ __launch_bounds__(256) void k_edat(const int* esorted, const int* src, const int* dst,
                                              const float* pos, int4* edat) {
    int p = blockIdx.x * 256 + threadIdx.x;
    int e = esorted[p];
    int s = src[e], d = dst[e];
    float dx = pos[s * 3 + 0] - pos[d * 3 + 0];
    float dy = pos[s * 3 + 1] - pos[d * 3 + 1];
    float dz = pos[s * 3 + 2] - pos[d * 3 + 2];
    float dist = sqrtf(dx * dx + dy * dy + dz * dz + 1e-12f);
    edat[p] = make_int4(s, d, __float_as_int(dist), 0);
}

// ---------------- per-layer filter tables (exact math, 4096 bins) ----------------
__global__ __launch_bounds__(128) void k_ftab(const float* mw1, const float* mb1,
                                              const float* mw2, const float* mb2,
                                              const float* aw1,
                                              float* z1tab, float* wtab, float* ztabS) {
    __shared__ float gs[G_DIM];
    __shared__ float tb[F_DIM];
    int b = blockIdx.x, t = threadIdx.x;
    float d = b * DD;
    if (t < G_DIM) { float u = d - t * STEP; gs[t] = expf(COEFF * u * u); }
    __syncthreads();
    const float* wd = aw1 + 2 * H_DIM * H_DIM;
    float zs = 0.f;
    for (int g = 0; g < G_DIM; g++) zs += gs[g] * wd[g * H_DIM + t];
    ztabS[b * H_DIM + t] = zs;
    if (t < F_DIM) {
        float z1 = 0.f;
        for (int g = 0; g < G_DIM; g++) z1 += gs[g] * mw1[g * F_DIM + t];
        z1tab[b * F_DIM + t] = z1;
        tb[t] = ssp_f(z1 + mb1[t]);
    }
    __syncthreads();
    if (t < F_DIM) {
        float w = mb2[t];
        for (int k = 0; k < F_DIM; k++) w += tb[k] * mw2[k * F_DIM + t];
        wtab[b * F_DIM + t] = w * ccut_f(d);
    }
}

// ---------------- embedding ----------------
__global__ __launch_bounds__(256) void k_embed(const int* atoms, const float* emb, float* h) {
    int i = blockIdx.x * 256 + threadIdx.x;
    int n = i >> 7, c = i & 127;
    h[i] = emb[atoms[n] * H_DIM + c];
}

// ---------------- x = h @ cf1 (+ zero agg buffer of same shape) ----------------
__global__ __launch_bounds__(256) void k_x(const float* __restrict__ h, const float* __restrict__ cf1,
                                           float* __restrict__ x, float* __restrict__ aggz, int M) {
    int wave = threadIdx.x >> 6, lane = threadIdx.x & 63;
    int n = blockIdx.x * 4 + wave;
    if (n >= M) return;
    float acc = 0.f;
    for (int k = 0; k < H_DIM; k++) acc += h[n * H_DIM + k] * cf1[k * F_DIM + lane];
    x[n * F_DIM + lane] = acc;
    aggz[n * F_DIM + lane] = 0.f;
}

// ---------------- edge filter: table lookup ----------------
__global__ __launch_bounds__(256) void k_edge_s(const int4* edat, const float* x,
                                                const float* __restrict__ wtab,
                                                float* agg) {
    int t = threadIdx.x, wave = t >> 6, lane = t & 63;
    int p0 = (blockIdx.x * 4 + wave) * EPW2;
    int curDst = -1;
    float acc = 0.f;
    for (int ee = 0; ee < EPW2; ee++) {
        int4 ed = edat[p0 + ee];
        int sI = ed.x, dI = ed.y;
        float d = __int_as_float(ed.z);
        float s = d * INV_DD;
        int b0 = min((int)s, NB - 2);
        float fr = s - b0;
        float w0 = wtab[b0 * F_DIM + lane];
        float w1 = wtab[(b0 + 1) * F_DIM + lane];
        float w = w0 + fr * (w1 - w0);
        float contrib = x[sI * F_DIM + lane] * w;
        if (dI != curDst) {
            if (curDst >= 0) atomicAdd(&agg[curDst * F_DIM + lane], acc);
            acc = 0.f;
            curDst = dI;
        }
        acc += contrib;
    }
    if (curDst >= 0) atomicAdd(&agg[curDst * F_DIM + lane], acc);
}

// ---------------- out = base + ssp(agg@cf2w + cf2b) @ lw + lb ----------------
__global__ __launch_bounds__(256) void k_update(const float* __restrict__ agg, const float* __restrict__ base,
                                                const float* cf2w, const float* cf2b,
                                                const float* lw, const float* lb,
                                                float* out, int M) {
    __shared__ float tbuf[4][H_DIM];
    int wave = threadIdx.x >> 6, lane = threadIdx.x & 63;
    int n = blockIdx.x * 4 + wave;
    float t0 = cf2b[lane], t1 = cf2b[lane + 64];
    if (n < M) {
        for (int f = 0; f < F_DIM; f++) {
            float a = agg[n * F_DIM + f];
            t0 += a * cf2w[f * H_DIM + lane];
            t1 += a * cf2w[f * H_DIM + lane + 64];
        }
    }
    tbuf[wave][lane] = ssp_f(t0);
    tbuf[wave][lane + 64] = ssp_f(t1);
    __syncthreads();
    if (n < M) {
        float o0 = lb[lane], o1 = lb[lane + 64];
        const float4* t4v = (const float4*)tbuf[wave];
        #pragma unroll
        for (int kk = 0; kk < 32; kk++) {
            float4 tq = t4v[kk];
            int k4 = kk * 4;
            o0 += tq.x * lw[(k4 + 0) * H_DIM + lane];
            o1 += tq.x * lw[(k4 + 0) * H_DIM + lane + 64];
            o0 += tq.y * lw[(k4 + 1) * H_DIM + lane];
            o1 += tq.y * lw[(k4 + 1) * H_DIM + lane + 64];
            o0 += tq.z * lw[(k4 + 2) * H_DIM + lane];
            o1 += tq.z * lw[(k4 + 2) * H_DIM + lane + 64];
            o0 += tq.w * lw[(k4 + 3) * H_DIM + lane];
            o1 += tq.w * lw[(k4 + 3) * H_DIM + lane + 64];
        }
        out[n * H_DIM + lane]      = base[n * H_DIM + lane] + o0;
        out[n * H_DIM + lane + 64] = base[n * H_DIM + lane + 64] + o1;
    }
}

// ---------------- node scores (exact: feeds top-K) ----------------
__global__ __launch_bounds__(256) void k_scores(const float* h_local,
                                                const float* msw1, const float* msb1,
                                                const float* msw2, const float* msb2,
                                                float* scores) {
    int n = blockIdx.x * 256 + threadIdx.x;
    if (n >= N_ATOMS) return;
    float hs[S_DIM];
    for (int s = 0; s < S_DIM; s++) hs[s] = h_local[n * H_DIM + s];
    float sc = msb2[0];
    for (int j = 0; j < MH_DIM; j++) {
        float v = msb1[j];
        for (int s = 0; s < S_DIM; s++) v += hs[s] * msw1[s * MH_DIM + j];
        sc += fmaxf(v, 0.f) * msw2[j];
    }
    scores[n] = sc;
}

// ---------------- parallel exact rank ----------------
__global__ __launch_bounds__(256) void k_rank(const float* scores, int* rank) {
    __shared__ float s[N_ATOMS];
    __shared__ int pc[16][17];
    int t = threadIdx.x;
    for (int i = t; i < N_ATOMS; i += 256) s[i] = scores[i];
    __syncthreads();
    int ii = t & 15, chunk = t >> 4;
    int i = blockIdx.x * 16 + ii;
    float si = s[i];
    int cnt = 0;
    int j0 = chunk * (N_ATOMS / 16);
    #pragma unroll 4
    for (int j = j0; j < j0 + N_ATOMS / 16; j++) {
        float sj = s[j];
        cnt += (sj > si) || (sj == si && j < i);
    }
    pc[chunk][ii] = cnt;
    __syncthreads();
    if (chunk == 0) {
        int r = 0;
        #pragma unroll
        for (int c = 0; c < 16; c++) r += pc[c][ii];
        rank[i] = r;
    }
}

// ---------------- selection, prefix, midx, m ----------------
__global__ __launch_bounds__(1024) void k_select(const float* scores, const int* rank,
                                                 int* is_m, int* invg, int* midx, float* m) {
    __shared__ int flag[N_ATOMS];
    __shared__ int bufA[N_ATOMS], bufB[N_ATOMS];
    __shared__ float kth;
    int t = threadIdx.x;
    for (int i = t; i < N_ATOMS; i += 1024) {
        int f = rank[i] < K_TOP;
        flag[i] = f;
        bufA[i] = f;
        if (rank[i] == K_TOP - 1) kth = scores[i];
    }
    __syncthreads();
    int* in = bufA;
    int* out = bufB;
    for (int d = 1; d < N_ATOMS; d <<= 1) {
        for (int i = t; i < N_ATOMS; i += 1024) out[i] = in[i] + (i >= d ? in[i - d] : 0);
        __syncthreads();
        int* tmp = in; in = out; out = tmp;
    }
    float kv = kth;
    for (int i = t; i < N_ATOMS; i += 1024) {
        int f = flag[i];
        int pos = in[i] - f;
        is_m[i] = f;
        invg[i] = f ? pos : 0;
        if (f) midx[pos] = i;
        m[i] = sigm_f(scores[i] - kv + 1e-6f);
    }
}

// ---------------- gather h_m / pos_m (+ zero adj: 262144 threads == K*K bytes) ----------------
__global__ __launch_bounds__(256) void k_gather(const int* midx, const float* h_local,
                                                const float* pos, float* h_m, float* pos_m,
                                                unsigned char* adj) {
    int i = blockIdx.x * 256 + threadIdx.x;
    int k = i >> 7, c = i & 127;
    int n = midx[k];
    h_m[i] = h_local[n * H_DIM + c];
    if (c < 3) pos_m[k * 3 + c] = pos[n * 3 + c];
    adj[i] = 0;
}

// ---------------- adjacency + valid-edge list ----------------
__global__ __launch_bounds__(256) void k_adj(const int* src, const int* dst, const int* is_m,
                                             const int* invg, unsigned char* adj,
                                             int* velist, int* nve) {
    int e = blockIdx.x * 256 + threadIdx.x;
    int s = src[e], d = dst[e];
    bool valid = is_m[s] && is_m[d];
    if (valid) adj[invg[s] * K_TOP + invg[d]] = 1;
    unsigned long long mask = __ballot(valid);
    int lane = threadIdx.x & 63;
    int cnt = __popcll(mask);
    int base = 0;
    if (lane == 0 && cnt) base = atomicAdd(nve, cnt);
    base = __shfl(base, 0);
    if (valid) velist[base + __popcll(mask & ((1ull << lane) - 1))] = e;
}

// ---------------- per-valid-edge packed data {sm, dm, dist} ----------------
__global__ __launch_bounds__(256) void k_vdat(const int* velist, const int* nve,
                                              const int* src, const int* dst, const int* invg,
                                              const float* pos_m, int4* vdat) {
    int n = nve[0];
    for (int p = blockIdx.x * 256 + threadIdx.x; p < n; p += gridDim.x * 256) {
        int e = velist[p];
        int sm = invg[src[e]];
        int dm = invg[dst[e]];
        float dx = pos_m[sm * 3 + 0] - pos_m[dm * 3 + 0];
        float dy = pos_m[sm * 3 + 1] - pos_m[dm * 3 + 1];
        float dz = pos_m[sm * 3 + 2] - pos_m[dm * 3 + 2];
        float dist = sqrtf(dx * dx + dy * dy + dz * dz + 1e-12f);
        vdat[p] = make_int4(sm, dm, __float_as_int(dist), 0);
    }
}

// ---------------- q/k projections ----------------
__global__ __launch_bounds__(256) void k_qk(const float* h_m, const float* wq,
                                            const float* wk, float* qm, float* km) {
    int gid = blockIdx.x * 256 + threadIdx.x;
    int r = gid >> 5, t = gid & 31;
    const float* w = (t < 16) ? wq : wk;
    int c = t & 15;
    float acc = 0.f;
    for (int s = 0; s < S_DIM; s++) acc += h_m[r * H_DIM + s] * w[s * S_DIM + c];
    if (t < 16) qm[r * S_DIM + c] = acc; else km[r * S_DIM + c] = acc;
}

// ---------------- attention softmax -> Av mask (exact) ----------------
__global__ __launch_bounds__(256) void k_attn(const float* qm, const float* km,
                                              const unsigned char* adj, unsigned char* Av) {
    __shared__ float lrow[K_TOP];
    __shared__ float red[256];
    int i = blockIdx.x, t = threadIdx.x;
    float q[S_DIM];
    for (int s = 0; s < S_DIM; s++) q[s] = qm[i * S_DIM + s];
    for (int j = t; j < K_TOP; j += 256) {
        float acc = 0.f;
        for (int s = 0; s < S_DIM; s++) acc += q[s] * km[j * S_DIM + s];
        lrow[j] = acc * 0.25f;
    }
    __syncthreads();
    float mx = -1e30f;
    for (int j = t; j < K_TOP; j += 256) mx = fmaxf(mx, lrow[j]);
    red[t] = mx; __syncthreads();
    for (int o = 128; o > 0; o >>= 1) { if (t < o) red[t] = fmaxf(red[t], red[t + o]); __syncthreads(); }
    mx = red[0]; __syncthreads();
    float sum = 0.f;
    for (int j = t; j < K_TOP; j += 256) sum += expf(lrow[j] - mx);
    red[t] = sum; __syncthreads();
    for (int o = 128; o > 0; o >>= 1) { if (t < o) red[t] += red[t + o]; __syncthreads(); }
    float inv_s = 1.f / red[0];
    for (int j = t; j < K_TOP; j += 256) {
        float a = expf(lrow[j] - mx) * inv_s;
        Av[i * K_TOP + j] = (a > LAMBDA) && (!adj[i * K_TOP + j]) && (i != j);
    }
}

// ---------------- deterministic j-major pair compaction ----------------
__global__ __launch_bounds__(256) void k_pcount(const unsigned char* Av, int* bcount) {
    __shared__ int wsum[4];
    int idx = blockIdx.x * 256 + threadIdx.x;
    int j = idx >> 9, i = idx & (K_TOP - 1);
    bool act = Av[i * K_TOP + j] != 0;
    unsigned long long mask = __ballot(act);
    int lane = threadIdx.x & 63, wave = threadIdx.x >> 6;
    if (lane == 0) wsum[wave] = __popcll(mask);
    __syncthreads();
    if (threadIdx.x == 0) bcount[blockIdx.x] = wsum[0] + wsum[1] + wsum[2] + wsum[3];
}

__global__ __launch_bounds__(1024) void k_pscan(const int* bcount, int* boffset, int* total) {
    __shared__ int bufA[1024], bufB[1024];
    int t = threadIdx.x;
    bufA[t] = bcount[t];
    __syncthreads();
    int* in = bufA;
    int* out = bufB;
    for (int d = 1; d < 1024; d <<= 1) {
        out[t] = in[t] + (t >= d ? in[t - d] : 0);
        __syncthreads();
        int* tmp = in; in = out; out = tmp;
    }
    boffset[t] = in[t] - bcount[t];
    if (t == 1023) total[0] = in[1023];
}

__global__ __launch_bounds__(256) void k_pscatter(const unsigned char* Av, const int* boffset,
                                                  unsigned int* plist) {
    __shared__ int wsum[4], woff[4];
    int idx = blockIdx.x * 256 + threadIdx.x;
    int j = idx >> 9, i = idx & (K_TOP - 1);
    bool act = Av[i * K_TOP + j] != 0;
    unsigned long long mask = __ballot(act);
    int lane = threadIdx.x & 63, wave = threadIdx.x >> 6;
    if (lane == 0) wsum[wave] = __popcll(mask);
    __syncthreads();
    if (threadIdx.x == 0) {
        int s = 0;
        for (int w = 0; w < 4; w++) { woff[w] = s; s += wsum[w]; }
    }
    __syncthreads();
    if (act) {
        int pos = boffset[blockIdx.x] + woff[wave] + __popcll(mask & ((1ull << lane) - 1));
        plist[pos] = ((unsigned int)j << 9) | (unsigned int)i;
    }
}

// ---------------- packed pair data for score: {key, dd} ----------------
__global__ __launch_bounds__(256) void k_sdata(const unsigned int* plist, const int* npairs,
                                               const float* pos_m, float2* sd) {
    int n = npairs[0];
    for (int p = blockIdx.x * 256 + threadIdx.x; p < n; p += gridDim.x * 256) {
        unsigned int key = plist[p];
        int j = key >> 9, i = key & (K_TOP - 1);
        float dx = pos_m[i * 3 + 0] - pos_m[j * 3 + 0];
        float dy = pos_m[i * 3 + 1] - pos_m[j * 3 + 1];
        float dz = pos_m[i * 3 + 2] - pos_m[j * 3 + 2];
        float dd = sqrtf(dx * dx + dy * dy + dz * dz + 1e-12f);
        sd[p] = make_float2(__uint_as_float(key), dd);
    }
}

// ---------------- packed pair data for aggd: {key, dd, dec} (+ zero agg_m) ----------------
__global__ __launch_bounds__(256) void k_pdat(const unsigned int* plist, const int* npairs,
                                              const float* pos_m, const float* decay, float4* pd,
                                              float* agg_m) {
    int gid = blockIdx.x * 256 + threadIdx.x;
    if (gid < K_TOP * F_DIM) agg_m[gid] = 0.f;
    int n = npairs[0];
    for (int p = gid; p < n; p += gridDim.x * 256) {
        unsigned int key = plist[p];
        int j = key >> 9, i = key & (K_TOP - 1);
        float dx = pos_m[i * 3 + 0] - pos_m[j * 3 + 0];
        float dy = pos_m[i * 3 + 1] - pos_m[j * 3 + 1];
        float dz = pos_m[i * 3 + 2] - pos_m[j * 3 + 2];
        float dd = sqrtf(dx * dx + dy * dy + dz * dz + 1e-12f);
        pd[p] = make_float4(__uint_as_float(key), dd, decay[i * K_TOP + j], 0.f);
    }
}

// ---------------- hi = h_m@Wi, hj = h_m@Wj ----------------
__global__ __launch_bounds__(256) void k_hij(const float* h_m, const float* aw1,
                                             float* hi, float* hj) {
    int wave = threadIdx.x >> 6, lane = threadIdx.x & 63;
    int idx = blockIdx.x * 4 + wave;
    int which = idx >> 9;
    int r = idx & (K_TOP - 1);
    const float* W = aw1 + which * H_DIM * H_DIM;
    float o0 = 0.f, o1 = 0.f;
    for (int k = 0; k < H_DIM; k++) {
        float hv = h_m[r * H_DIM + k];
        o0 += hv * W[k * H_DIM + lane];
        o1 += hv * W[k * H_DIM + lane + 64];
    }
    float* out = which ? hj : hi;
    out[r * H_DIM + lane] = o0;
    out[r * H_DIM + lane + 64] = o1;
}

// ---------------- per-pair attention scores: ztabS lookup ----------------
__global__ __launch_bounds__(256) void k_score_p(const float2* sd, const int* npairs,
                                                 const float* hi, const float* hj,
                                                 const float* __restrict__ ztabS,
                                                 const float* ab1, const float* aw2, const float* ab2,
                                                 float* sbuf) {
    int t = threadIdx.x, wave = t >> 6, lane = t & 63;
    float ab0 = ab1[lane], ab1v = ab1[lane + 64];
    float aw0 = aw2[lane], aw1v = aw2[lane + 64];
    float b2 = ab2[0];
    int n = npairs[0];
    int wid = blockIdx.x * 4 + wave;
    int nw = gridDim.x * 4;
    for (int p = wid; p < n; p += nw) {
        float2 s2 = sd[p];
        unsigned int key = __float_as_uint(s2.x);
        float dd = s2.y;
        int j = key >> 9, i = key & (K_TOP - 1);
        int ij = i * K_TOP + j;
        float s = dd * INV_DD;
        int b0 = min((int)s, NB - 2);
        float fr = s - b0;
        const float* r0 = ztabS + b0 * H_DIM;
        const float* r1 = r0 + H_DIM;
        float z0a = r0[lane],      z1a = r1[lane];
        float z0b = r0[lane + 64], z1b = r1[lane + 64];
        float zs0 = z0a + fr * (z1a - z0a);
        float zs1 = z0b + fr * (z1b - z0b);
        float v0 = hi[i * H_DIM + lane] + hj[j * H_DIM + lane] + ab0 + zs0;
        float v1 = hi[i * H_DIM + lane + 64] + hj[j * H_DIM + lane + 64] + ab1v + zs1;
        float pv = fmaxf(v0, 0.f) * aw0 + fmaxf(v1, 0.f) * aw1v;
        for (int o = 1; o < 64; o <<= 1) pv += __shfl_xor(pv, o);
        if (lane == 0) sbuf[ij] = pv + b2;
    }
}

// ---------------- row softmax (Av-guarded) -> decay (exact) ----------------
__global__ __launch_bounds__(256) void k_decay(const float* sbuf, const unsigned char* Av, float* decay) {
    __shared__ float srow[K_TOP];
    __shared__ float red[256];
    int i = blockIdx.x, t = threadIdx.x;
    for (int j = t; j < K_TOP; j += 256)
        srow[j] = Av[i * K_TOP + j] ? sbuf[i * K_TOP + j] : -1e9f;
    __syncthreads();
    float mx = -1e30f;
    for (int j = t; j < K_TOP; j += 256) mx = fmaxf(mx, srow[j]);
    red[t] = mx; __syncthreads();
    for (int o = 128; o > 0; o >>= 1) { if (t < o) red[t] = fmaxf(red[t], red[t + o]); __syncthreads(); }
    mx = red[0]; __syncthreads();
    float sum = 0.f;
    for (int j = t; j < K_TOP; j += 256) sum += (srow[j] > -5e8f) ? expf(srow[j] - mx) : 0.f;
    red[t] = sum; __syncthreads();
    for (int o = 128; o > 0; o >>= 1) { if (t < o) red[t] += red[t + o]; __syncthreads(); }
    float s_total = red[0];
    float inv_s = (s_total > 0.f) ? 1.f / s_total : 0.f;
    for (int j = t; j < K_TOP; j += 256)
        decay[i * K_TOP + j] = (srow[j] > -5e8f) ? expf(srow[j] - mx) * inv_s : 0.f;
}

// ---------------- agg_d: z1 table + second layer, short chunks ----------------
__global__ __launch_bounds__(256) void k_aggd_p2(const float4* pd, const int* npairs,
                                                 const float* xm,
                                                 const float* __restrict__ z1tab,
                                                 const float* mb1,
                                                 const float* mw2, const float* mb2,
                                                 float* agg_m) {
    __shared__ float tbuf[4][F_DIM];
    int t = threadIdx.x, wave = t >> 6, lane = t & 63;
    float w2r[F_DIM];
    #pragma unroll
    for (int k = 0; k < F_DIM; k++) w2r[k] = mw2[k * F_DIM + lane];
    float b1 = mb1[lane], b2v = mb2[lane];
    int n = npairs[0];
    int nchunks = (n + PCHUNK - 1) / PCHUNK;
    int wid = blockIdx.x * 4 + wave;
    int nw = gridDim.x * 4;
    for (int c = wid; c < nchunks; c += nw) {
        int p0 = c * PCHUNK;
        int p1 = min(p0 + PCHUNK, n);
        int curJ = -1;
        float acc = 0.f;
        for (int p = p0; p < p1; p++) {
            float4 q = pd[p];
            unsigned int key = __float_as_uint(q.x);
            float dd = q.y, dec = q.z;
            int j = key >> 9, i = key & (K_TOP - 1);
            float s = dd * INV_DD;
            int b0 = min((int)s, NB - 2);
            float fr = s - b0;
            float z0 = z1tab[b0 * F_DIM + lane];
            float z1 = z1tab[(b0 + 1) * F_DIM + lane];
            float z1v = z0 + fr * (z1 - z0);
            float tv = ssp_fast(dec * z1v + b1);
            tbuf[wave][lane] = tv;
            float w = b2v;
            const float4* t4v = (const float4*)tbuf[wave];
            #pragma unroll
            for (int kk = 0; kk < 16; kk++) {
                float4 tq = t4v[kk];
                w += tq.x * w2r[4 * kk + 0];
                w += tq.y * w2r[4 * kk + 1];
                w += tq.z * w2r[4 * kk + 2];
                w += tq.w * w2r[4 * kk + 3];
            }
            float contrib = xm[i * F_DIM + lane] * w * ccut_fast(dd);
            if (j != curJ) {
                if (curJ >= 0) atomicAdd(&agg_m[curJ * F_DIM + lane], acc);
                acc = 0.f;
                curJ = j;
            }
            acc += contrib;
        }
        if (curJ >= 0) atomicAdd(&agg_m[curJ * F_DIM + lane], acc);
    }
}

// ---------------- valid-edge filter: table lookup ----------------
__global__ __launch_bounds__(256) void k_aggs_p(const int4* vdat, const int* nve,
                                                const float* xm,
                                                const float* __restrict__ wtab,
                                                float* agg_m) {
    int t = threadIdx.x, wave = t >> 6, lane = t & 63;
    int n = nve[0];
    int wid = blockIdx.x * 4 + wave;
    int nw = gridDim.x * 4;
    for (int p = wid; p < n; p += nw) {
        int4 vd = vdat[p];
        int sm = vd.x, dm = vd.y;
        float d = __int_as_float(vd.z);
        float s = d * INV_DD;
        int b0 = min((int)s, NB - 2);
        float fr = s - b0;
        float w0 = wtab[b0 * F_DIM + lane];
        float w1 = wtab[(b0 + 1) * F_DIM + lane];
        float w = w0 + fr * (w1 - w0);
        atomicAdd(&agg_m[dm * F_DIM + lane], xm[sm * F_DIM + lane] * w);
    }
}

// ---------------- blend ----------------
__global__ __launch_bounds__(256) void k_blend(const float* h_local, const float* h_hier,
                                               const int* is_m, const int* invg, const float* m,
                                               float* h_out) {
    int idx = blockIdx.x * 256 + threadIdx.x;
    int n = idx >> 7, c = idx & 127;
    float mm = m[n];
    float hh = is_m[n] ? h_hier[invg[n] * H_DIM + c] : 0.f;
    h_out[idx] = (1.f - mm) * h_local[idx] + mm * hh;
}

// ---------------- parallel segment-sum pooling ----------------
__global__ __launch_bounds__(256) void k_pool(const float* __restrict__ h, const int* __restrict__ batch,
                                              float* pooled) {
    int c = threadIdx.x & 127, a = threadIdx.x >> 7;
    int n0 = blockIdx.x * 64;
    float acc = 0.f;
    int cur = batch[n0 + a];
    for (int i = a; i < 64; i += 2) {
        int n = n0 + i;
        int b = batch[n];
        if (b != cur) { atomicAdd(&pooled[cur * H_DIM + c], acc); acc = 0.f; cur = b; }
        acc += h[n * H_DIM + c];
    }
    atomicAdd(&pooled[cur * H_DIM + c], acc);
}

// ---------------- predict MLP ----------------
__global__ __launch_bounds__(128) void k_pred2(const float* pooled,
                                               const float* w1, const float* b1,
                                               const float* w2, const float* b2,
                                               void* outv, const int* flag) {
    __shared__ float c64[64];
    int b = blockIdx.x, t = threadIdx.x;
    if (t < 64) {
        float v = b1[t];
        for (int k = 0; k < H_DIM; k++) v += pooled[b * H_DIM + k] * w1[k * 64 + t];
        c64[t] = v * sigm_f(v);
    }
    __syncthreads();
    if (t == 0) {
        float o = b2[0];
        for (int k = 0; k < 64; k++) o += c64[k] * w2[k];
        if (flag[0]) ((float*)outv)[b] = o;
        else ((__hip_bfloat16*)outv)[b] = __float2bfloat16(o);
    }
}

extern "C" void kernel_launch(void* const* d_in, const int* in_sizes, int n_in,
                              void* d_out, int out_size, void* d_ws, size_t ws_size,
                              hipStream_t stream) {
    (void)n_in; (void)out_size; (void)ws_size;
    const int* atoms = (const int*)d_in[0];
    const int* src = (const int*)d_in[2];
    const int* dst = (const int*)d_in[3];
    const int* batch = (const int*)d_in[4];

    float* W = (float*)d_ws;
    int* dflag = (int*)W; W += 16;
    int* counters = (int*)W; W += 16;  // [0]=npairs, [1]=nve

    static const int fidx[25] = {1,5,6,7,8,9,10,11,12,13,14,15,16,17,18,19,20,21,22,23,24,25,26,27,28};
    float* fin[29];
    ConvArgs ca;
    float* convBase = W;
    int off = 0;
    for (int q = 0; q < 25; q++) {
        int i = fidx[q];
        ca.p[q] = d_in[i];
        ca.off[q] = off;
        fin[i] = convBase + off;
        off += in_sizes[i];
    }
    ca.off[25] = off;
    W += off;

    k_detect<<<1, 256, 0, stream>>>((const unsigned short*)d_in[5], in_sizes[5], dflag);
    k_convert_all<<<(off + 255) / 256, 256, 0, stream>>>(ca, convBase, dflag);

    const float* posf = fin[1];
    const float* embf = fin[5];

    float* h      = W; W += N_ATOMS * H_DIM;
    float* h_loc  = W; W += N_ATOMS * H_DIM;
    float* xbuf   = W; W += N_ATOMS * F_DIM;
    float* aggbuf = W; W += N_ATOMS * F_DIM;
    float* scores = W; W += N_ATOMS;
    float* mbuf   = W; W += N_ATOMS;
    float* h_m    = W; W += K_TOP * H_DIM;
    float* pos_m  = W; W += K_TOP * 3;
    float* xm     = W; W += K_TOP * F_DIM;
    float* qm     = W; W += K_TOP * S_DIM;
    float* km     = W; W += K_TOP * S_DIM;
    float* decay  = W; W += K_TOP * K_TOP;
    float* sbuf   = W; W += K_TOP * K_TOP;
    float* hi     = W; W += K_TOP * H_DIM;
    float* hj     = W; W += K_TOP * H_DIM;
    float* agg_m  = W; W += K_TOP * F_DIM;
    float* h_hier = W; W += K_TOP * H_DIM;
    float* pooled = W; W += B_BATCH * H_DIM;
    float* z1tab  = W; W += NB * F_DIM;
    float* wtab   = W; W += NB * F_DIM;
    float* ztabS  = W; W += NB * H_DIM;
    int* rankb  = (int*)W; W += N_ATOMS;
    int* is_m   = (int*)W; W += N_ATOMS;
    int* invg   = (int*)W; W += N_ATOMS;
    int* midx   = (int*)W; W += K_TOP;
    unsigned int* plist = (unsigned int*)W; W += K_TOP * K_TOP;
    int* velist = (int*)W; W += E_EDGES;
    int* esorted = (int*)W; W += E_EDGES;
    int* ehist  = (int*)W; W += N_ATOMS;
    int* ebase  = (int*)W; W += N_ATOMS;
    int* ecur   = (int*)W; W += N_ATOMS;
    int* bcount = (int*)W; W += 1024;
    int* boffset = (int*)W; W += 1024;
    int4* edat  = (int4*)W; W += E_EDGES * 4;
    int4* vdat  = (int4*)W; W += E_EDGES * 4;
    float2* sd  = (float2*)W; W += K_TOP * K_TOP * 2;
    float4* pd  = (float4*)W; W += K_TOP * K_TOP * 4;
    unsigned char* adj = (unsigned char*)W; W += (K_TOP * K_TOP) / 4;
    unsigned char* Av  = (unsigned char*)W; W += (K_TOP * K_TOP) / 4;

    // one-time: counting-sort edges by dst + packed edge data
    (void)hipMemsetAsync(ehist, 0, N_ATOMS * sizeof(int), stream);
    k_ehist<<<E_EDGES / 256, 256, 0, stream>>>(dst, ehist);
    k_escan<<<1, 1024, 0, stream>>>(ehist, ebase, ecur);
    k_escatter<<<E_EDGES / 256, 256, 0, stream>>>(dst, ecur, esorted);
    k_edat<<<E_EDGES / 256, 256, 0, stream>>>(esorted, src, dst, posf, edat);

    k_embed<<<(N_ATOMS * H_DIM) / 256, 256, 0, stream>>>(atoms, embf, h);

    for (int l = 0; l < L_LAYERS; l++) {
        const float* mw1 = fin[6]  + l * G_DIM * F_DIM;
        const float* mb1 = fin[7]  + l * F_DIM;
        const float* mw2 = fin[8]  + l * F_DIM * F_DIM;
        const float* mb2 = fin[9]  + l * F_DIM;
        const float* cf1 = fin[10] + l * H_DIM * F_DIM;
        const float* cf2w = fin[11] + l * F_DIM * H_DIM;
        const float* cf2b = fin[12] + l * H_DIM;
        const float* lw  = fin[13] + l * H_DIM * H_DIM;
        const float* lb  = fin[14] + l * H_DIM;
        const float* aw1 = fin[15] + l * (2 * H_DIM + G_DIM) * H_DIM;
        const float* ab1 = fin[16] + l * H_DIM;
        const float* aw2 = fin[17] + l * H_DIM;
        const float* ab2 = fin[18] + l;
        const float* msw1 = fin[19] + l * S_DIM * MH_DIM;
        const float* msb1 = fin[20] + l * MH_DIM;
        const float* msw2 = fin[21] + l * MH_DIM;
        const float* msb2 = fin[22] + l;
        const float* wq  = fin[23] + l * S_DIM * S_DIM;
        const float* wk  = fin[24] + l * S_DIM * S_DIM;

        k_ftab<<<NB, 128, 0, stream>>>(mw1, mb1, mw2, mb2, aw1, z1tab, wtab, ztabS);
        k_x<<<N_ATOMS / 4, 256, 0, stream>>>(h, cf1, xbuf, aggbuf, N_ATOMS);
        k_edge_s<<<E_EDGES / (4 * EPW2), 256, 0, stream>>>(edat, xbuf, wtab, aggbuf);
        k_update<<<N_ATOMS / 4, 256, 0, stream>>>(aggbuf, h, cf2w, cf2b, lw, lb, h_loc, N_ATOMS);
        k_scores<<<N_ATOMS / 256, 256, 0, stream>>>(h_loc, msw1, msb1, msw2, msb2, scores);
        k_rank<<<N_ATOMS / 16, 256, 0, stream>>>(scores, rankb);
        k_select<<<1, 1024, 0, stream>>>(scores, rankb, is_m, invg, midx, mbuf);
        k_gather<<<(K_TOP * H_DIM) / 256, 256, 0, stream>>>(midx, h_loc, posf, h_m, pos_m, adj);
        k_x<<<K_TOP / 4, 256, 0, stream>>>(h_m, cf1, xm, agg_m, K_TOP);
        (void)hipMemsetAsync(counters, 0, 2 * sizeof(int), stream);
        k_adj<<<E_EDGES / 256, 256, 0, stream>>>(src, dst, is_m, invg, adj, velist, counters + 1);
        k_vdat<<<256, 256, 0, stream>>>(velist, counters + 1, src, dst, invg, pos_m, vdat);
        k_qk<<<(K_TOP * 32) / 256, 256, 0, stream>>>(h_m, wq, wk, qm, km);
        k_attn<<<K_TOP, 256, 0, stream>>>(qm, km, adj, Av);
        k_pcount<<<(K_TOP * K_TOP) / 256, 256, 0, stream>>>(Av, bcount);
        k_pscan<<<1, 1024, 0, stream>>>(bcount, boffset, counters);
        k_pscatter<<<(K_TOP * K_TOP) / 256, 256, 0, stream>>>(Av, boffset, plist);
        k_sdata<<<512, 256, 0, stream>>>(plist, counters, pos_m, sd);
        k_hij<<<(2 * K_TOP) / 4, 256, 0, stream>>>(h_m, aw1, hi, hj);
        k_score_p<<<1024, 256, 0, stream>>>(sd, counters, hi, hj, ztabS, ab1, aw2, ab2, sbuf);
        k_decay<<<K_TOP, 256, 0, stream>>>(sbuf, Av, decay);
        k_pdat<<<512, 256, 0, stream>>>(plist, counters, pos_m, decay, pd, agg_m);
        k_aggd_p2<<<4096, 256, 0, stream>>>(pd, counters, xm, z1tab, mb1, mw2, mb2, agg_m);
        k_aggs_p<<<256, 256, 0, stream>>>(vdat, counters + 1, xm, wtab, agg_m);
        k_update<<<K_TOP / 4, 256, 0, stream>>>(agg_m, h_m, cf2w, cf2b, lw, lb, h_hier, K_TOP);
        k_blend<<<(N_ATOMS * H_DIM) / 256, 256, 0, stream>>>(h_loc, h_hier, is_m, invg, mbuf, h);
    }

    (void)hipMemsetAsync(pooled, 0, B_BATCH * H_DIM * sizeof(float), stream);
    k_pool<<<N_ATOMS / 64, 256, 0, stream>>>(h, batch, pooled);
    k_pred2<<<B_BATCH, 128, 0, stream>>>(pooled, fin[25], fin[26], fin[27], fin[28], d_out, dflag);
}

// Round 19
// 360.517 us; speedup vs baseline: 4.4794x; 1.0233x over previous
//
#include <hip/hip_runtime.h>
#include <hip/hip_bf16.h>
#include <math.h>

#define N_ATOMS 2048
#define E_EDGES 65536
#define B_BATCH 8
#define H_DIM 128
#define G_DIM 50
#define F_DIM 64
#define S_DIM 16
#define MH_DIM 32
#define K_TOP 512
#define L_LAYERS 2
#define EPW2 8
#define PCHUNK 8
#define NB 4096
#define DD 0.015625f
#define INV_DD 64.0f

static constexpr float STEP   = 10.0f / 49.0f;
static constexpr float COEFF  = -12.005f;
static constexpr float PI10   = 0.31415926535897931f;
static constexpr float LN2    = 0.69314718055994531f;
static constexpr float LAMBDA = 0.002f;

#define DEV static __device__ __forceinline__

DEV float ssp_f(float x) { return fmaxf(x, 0.f) + log1pf(expf(-fabsf(x))) - LN2; }
DEV float ccut_f(float d) { return 0.5f * (cosf(d * PI10) + 1.f); }
DEV float sigm_f(float x) { return 1.f / (1.f + expf(-x)); }
DEV float ssp_fast(float x) { return fmaxf(x, 0.f) + __logf(1.f + __expf(-fabsf(x))) - LN2; }
DEV float ccut_fast(float d) { return 0.5f * (__cosf(d * PI10) + 1.f); }

// ---------------- dtype detect ----------------
__global__ __launch_bounds__(256) void k_detect(const unsigned short* raw, int n, int* flag) {
    __shared__ int any;
    if (threadIdx.x == 0) any = 0;
    __syncthreads();
    for (int i = threadIdx.x; i < n; i += 256) {
        unsigned int bits = ((unsigned int)raw[i]) << 16;
        float f = __uint_as_float(bits);
        if (!(fabsf(f) <= 1e10f)) any = 1;
    }
    __syncthreads();
    if (threadIdx.x == 0) flag[0] = any;
}

// ---------------- fused convert ----------------
struct ConvArgs {
    const void* p[25];
    int off[26];
};

__global__ __launch_bounds__(256) void k_convert_all(ConvArgs a, float* dst, const int* flag) {
    int i = blockIdx.x * 256 + threadIdx.x;
    int total = a.off[25];
    if (i >= total) return;
    int seg = 0;
    while (i >= a.off[seg + 1]) seg++;
    int k = i - a.off[seg];
    if (flag[0]) {
        dst[i] = ((const float*)a.p[seg])[k];
    } else {
        unsigned int bits = ((unsigned int)((const unsigned short*)a.p[seg])[k]) << 16;
        dst[i] = __uint_as_float(bits);
    }
}

// ---------------- edge counting-sort by dst ----------------
__global__ __launch_bounds__(256) void k_ehist(const int* dst, int* hist) {
    int e = blockIdx.x * 256 + threadIdx.x;
    atomicAdd(&hist[dst[e]], 1);
}

__global__ __launch_bounds__(1024) void k_escan(const int* hist, int* ebase, int* ecur) {
    __shared__ int bufA[N_ATOMS], bufB[N_ATOMS];
    int t = threadIdx.x;
    for (int i = t; i < N_ATOMS; i += 1024) bufA[i] = hist[i];
    __syncthreads();
    int* in = bufA;
    int* out = bufB;
    for (int d = 1; d < N_ATOMS; d <<= 1) {
        for (int i = t; i < N_ATOMS; i += 1024) out[i] = in[i] + (i >= d ? in[i - d] : 0);
        __syncthreads();
        int* tmp = in; in = out; out = tmp;
    }
    for (int i = t; i < N_ATOMS; i += 1024) {
        int ex = in[i] - hist[i];
        ebase[i] = ex;
        ecur[i] = ex;
    }
}

__global__ __launch_bounds__(256) void k_escatter(const int* dst, int* ecur, int* esorted) {
    int e = blockIdx.x * 256 + threadIdx.x;
    int pos = atomicAdd(&ecur[dst[e]], 1);
    esorted[pos] = e;
}

// ---------------- one-time packed edge data {src, dst, dist} ----------------
__global__ __launch_bounds__(256) void k_edat(const int* esorted, const int* src, const int* dst,
                                              const float* pos, int4* edat) {
    int p = blockIdx.x * 256 + threadIdx.x;
    int e = esorted[p];
    int s = src[e], d = dst[e];
    float dx = pos[s * 3 + 0] - pos[d * 3 + 0];
    float dy = pos[s * 3 + 1] - pos[d * 3 + 1];
    float dz = pos[s * 3 + 2] - pos[d * 3 + 2];
    float dist = sqrtf(dx * dx + dy * dy + dz * dz + 1e-12f);
    edat[p] = make_int4(s, d, __float_as_int(dist), 0);
}

// ---------------- per-layer filter tables (exact math, 4096 bins) ----------------
__global__ __launch_bounds__(128) void k_ftab(const float* mw1, const float* mb1,
                                              const float* mw2, const float* mb2,
                                              const float* aw1,
                                              float* z1tab, float* wtab, float* ztabS) {
    __shared__ float gs[G_DIM];
    __shared__ float tb[F_DIM];
    int b = blockIdx.x, t = threadIdx.x;
    float d = b * DD;
    if (t < G_DIM) { float u = d - t * STEP; gs[t] = expf(COEFF * u * u); }
    __syncthreads();
    const float* wd = aw1 + 2 * H_DIM * H_DIM;
    float zs = 0.f;
    for (int g = 0; g < G_DIM; g++) zs += gs[g] * wd[g * H_DIM + t];
    ztabS[b * H_DIM + t] = zs;
    if (t < F_DIM) {
        float z1 = 0.f;
        for (int g = 0; g < G_DIM; g++) z1 += gs[g] * mw1[g * F_DIM + t];
        z1tab[b * F_DIM + t] = z1;
        tb[t] = ssp_f(z1 + mb1[t]);
    }
    __syncthreads();
    if (t < F_DIM) {
        float w = mb2[t];
        for (int k = 0; k < F_DIM; k++) w += tb[k] * mw2[k * F_DIM + t];
        wtab[b * F_DIM + t] = w * ccut_f(d);
    }
}

// ---------------- embedding ----------------
__global__ __launch_bounds__(256) void k_embed(const int* atoms, const float* emb, float* h) {
    int i = blockIdx.x * 256 + threadIdx.x;
    int n = i >> 7, c = i & 127;
    h[i] = emb[atoms[n] * H_DIM + c];
}

// ---------------- x = h @ cf1 (+ zero agg buffer of same shape) ----------------
__global__ __launch_bounds__(256) void k_x(const float* __restrict__ h, const float* __restrict__ cf1,
                                           float* __restrict__ x, float* __restrict__ aggz, int M) {
    int wave = threadIdx.x >> 6, lane = threadIdx.x & 63;
    int n = blockIdx.x * 4 + wave;
    if (n >= M) return;
    float acc = 0.f;
    for (int k = 0; k < H_DIM; k++) acc += h[n * H_DIM + k] * cf1[k * F_DIM + lane];
    x[n * F_DIM + lane] = acc;
    aggz[n * F_DIM + lane] = 0.f;
}

// ---------------- edge filter: table lookup ----------------
__global__ __launch_bounds__(256) void k_edge_s(const int4* edat, const float* x,
                                                const float* __restrict__ wtab,
                                                float* agg) {
    int t = threadIdx.x, wave = t >> 6, lane = t & 63;
    int p0 = (blockIdx.x * 4 + wave) * EPW2;
    int curDst = -1;
    float acc = 0.f;
    for (int ee = 0; ee < EPW2; ee++) {
        int4 ed = edat[p0 + ee];
        int sI = ed.x, dI = ed.y;
        float d = __int_as_float(ed.z);
        float s = d * INV_DD;
        int b0 = min((int)s, NB - 2);
        float fr = s - b0;
        float w0 = wtab[b0 * F_DIM + lane];
        float w1 = wtab[(b0 + 1) * F_DIM + lane];
        float w = w0 + fr * (w1 - w0);
        float contrib = x[sI * F_DIM + lane] * w;
        if (dI != curDst) {
            if (curDst >= 0) atomicAdd(&agg[curDst * F_DIM + lane], acc);
            acc = 0.f;
            curDst = dI;
        }
        acc += contrib;
    }
    if (curDst >= 0) atomicAdd(&agg[curDst * F_DIM + lane], acc);
}

// ---------------- out = base + ssp(agg@cf2w + cf2b) @ lw + lb ----------------
__global__ __launch_bounds__(256) void k_update(const float* __restrict__ agg, const float* __restrict__ base,
                                                const float* cf2w, const float* cf2b,
                                                const float* lw, const float* lb,
                                                float* out, int M) {
    __shared__ float tbuf[4][H_DIM];
    int wave = threadIdx.x >> 6, lane = threadIdx.x & 63;
    int n = blockIdx.x * 4 + wave;
    float t0 = cf2b[lane], t1 = cf2b[lane + 64];
    if (n < M) {
        for (int f = 0; f < F_DIM; f++) {
            float a = agg[n * F_DIM + f];
            t0 += a * cf2w[f * H_DIM + lane];
            t1 += a * cf2w[f * H_DIM + lane + 64];
        }
    }
    tbuf[wave][lane] = ssp_f(t0);
    tbuf[wave][lane + 64] = ssp_f(t1);
    __syncthreads();
    if (n < M) {
        float o0 = lb[lane], o1 = lb[lane + 64];
        const float4* t4v = (const float4*)tbuf[wave];
        #pragma unroll
        for (int kk = 0; kk < 32; kk++) {
            float4 tq = t4v[kk];
            int k4 = kk * 4;
            o0 += tq.x * lw[(k4 + 0) * H_DIM + lane];
            o1 += tq.x * lw[(k4 + 0) * H_DIM + lane + 64];
            o0 += tq.y * lw[(k4 + 1) * H_DIM + lane];
            o1 += tq.y * lw[(k4 + 1) * H_DIM + lane + 64];
            o0 += tq.z * lw[(k4 + 2) * H_DIM + lane];
            o1 += tq.z * lw[(k4 + 2) * H_DIM + lane + 64];
            o0 += tq.w * lw[(k4 + 3) * H_DIM + lane];
            o1 += tq.w * lw[(k4 + 3) * H_DIM + lane + 64];
        }
        out[n * H_DIM + lane]      = base[n * H_DIM + lane] + o0;
        out[n * H_DIM + lane + 64] = base[n * H_DIM + lane + 64] + o1;
    }
}

// ---------------- node scores (exact: feeds top-K) ----------------
__global__ __launch_bounds__(256) void k_scores(const float* h_local,
                                                const float* msw1, const float* msb1,
                                                const float* msw2, const float* msb2,
                                                float* scores) {
    int n = blockIdx.x * 256 + threadIdx.x;
    if (n >= N_ATOMS) return;
    float hs[S_DIM];
    for (int s = 0; s < S_DIM; s++) hs[s] = h_local[n * H_DIM + s];
    float sc = msb2[0];
    for (int j = 0; j < MH_DIM; j++) {
        float v = msb1[j];
        for (int s = 0; s < S_DIM; s++) v += hs[s] * msw1[s * MH_DIM + j];
        sc += fmaxf(v, 0.f) * msw2[j];
    }
    scores[n] = sc;
}

// ---------------- parallel exact rank (+ kth-score capture) ----------------
__global__ __launch_bounds__(256) void k_rank(const float* scores, int* rank, float* kvbuf) {
    __shared__ float s[N_ATOMS];
    __shared__ int pc[16][17];
    int t = threadIdx.x;
    for (int i = t; i < N_ATOMS; i += 256) s[i] = scores[i];
    __syncthreads();
    int ii = t & 15, chunk = t >> 4;
    int i = blockIdx.x * 16 + ii;
    float si = s[i];
    int cnt = 0;
    int j0 = chunk * (N_ATOMS / 16);
    #pragma unroll 4
    for (int j = j0; j < j0 + N_ATOMS / 16; j++) {
        float sj = s[j];
        cnt += (sj > si) || (sj == si && j < i);
    }
    pc[chunk][ii] = cnt;
    __syncthreads();
    if (chunk == 0) {
        int r = 0;
        #pragma unroll
        for (int c = 0; c < 16; c++) r += pc[c][ii];
        rank[i] = r;
        if (r == K_TOP - 1) kvbuf[0] = si;
    }
}

// ---------------- parallel selection (pos = #{j<i: rank[j]<K}) ----------------
__global__ __launch_bounds__(256) void k_select2(const float* scores, const int* rank,
                                                 const float* kvbuf,
                                                 int* is_m, int* invg, int* midx, float* m) {
    __shared__ int rk[N_ATOMS];
    __shared__ int pc[16][17];
    int t = threadIdx.x;
    for (int i = t; i < N_ATOMS; i += 256) rk[i] = rank[i];
    __syncthreads();
    int ii = t & 15, chunk = t >> 4;
    int i = blockIdx.x * 16 + ii;
    int j0 = chunk * (N_ATOMS / 16);
    int cnt = 0;
    #pragma unroll 4
    for (int j = j0; j < j0 + N_ATOMS / 16; j++)
        cnt += (j < i && rk[j] < K_TOP);
    pc[chunk][ii] = cnt;
    __syncthreads();
    if (chunk == 0) {
        int pos = 0;
        #pragma unroll
        for (int c = 0; c < 16; c++) pos += pc[c][ii];
        int f = rk[i] < K_TOP;
        is_m[i] = f;
        invg[i] = f ? pos : 0;
        if (f) midx[pos] = i;
        m[i] = sigm_f(scores[i] - kvbuf[0] + 1e-6f);
    }
}

// ---------------- gather h_m / pos_m (+ zero adj and counters) ----------------
__global__ __launch_bounds__(256) void k_gather(const int* midx, const float* h_local,
                                                const float* pos, float* h_m, float* pos_m,
                                                unsigned char* adj, int* counters) {
    int i = blockIdx.x * 256 + threadIdx.x;
    int k = i >> 7, c = i & 127;
    int n = midx[k];
    h_m[i] = h_local[n * H_DIM + c];
    if (c < 3) pos_m[k * 3 + c] = pos[n * 3 + c];
    adj[i] = 0;
    if (i < 2) counters[i] = 0;
}

// ---------------- adjacency + packed valid-edge data (fused vdat) ----------------
__global__ __launch_bounds__(256) void k_adj(const int* src, const int* dst, const int* is_m,
                                             const int* invg, const float* pos_m,
                                             unsigned char* adj, int4* vdat, int* nve) {
    int e = blockIdx.x * 256 + threadIdx.x;
    int s = src[e], d = dst[e];
    bool valid = is_m[s] && is_m[d];
    int sm = valid ? invg[s] : 0;
    int dm = valid ? invg[d] : 0;
    if (valid) adj[sm * K_TOP + dm] = 1;
    unsigned long long mask = __ballot(valid);
    int lane = threadIdx.x & 63;
    int cnt = __popcll(mask);
    int base = 0;
    if (lane == 0 && cnt) base = atomicAdd(nve, cnt);
    base = __shfl(base, 0);
    if (valid) {
        int pos = base + __popcll(mask & ((1ull << lane) - 1));
        float dx = pos_m[sm * 3 + 0] - pos_m[dm * 3 + 0];
        float dy = pos_m[sm * 3 + 1] - pos_m[dm * 3 + 1];
        float dz = pos_m[sm * 3 + 2] - pos_m[dm * 3 + 2];
        float dist = sqrtf(dx * dx + dy * dy + dz * dz + 1e-12f);
        vdat[pos] = make_int4(sm, dm, __float_as_int(dist), 0);
    }
}

// ---------------- hij + qk fused (grid 256 + 64) ----------------
__global__ __launch_bounds__(256) void k_hijqk(const float* h_m, const float* aw1,
                                               const float* wq, const float* wk,
                                               float* hi, float* hj, float* qm, float* km) {
    if (blockIdx.x < 256) {
        int wave = threadIdx.x >> 6, lane = threadIdx.x & 63;
        int idx = blockIdx.x * 4 + wave;
        int which = idx >> 9;
        int r = idx & (K_TOP - 1);
        const float* W = aw1 + which * H_DIM * H_DIM;
        float o0 = 0.f, o1 = 0.f;
        for (int k = 0; k < H_DIM; k++) {
            float hv = h_m[r * H_DIM + k];
            o0 += hv * W[k * H_DIM + lane];
            o1 += hv * W[k * H_DIM + lane + 64];
        }
        float* out = which ? hj : hi;
        out[r * H_DIM + lane] = o0;
        out[r * H_DIM + lane + 64] = o1;
    } else {
        int gid = (blockIdx.x - 256) * 256 + threadIdx.x;
        int r = gid >> 5, t = gid & 31;
        const float* w = (t < 16) ? wq : wk;
        int c = t & 15;
        float acc = 0.f;
        for (int s = 0; s < S_DIM; s++) acc += h_m[r * H_DIM + s] * w[s * S_DIM + c];
        if (t < 16) qm[r * S_DIM + c] = acc; else km[r * S_DIM + c] = acc;
    }
}

// ---------------- attention softmax -> Av mask (exact) ----------------
__global__ __launch_bounds__(256) void k_attn(const float* qm, const float* km,
                                              const unsigned char* adj, unsigned char* Av) {
    __shared__ float lrow[K_TOP];
    __shared__ float red[256];
    int i = blockIdx.x, t = threadIdx.x;
    float q[S_DIM];
    for (int s = 0; s < S_DIM; s++) q[s] = qm[i * S_DIM + s];
    for (int j = t; j < K_TOP; j += 256) {
        float acc = 0.f;
        for (int s = 0; s < S_DIM; s++) acc += q[s] * km[j * S_DIM + s];
        lrow[j] = acc * 0.25f;
    }
    __syncthreads();
    float mx = -1e30f;
    for (int j = t; j < K_TOP; j += 256) mx = fmaxf(mx, lrow[j]);
    red[t] = mx; __syncthreads();
    for (int o = 128; o > 0; o >>= 1) { if (t < o) red[t] = fmaxf(red[t], red[t + o]); __syncthreads(); }
    mx = red[0]; __syncthreads();
    float sum = 0.f;
    for (int j = t; j < K_TOP; j += 256) sum += expf(lrow[j] - mx);
    red[t] = sum; __syncthreads();
    for (int o = 128; o > 0; o >>= 1) { if (t < o) red[t] += red[t + o]; __syncthreads(); }
    float inv_s = 1.f / red[0];
    for (int j = t; j < K_TOP; j += 256) {
        float a = expf(lrow[j] - mx) * inv_s;
        Av[i * K_TOP + j] = (a > LAMBDA) && (!adj[i * K_TOP + j]) && (i != j);
    }
}

// ---------------- deterministic j-major pair compaction ----------------
__global__ __launch_bounds__(256) void k_pcount(const unsigned char* Av, int* bcount) {
    __shared__ int wsum[4];
    int idx = blockIdx.x * 256 + threadIdx.x;
    int j = idx >> 9, i = idx & (K_TOP - 1);
    bool act = Av[i * K_TOP + j] != 0;
    unsigned long long mask = __ballot(act);
    int lane = threadIdx.x & 63, wave = threadIdx.x >> 6;
    if (lane == 0) wsum[wave] = __popcll(mask);
    __syncthreads();
    if (threadIdx.x == 0) bcount[blockIdx.x] = wsum[0] + wsum[1] + wsum[2] + wsum[3];
}

__global__ __launch_bounds__(1024) void k_pscan(const int* bcount, int* boffset, int* total) {
    __shared__ int bufA[1024], bufB[1024];
    int t = threadIdx.x;
    bufA[t] = bcount[t];
    __syncthreads();
    int* in = bufA;
    int* out = bufB;
    for (int d = 1; d < 1024; d <<= 1) {
        out[t] = in[t] + (t >= d ? in[t - d] : 0);
        __syncthreads();
        int* tmp = in; in = out; out = tmp;
    }
    boffset[t] = in[t] - bcount[t];
    if (t == 1023) total[0] = in[1023];
}

// ---------------- scatter plist + fused sd {key, dist} ----------------
__global__ __launch_bounds__(256) void k_pscatter(const unsigned char* Av, const int* boffset,
                                                  const float* pos_m,
                                                  unsigned int* plist, float2* sd) {
    __shared__ int wsum[4], woff[4];
    int idx = blockIdx.x * 256 + threadIdx.x;
    int j = idx >> 9, i = idx & (K_TOP - 1);
    bool act = Av[i * K_TOP + j] != 0;
    unsigned long long mask = __ballot(act);
    int lane = threadIdx.x & 63, wave = threadIdx.x >> 6;
    if (lane == 0) wsum[wave] = __popcll(mask);
    __syncthreads();
    if (threadIdx.x == 0) {
        int s = 0;
        for (int w = 0; w < 4; w++) { woff[w] = s; s += wsum[w]; }
    }
    __syncthreads();
    if (act) {
        int pos = boffset[blockIdx.x] + woff[wave] + __popcll(mask & ((1ull << lane) - 1));
        unsigned int key = ((unsigned int)j << 9) | (unsigned int)i;
        plist[pos] = key;
        float dx = pos_m[i * 3 + 0] - pos_m[j * 3 + 0];
        float dy = pos_m[i * 3 + 1] - pos_m[j * 3 + 1];
        float dz = pos_m[i * 3 + 2] - pos_m[j * 3 + 2];
        float dd = sqrtf(dx * dx + dy * dy + dz * dz + 1e-12f);
        sd[pos] = make_float2(__uint_as_float(key), dd);
    }
}

// ---------------- per-pair attention scores: ztabS lookup ----------------
__global__ __launch_bounds__(256) void k_score_p(const float2* sd, const int* npairs,
                                                 const float* hi, const float* hj,
                                                 const float* __restrict__ ztabS,
                                                 const float* ab1, const float* aw2, const float* ab2,
                                                 float* sbuf) {
    int t = threadIdx.x, wave = t >> 6, lane = t & 63;
    float ab0 = ab1[lane], ab1v = ab1[lane + 64];
    float aw0 = aw2[lane], aw1v = aw2[lane + 64];
    float b2 = ab2[0];
    int n = npairs[0];
    int wid = blockIdx.x * 4 + wave;
    int nw = gridDim.x * 4;
    for (int p = wid; p < n; p += nw) {
        float2 s2 = sd[p];
        unsigned int key = __float_as_uint(s2.x);
        float dd = s2.y;
        int j = key >> 9, i = key & (K_TOP - 1);
        int ij = i * K_TOP + j;
        float s = dd * INV_DD;
        int b0 = min((int)s, NB - 2);
        float fr = s - b0;
        const float* r0 = ztabS + b0 * H_DIM;
        const float* r1 = r0 + H_DIM;
        float z0a = r0[lane],      z1a = r1[lane];
        float z0b = r0[lane + 64], z1b = r1[lane + 64];
        float zs0 = z0a + fr * (z1a - z0a);
        float zs1 = z0b + fr * (z1b - z0b);
        float v0 = hi[i * H_DIM + lane] + hj[j * H_DIM + lane] + ab0 + zs0;
        float v1 = hi[i * H_DIM + lane + 64] + hj[j * H_DIM + lane + 64] + ab1v + zs1;
        float pv = fmaxf(v0, 0.f) * aw0 + fmaxf(v1, 0.f) * aw1v;
        for (int o = 1; o < 64; o <<= 1) pv += __shfl_xor(pv, o);
        if (lane == 0) sbuf[ij] = pv + b2;
    }
}

// ---------------- row softmax (Av-guarded) -> decay (exact) ----------------
__global__ __launch_bounds__(256) void k_decay(const float* sbuf, const unsigned char* Av, float* decay) {
    __shared__ float srow[K_TOP];
    __shared__ float red[256];
    int i = blockIdx.x, t = threadIdx.x;
    for (int j = t; j < K_TOP; j += 256)
        srow[j] = Av[i * K_TOP + j] ? sbuf[i * K_TOP + j] : -1e9f;
    __syncthreads();
    float mx = -1e30f;
    for (int j = t; j < K_TOP; j += 256) mx = fmaxf(mx, srow[j]);
    red[t] = mx; __syncthreads();
    for (int o = 128; o > 0; o >>= 1) { if (t < o) red[t] = fmaxf(red[t], red[t + o]); __syncthreads(); }
    mx = red[0]; __syncthreads();
    float sum = 0.f;
    for (int j = t; j < K_TOP; j += 256) sum += (srow[j] > -5e8f) ? expf(srow[j] - mx) : 0.f;
    red[t] = sum; __syncthreads();
    for (int o = 128; o > 0; o >>= 1) { if (t < o) red[t] += red[t + o]; __syncthreads(); }
    float s_total = red[0];
    float inv_s = (s_total > 0.f) ? 1.f / s_total : 0.f;
    for (int j = t; j < K_TOP; j += 256)
        decay[i * K_TOP + j] = (srow[j] > -5e8f) ? expf(srow[j] - mx) * inv_s : 0.f;
}

// ---------------- packed pair data for aggd: {key, dd, dec} ----------------
__global__ __launch_bounds__(256) void k_pdat(const float2* sd, const int* npairs,
                                              const float* decay, float4* pd) {
    int n = npairs[0];
    for (int p = blockIdx.x * 256 + threadIdx.x; p < n; p += gridDim.x * 256) {
        float2 s2 = sd[p];
        unsigned int key = __float_as_uint(s2.x);
        int j = key >> 9, i = key & (K_TOP - 1);
        pd[p] = make_float4(s2.x, s2.y, decay[i * K_TOP + j], 0.f);
    }
}

// ---------------- agg_d: z1 table + second layer, short chunks ----------------
__global__ __launch_bounds__(256) void k_aggd_p2(const float4* pd, const int* npairs,
                                                 const float* xm,
                                                 const float* __restrict__ z1tab,
                                                 const float* mb1,
                                                 const float* mw2, const float* mb2,
                                                 float* agg_m) {
    __shared__ float tbuf[4][F_DIM];
    int t = threadIdx.x, wave = t >> 6, lane = t & 63;
    float w2r[F_DIM];
    #pragma unroll
    for (int k = 0; k < F_DIM; k++) w2r[k] = mw2[k * F_DIM + lane];
    float b1 = mb1[lane], b2v = mb2[lane];
    int n = npairs[0];
    int nchunks = (n + PCHUNK - 1) / PCHUNK;
    int wid = blockIdx.x * 4 + wave;
    int nw = gridDim.x * 4;
    for (int c = wid; c < nchunks; c += nw) {
        int p0 = c * PCHUNK;
        int p1 = min(p0 + PCHUNK, n);
        int curJ = -1;
        float acc = 0.f;
        for (int p = p0; p < p1; p++) {
            float4 q = pd[p];
            unsigned int key = __float_as_uint(q.x);
            float dd = q.y, dec = q.z;
            int j = key >> 9, i = key & (K_TOP - 1);
            float s = dd * INV_DD;
            int b0 = min((int)s, NB - 2);
            float fr = s - b0;
            float z0 = z1tab[b0 * F_DIM + lane];
            float z1 = z1tab[(b0 + 1) * F_DIM + lane];
            float z1v = z0 + fr * (z1 - z0);
            float tv = ssp_fast(dec * z1v + b1);
            tbuf[wave][lane] = tv;
            float w = b2v;
            const float4* t4v = (const float4*)tbuf[wave];
            #pragma unroll
            for (int kk = 0; kk < 16; kk++) {
                float4 tq = t4v[kk];
                w += tq.x * w2r[4 * kk + 0];
                w += tq.y * w2r[4 * kk + 1];
                w += tq.z * w2r[4 * kk + 2];
                w += tq.w * w2r[4 * kk + 3];
            }
            float contrib = xm[i * F_DIM + lane] * w * ccut_fast(dd);
            if (j != curJ) {
                if (curJ >= 0) atomicAdd(&agg_m[curJ * F_DIM + lane], acc);
                acc = 0.f;
                curJ = j;
            }
            acc += contrib;
        }
        if (curJ >= 0) atomicAdd(&agg_m[curJ * F_DIM + lane], acc);
    }
}

// ---------------- valid-edge filter: table lookup ----------------
__global__ __launch_bounds__(256) void k_aggs_p(const int4* vdat, const int* nve,
                                                const float* xm,
                                                const float* __restrict__ wtab,
                                                float* agg_m) {
    int t = threadIdx.x, wave = t >> 6, lane = t & 63;
    int n = nve[0];
    int wid = blockIdx.x * 4 + wave;
    int nw = gridDim.x * 4;
    for (int p = wid; p < n; p += nw) {
        int4 vd = vdat[p];
        int sm = vd.x, dm = vd.y;
        float d = __int_as_float(vd.z);
        float s = d * INV_DD;
        int b0 = min((int)s, NB - 2);
        float fr = s - b0;
        float w0 = wtab[b0 * F_DIM + lane];
        float w1 = wtab[(b0 + 1) * F_DIM + lane];
        float w = w0 + fr * (w1 - w0);
        atomicAdd(&agg_m[dm * F_DIM + lane], xm[sm * F_DIM + lane] * w);
    }
}

// ---------------- blend ----------------
__global__ __launch_bounds__(256) void k_blend(const float* h_local, const float* h_hier,
                                               const int* is_m, const int* invg, const float* m,
                                               float* h_out) {
    int idx = blockIdx.x * 256 + threadIdx.x;
    int n = idx >> 7, c = idx & 127;
    float mm = m[n];
    float hh = is_m[n] ? h_hier[invg[n] * H_DIM + c] : 0.f;
    h_out[idx] = (1.f - mm) * h_local[idx] + mm * hh;
}

// ---------------- parallel segment-sum pooling ----------------
__global__ __launch_bounds__(256) void k_pool(const float* __restrict__ h, const int* __restrict__ batch,
                                              float* pooled) {
    int c = threadIdx.x & 127, a = threadIdx.x >> 7;
    int n0 = blockIdx.x * 64;
    float acc = 0.f;
    int cur = batch[n0 + a];
    for (int i = a; i < 64; i += 2) {
        int n = n0 + i;
        int b = batch[n];
        if (b != cur) { atomicAdd(&pooled[cur * H_DIM + c], acc); acc = 0.f; cur = b; }
        acc += h[n * H_DIM + c];
    }
    atomicAdd(&pooled[cur * H_DIM + c], acc);
}

// ---------------- predict MLP ----------------
__global__ __launch_bounds__(128) void k_pred2(const float* pooled,
                                               const float* w1, const float* b1,
                                               const float* w2, const float* b2,
                                               void* outv, const int* flag) {
    __shared__ float c64[64];
    int b = blockIdx.x, t = threadIdx.x;
    if (t < 64) {
        float v = b1[t];
        for (int k = 0; k < H_DIM; k++) v += pooled[b * H_DIM + k] * w1[k * 64 + t];
        c64[t] = v * sigm_f(v);
    }
    __syncthreads();
    if (t == 0) {
        float o = b2[0];
        for (int k = 0; k < 64; k++) o += c64[k] * w2[k];
        if (flag[0]) ((float*)outv)[b] = o;
        else ((__hip_bfloat16*)outv)[b] = __float2bfloat16(o);
    }
}

extern "C" void kernel_launch(void* const* d_in, const int* in_sizes, int n_in,
                              void* d_out, int out_size, void* d_ws, size_t ws_size,
                              hipStream_t stream) {
    (void)n_in; (void)out_size; (void)ws_size;
    const int* atoms = (const int*)d_in[0];
    const int* src = (const int*)d_in[2];
    const int* dst = (const int*)d_in[3];
    const int* batch = (const int*)d_in[4];

    float* W = (float*)d_ws;
    int* dflag = (int*)W; W += 16;
    int* counters = (int*)W; W += 16;  // [0]=npairs, [1]=nve
    float* kvbuf = (float*)(counters + 4);

    static const int fidx[25] = {1,5,6,7,8,9,10,11,12,13,14,15,16,17,18,19,20,21,22,23,24,25,26,27,28};
    float* fin[29];
    ConvArgs ca;
    float* convBase = W;
    int off = 0;
    for (int q = 0; q < 25; q++) {
        int i = fidx[q];
        ca.p[q] = d_in[i];
        ca.off[q] = off;
        fin[i] = convBase + off;
        off += in_sizes[i];
    }
    ca.off[25] = off;
    W += off;

    k_detect<<<1, 256, 0, stream>>>((const unsigned short*)d_in[5], in_sizes[5], dflag);
    k_convert_all<<<(off + 255) / 256, 256, 0, stream>>>(ca, convBase, dflag);

    const float* posf = fin[1];
    const float* embf = fin[5];

    float* h      = W; W += N_ATOMS * H_DIM;
    float* h_loc  = W; W += N_ATOMS * H_DIM;
    float* xbuf   = W; W += N_ATOMS * F_DIM;
    float* aggbuf = W; W += N_ATOMS * F_DIM;
    float* scores = W; W += N_ATOMS;
    float* mbuf   = W; W += N_ATOMS;
    float* h_m    = W; W += K_TOP * H_DIM;
    float* pos_m  = W; W += K_TOP * 3;
    float* xm     = W; W += K_TOP * F_DIM;
    float* qm     = W; W += K_TOP * S_DIM;
    float* km     = W; W += K_TOP * S_DIM;
    float* decay  = W; W += K_TOP * K_TOP;
    float* sbuf   = W; W += K_TOP * K_TOP;
    float* hi     = W; W += K_TOP * H_DIM;
    float* hj     = W; W += K_TOP * H_DIM;
    float* agg_m  = W; W += K_TOP * F_DIM;
    float* h_hier = W; W += K_TOP * H_DIM;
    float* pooled = W; W += B_BATCH * H_DIM;
    float* z1tab  = W; W += NB * F_DIM;
    float* wtab   = W; W += NB * F_DIM;
    float* ztabS  = W; W += NB * H_DIM;
    int* rankb  = (int*)W; W += N_ATOMS;
    int* is_m   = (int*)W; W += N_ATOMS;
    int* invg   = (int*)W; W += N_ATOMS;
    int* midx   = (int*)W; W += K_TOP;
    unsigned int* plist = (unsigned int*)W; W += K_TOP * K_TOP;
    int* esorted = (int*)W; W += E_EDGES;
    int* ehist  = (int*)W; W += N_ATOMS;
    int* ebase  = (int*)W; W += N_ATOMS;
    int* ecur   = (int*)W; W += N_ATOMS;
    int* bcount = (int*)W; W += 1024;
    int* boffset = (int*)W; W += 1024;
    int4* edat  = (int4*)W; W += E_EDGES * 4;
    int4* vdat  = (int4*)W; W += E_EDGES * 4;
    float2* sd  = (float2*)W; W += K_TOP * K_TOP * 2;
    float4* pd  = (float4*)W; W += K_TOP * K_TOP * 4;
    unsigned char* adj = (unsigned char*)W; W += (K_TOP * K_TOP) / 4;
    unsigned char* Av  = (unsigned char*)W; W += (K_TOP * K_TOP) / 4;

    // one-time: counting-sort edges by dst + packed edge data
    (void)hipMemsetAsync(ehist, 0, N_ATOMS * sizeof(int), stream);
    k_ehist<<<E_EDGES / 256, 256, 0, stream>>>(dst, ehist);
    k_escan<<<1, 1024, 0, stream>>>(ehist, ebase, ecur);
    k_escatter<<<E_EDGES / 256, 256, 0, stream>>>(dst, ecur, esorted);
    k_edat<<<E_EDGES / 256, 256, 0, stream>>>(esorted, src, dst, posf, edat);

    k_embed<<<(N_ATOMS * H_DIM) / 256, 256, 0, stream>>>(atoms, embf, h);

    for (int l = 0; l < L_LAYERS; l++) {
        const float* mw1 = fin[6]  + l * G_DIM * F_DIM;
        const float* mb1 = fin[7]  + l * F_DIM;
        const float* mw2 = fin[8]  + l * F_DIM * F_DIM;
        const float* mb2 = fin[9]  + l * F_DIM;
        const float* cf1 = fin[10] + l * H_DIM * F_DIM;
        const float* cf2w = fin[11] + l * F_DIM * H_DIM;
        const float* cf2b = fin[12] + l * H_DIM;
        const float* lw  = fin[13] + l * H_DIM * H_DIM;
        const float* lb  = fin[14] + l * H_DIM;
        const float* aw1 = fin[15] + l * (2 * H_DIM + G_DIM) * H_DIM;
        const float* ab1 = fin[16] + l * H_DIM;
        const float* aw2 = fin[17] + l * H_DIM;
        const float* ab2 = fin[18] + l;
        const float* msw1 = fin[19] + l * S_DIM * MH_DIM;
        const float* msb1 = fin[20] + l * MH_DIM;
        const float* msw2 = fin[21] + l * MH_DIM;
        const float* msb2 = fin[22] + l;
        const float* wq  = fin[23] + l * S_DIM * S_DIM;
        const float* wk  = fin[24] + l * S_DIM * S_DIM;

        k_ftab<<<NB, 128, 0, stream>>>(mw1, mb1, mw2, mb2, aw1, z1tab, wtab, ztabS);
        k_x<<<N_ATOMS / 4, 256, 0, stream>>>(h, cf1, xbuf, aggbuf, N_ATOMS);
        k_edge_s<<<E_EDGES / (4 * EPW2), 256, 0, stream>>>(edat, xbuf, wtab, aggbuf);
        k_update<<<N_ATOMS / 4, 256, 0, stream>>>(aggbuf, h, cf2w, cf2b, lw, lb, h_loc, N_ATOMS);
        k_scores<<<N_ATOMS / 256, 256, 0, stream>>>(h_loc, msw1, msb1, msw2, msb2, scores);
        k_rank<<<N_ATOMS / 16, 256, 0, stream>>>(scores, rankb, kvbuf);
        k_select2<<<N_ATOMS / 16, 256, 0, stream>>>(scores, rankb, kvbuf, is_m, invg, midx, mbuf);
        k_gather<<<(K_TOP * H_DIM) / 256, 256, 0, stream>>>(midx, h_loc, posf, h_m, pos_m, adj, counters);
        k_x<<<K_TOP / 4, 256, 0, stream>>>(h_m, cf1, xm, agg_m, K_TOP);
        k_adj<<<E_EDGES / 256, 256, 0, stream>>>(src, dst, is_m, invg, pos_m, adj, vdat, counters + 1);
        k_hijqk<<<320, 256, 0, stream>>>(h_m, aw1, wq, wk, hi, hj, qm, km);
        k_attn<<<K_TOP, 256, 0, stream>>>(qm, km, adj, Av);
        k_pcount<<<(K_TOP * K_TOP) / 256, 256, 0, stream>>>(Av, bcount);
        k_pscan<<<1, 1024, 0, stream>>>(bcount, boffset, counters);
        k_pscatter<<<(K_TOP * K_TOP) / 256, 256, 0, stream>>>(Av, boffset, pos_m, plist, sd);
        k_score_p<<<1024, 256, 0, stream>>>(sd, counters, hi, hj, ztabS, ab1, aw2, ab2, sbuf);
        k_decay<<<K_TOP, 256, 0, stream>>>(sbuf, Av, decay);
        k_pdat<<<512, 256, 0, stream>>>(sd, counters, decay, pd);
        k_aggd_p2<<<4096, 256, 0, stream>>>(pd, counters, xm, z1tab, mb1, mw2, mb2, agg_m);
        k_aggs_p<<<256, 256, 0, stream>>>(vdat, counters + 1, xm, wtab, agg_m);
        k_update<<<K_TOP / 4, 256, 0, stream>>>(agg_m, h_m, cf2w, cf2b, lw, lb, h_hier, K_TOP);
        k_blend<<<(N_ATOMS * H_DIM) / 256, 256, 0, stream>>>(h_loc, h_hier, is_m, invg, mbuf, h);
    }

    (void)hipMemsetAsync(pooled, 0, B_BATCH * H_DIM * sizeof(float), stream);
    k_pool<<<N_ATOMS / 64, 256, 0, stream>>>(h, batch, pooled);
    k_pred2<<<B_BATCH, 128, 0, stream>>>(pooled, fin[25], fin[26], fin[27], fin[28], d_out, dflag);
}

// Round 20
// 357.832 us; speedup vs baseline: 4.5130x; 1.0075x over previous
//
#include <hip/hip_runtime.h>
#include <hip/hip_bf16.h>
#include <math.h>

#define N_ATOMS 2048
#define E_EDGES 65536
#define B_BATCH 8
#define H_DIM 128
#define G_DIM 50
#define F_DIM 64
#define S_DIM 16
#define MH_DIM 32
#define K_TOP 512
#define L_LAYERS 2
#define EPW2 8
#define PCHUNK 8
#define NB 4096
#define DD 0.015625f
#define INV_DD 64.0f

static constexpr float STEP   = 10.0f / 49.0f;
static constexpr float COEFF  = -12.005f;
static constexpr float PI10   = 0.31415926535897931f;
static constexpr float LN2    = 0.69314718055994531f;
static constexpr float LAMBDA = 0.002f;

#define DEV static __device__ __forceinline__

DEV float ssp_f(float x) { return fmaxf(x, 0.f) + log1pf(expf(-fabsf(x))) - LN2; }
DEV float ccut_f(float d) { return 0.5f * (cosf(d * PI10) + 1.f); }
DEV float sigm_f(float x) { return 1.f / (1.f + expf(-x)); }
DEV float ssp_fast(float x) { return fmaxf(x, 0.f) + __logf(1.f + __expf(-fabsf(x))) - LN2; }
DEV float ccut_fast(float d) { return 0.5f * (__cosf(d * PI10) + 1.f); }

// ---------------- dtype detect ----------------
__global__ __launch_bounds__(256) void k_detect(const unsigned short* raw, int n, int* flag) {
    __shared__ int any;
    if (threadIdx.x == 0) any = 0;
    __syncthreads();
    for (int i = threadIdx.x; i < n; i += 256) {
        unsigned int bits = ((unsigned int)raw[i]) << 16;
        float f = __uint_as_float(bits);
        if (!(fabsf(f) <= 1e10f)) any = 1;
    }
    __syncthreads();
    if (threadIdx.x == 0) flag[0] = any;
}

// ---------------- fused convert ----------------
struct ConvArgs {
    const void* p[25];
    int off[26];
};

__global__ __launch_bounds__(256) void k_convert_all(ConvArgs a, float* dst, const int* flag) {
    int i = blockIdx.x * 256 + threadIdx.x;
    int total = a.off[25];
    if (i >= total) return;
    int seg = 0;
    while (i >= a.off[seg + 1]) seg++;
    int k = i - a.off[seg];
    if (flag[0]) {
        dst[i] = ((const float*)a.p[seg])[k];
    } else {
        unsigned int bits = ((unsigned int)((const unsigned short*)a.p[seg])[k]) << 16;
        dst[i] = __uint_as_float(bits);
    }
}

// ---------------- edge counting-sort by dst ----------------
__global__ __launch_bounds__(256) void k_ehist(const int* dst, int* hist) {
    int e = blockIdx.x * 256 + threadIdx.x;
    atomicAdd(&hist[dst[e]], 1);
}

__global__ __launch_bounds__(1024) void k_escan(const int* hist, int* ebase, int* ecur) {
    __shared__ int bufA[N_ATOMS], bufB[N_ATOMS];
    int t = threadIdx.x;
    for (int i = t; i < N_ATOMS; i += 1024) bufA[i] = hist[i];
    __syncthreads();
    int* in = bufA;
    int* out = bufB;
    for (int d = 1; d < N_ATOMS; d <<= 1) {
        for (int i = t; i < N_ATOMS; i += 1024) out[i] = in[i] + (i >= d ? in[i - d] : 0);
        __syncthreads();
        int* tmp = in; in = out; out = tmp;
    }
    for (int i = t; i < N_ATOMS; i += 1024) {
        int ex = in[i] - hist[i];
        ebase[i] = ex;
        ecur[i] = ex;
    }
}

__global__ __launch_bounds__(256) void k_escatter(const int* dst, int* ecur, int* esorted) {
    int e = blockIdx.x * 256 + threadIdx.x;
    int pos = atomicAdd(&ecur[dst[e]], 1);
    esorted[pos] = e;
}

// ---------------- one-time packed edge data {src, dst, dist} ----------------
__global__ __launch_bounds__(256) void k_edat(const int* esorted, const int* src, const int* dst,
                                              const float* pos, int4* edat) {
    int p = blockIdx.x * 256 + threadIdx.x;
    int e = esorted[p];
    int s = src[e], d = dst[e];
    float dx = pos[s * 3 + 0] - pos[d * 3 + 0];
    float dy = pos[s * 3 + 1] - pos[d * 3 + 1];
    float dz = pos[s * 3 + 2] - pos[d * 3 + 2];
    float dist = sqrtf(dx * dx + dy * dy + dz * dz + 1e-12f);
    edat[p] = make_int4(s, d, __float_as_int(dist), 0);
}

// ---------------- per-layer filter tables (exact math, 4096 bins) ----------------
__global__ __launch_bounds__(128) void k_ftab(const float* mw1, const float* mb1,
                                              const float* mw2, const float* mb2,
                                              const float* aw1,
                                              float* z1tab, float* wtab, float* ztabS) {
    __shared__ float gs[G_DIM];
    __shared__ float tb[F_DIM];
    int b = blockIdx.x, t = threadIdx.x;
    float d = b * DD;
    if (t < G_DIM) { float u = d - t * STEP; gs[t] = expf(COEFF * u * u); }
    __syncthreads();
    const float* wd = aw1 + 2 * H_DIM * H_DIM;
    float zs = 0.f;
    for (int g = 0; g < G_DIM; g++) zs += gs[g] * wd[g * H_DIM + t];
    ztabS[b * H_DIM + t] = zs;
    if (t < F_DIM) {
        float z1 = 0.f;
        for (int g = 0; g < G_DIM; g++) z1 += gs[g] * mw1[g * F_DIM + t];
        z1tab[b * F_DIM + t] = z1;
        tb[t] = ssp_f(z1 + mb1[t]);
    }
    __syncthreads();
    if (t < F_DIM) {
        float w = mb2[t];
        for (int k = 0; k < F_DIM; k++) w += tb[k] * mw2[k * F_DIM + t];
        wtab[b * F_DIM + t] = w * ccut_f(d);
    }
}

// ---------------- embedding ----------------
__global__ __launch_bounds__(256) void k_embed(const int* atoms, const float* emb, float* h) {
    int i = blockIdx.x * 256 + threadIdx.x;
    int n = i >> 7, c = i & 127;
    h[i] = emb[atoms[n] * H_DIM + c];
}

// ---------------- x = h @ cf1 (+ zero agg buffer of same shape) ----------------
__global__ __launch_bounds__(256) void k_x(const float* __restrict__ h, const float* __restrict__ cf1,
                                           float* __restrict__ x, float* __restrict__ aggz, int M) {
    int wave = threadIdx.x >> 6, lane = threadIdx.x & 63;
    int n = blockIdx.x * 4 + wave;
    if (n >= M) return;
    float acc = 0.f;
    for (int k = 0; k < H_DIM; k++) acc += h[n * H_DIM + k] * cf1[k * F_DIM + lane];
    x[n * F_DIM + lane] = acc;
    aggz[n * F_DIM + lane] = 0.f;
}

// ---------------- edge filter: table lookup ----------------
__global__ __launch_bounds__(256) void k_edge_s(const int4* edat, const float* x,
                                                const float* __restrict__ wtab,
                                                float* agg) {
    int t = threadIdx.x, wave = t >> 6, lane = t & 63;
    int p0 = (blockIdx.x * 4 + wave) * EPW2;
    int curDst = -1;
    float acc = 0.f;
    for (int ee = 0; ee < EPW2; ee++) {
        int4 ed = edat[p0 + ee];
        int sI = ed.x, dI = ed.y;
        float d = __int_as_float(ed.z);
        float s = d * INV_DD;
        int b0 = min((int)s, NB - 2);
        float fr = s - b0;
        float w0 = wtab[b0 * F_DIM + lane];
        float w1 = wtab[(b0 + 1) * F_DIM + lane];
        float w = w0 + fr * (w1 - w0);
        float contrib = x[sI * F_DIM + lane] * w;
        if (dI != curDst) {
            if (curDst >= 0) atomicAdd(&agg[curDst * F_DIM + lane], acc);
            acc = 0.f;
            curDst = dI;
        }
        acc += contrib;
    }
    if (curDst >= 0) atomicAdd(&agg[curDst * F_DIM + lane], acc);
}

// ---------------- out = base + ssp(agg@cf2w + cf2b) @ lw + lb ----------------
__global__ __launch_bounds__(256) void k_update(const float* __restrict__ agg, const float* __restrict__ base,
                                                const float* cf2w, const float* cf2b,
                                                const float* lw, const float* lb,
                                                float* out, int M) {
    __shared__ float tbuf[4][H_DIM];
    int wave = threadIdx.x >> 6, lane = threadIdx.x & 63;
    int n = blockIdx.x * 4 + wave;
    float t0 = cf2b[lane], t1 = cf2b[lane + 64];
    if (n < M) {
        for (int f = 0; f < F_DIM; f++) {
            float a = agg[n * F_DIM + f];
            t0 += a * cf2w[f * H_DIM + lane];
            t1 += a * cf2w[f * H_DIM + lane + 64];
        }
    }
    tbuf[wave][lane] = ssp_f(t0);
    tbuf[wave][lane + 64] = ssp_f(t1);
    __syncthreads();
    if (n < M) {
        float o0 = lb[lane], o1 = lb[lane + 64];
        const float4* t4v = (const float4*)tbuf[wave];
        #pragma unroll
        for (int kk = 0; kk < 32; kk++) {
            float4 tq = t4v[kk];
            int k4 = kk * 4;
            o0 += tq.x * lw[(k4 + 0) * H_DIM + lane];
            o1 += tq.x * lw[(k4 + 0) * H_DIM + lane + 64];
            o0 += tq.y * lw[(k4 + 1) * H_DIM + lane];
            o1 += tq.y * lw[(k4 + 1) * H_DIM + lane + 64];
            o0 += tq.z * lw[(k4 + 2) * H_DIM + lane];
            o1 += tq.z * lw[(k4 + 2) * H_DIM + lane + 64];
            o0 += tq.w * lw[(k4 + 3) * H_DIM + lane];
            o1 += tq.w * lw[(k4 + 3) * H_DIM + lane + 64];
        }
        out[n * H_DIM + lane]      = base[n * H_DIM + lane] + o0;
        out[n * H_DIM + lane + 64] = base[n * H_DIM + lane + 64] + o1;
    }
}

// ---------------- node scores (exact: feeds top-K) ----------------
__global__ __launch_bounds__(256) void k_scores(const float* h_local,
                                                const float* msw1, const float* msb1,
                                                const float* msw2, const float* msb2,
                                                float* scores) {
    int n = blockIdx.x * 256 + threadIdx.x;
    if (n >= N_ATOMS) return;
    float hs[S_DIM];
    for (int s = 0; s < S_DIM; s++) hs[s] = h_local[n * H_DIM + s];
    float sc = msb2[0];
    for (int j = 0; j < MH_DIM; j++) {
        float v = msb1[j];
        for (int s = 0; s < S_DIM; s++) v += hs[s] * msw1[s * MH_DIM + j];
        sc += fmaxf(v, 0.f) * msw2[j];
    }
    scores[n] = sc;
}

// ---------------- parallel exact rank (+ kth-score capture) ----------------
__global__ __launch_bounds__(256) void k_rank(const float* scores, int* rank, float* kvbuf) {
    __shared__ float s[N_ATOMS];
    __shared__ int pc[16][17];
    int t = threadIdx.x;
    for (int i = t; i < N_ATOMS; i += 256) s[i] = scores[i];
    __syncthreads();
    int ii = t & 15, chunk = t >> 4;
    int i = blockIdx.x * 16 + ii;
    float si = s[i];
    int cnt = 0;
    int j0 = chunk * (N_ATOMS / 16);
    #pragma unroll 4
    for (int j = j0; j < j0 + N_ATOMS / 16; j++) {
        float sj = s[j];
        cnt += (sj > si) || (sj == si && j < i);
    }
    pc[chunk][ii] = cnt;
    __syncthreads();
    if (chunk == 0) {
        int r = 0;
        #pragma unroll
        for (int c = 0; c < 16; c++) r += pc[c][ii];
        rank[i] = r;
        if (r == K_TOP - 1) kvbuf[0] = si;
    }
}

// ---------------- parallel selection (pos = #{j<i: rank[j]<K}) ----------------
__global__ __launch_bounds__(256) void k_select2(const float* scores, const int* rank,
                                                 const float* kvbuf,
                                                 int* is_m, int* invg, int* midx, float* m) {
    __shared__ int rk[N_ATOMS];
    __shared__ int pc[16][17];
    int t = threadIdx.x;
    for (int i = t; i < N_ATOMS; i += 256) rk[i] = rank[i];
    __syncthreads();
    int ii = t & 15, chunk = t >> 4;
    int i = blockIdx.x * 16 + ii;
    int j0 = chunk * (N_ATOMS / 16);
    int cnt = 0;
    #pragma unroll 4
    for (int j = j0; j < j0 + N_ATOMS / 16; j++)
        cnt += (j < i && rk[j] < K_TOP);
    pc[chunk][ii] = cnt;
    __syncthreads();
    if (chunk == 0) {
        int pos = 0;
        #pragma unroll
        for (int c = 0; c < 16; c++) pos += pc[c][ii];
        int f = rk[i] < K_TOP;
        is_m[i] = f;
        invg[i] = f ? pos : 0;
        if (f) midx[pos] = i;
        m[i] = sigm_f(scores[i] - kvbuf[0] + 1e-6f);
    }
}

// ---------------- gather h_m / pos_m (+ zero adj and counters) ----------------
__global__ __launch_bounds__(256) void k_gather(const int* midx, const float* h_local,
                                                const float* pos, float* h_m, float* pos_m,
                                                unsigned char* adj, int* counters) {
    int i = blockIdx.x * 256 + threadIdx.x;
    int k = i >> 7, c = i & 127;
    int n = midx[k];
    h_m[i] = h_local[n * H_DIM + c];
    if (c < 3) pos_m[k * 3 + c] = pos[n * 3 + c];
    adj[i] = 0;
    if (i < 2) counters[i] = 0;
}

// ---------------- adjacency + packed valid-edge data (fused vdat) ----------------
__global__ __launch_bounds__(256) void k_adj(const int* src, const int* dst, const int* is_m,
                                             const int* invg, const float* pos_m,
                                             unsigned char* adj, int4* vdat, int* nve) {
    int e = blockIdx.x * 256 + threadIdx.x;
    int s = src[e], d = dst[e];
    bool valid = is_m[s] && is_m[d];
    int sm = valid ? invg[s] : 0;
    int dm = valid ? invg[d] : 0;
    if (valid) adj[sm * K_TOP + dm] = 1;
    unsigned long long mask = __ballot(valid);
    int lane = threadIdx.x & 63;
    int cnt = __popcll(mask);
    int base = 0;
    if (lane == 0 && cnt) base = atomicAdd(nve, cnt);
    base = __shfl(base, 0);
    if (valid) {
        int pos = base + __popcll(mask & ((1ull << lane) - 1));
        float dx = pos_m[sm * 3 + 0] - pos_m[dm * 3 + 0];
        float dy = pos_m[sm * 3 + 1] - pos_m[dm * 3 + 1];
        float dz = pos_m[sm * 3 + 2] - pos_m[dm * 3 + 2];
        float dist = sqrtf(dx * dx + dy * dy + dz * dz + 1e-12f);
        vdat[pos] = make_int4(sm, dm, __float_as_int(dist), 0);
    }
}

// ---------------- hij + qk fused (grid 256 + 64) ----------------
__global__ __launch_bounds__(256) void k_hijqk(const float* h_m, const float* aw1,
                                               const float* wq, const float* wk,
                                               float* hi, float* hj, float* qm, float* km) {
    if (blockIdx.x < 256) {
        int wave = threadIdx.x >> 6, lane = threadIdx.x & 63;
        int idx = blockIdx.x * 4 + wave;
        int which = idx >> 9;
        int r = idx & (K_TOP - 1);
        const float* W = aw1 + which * H_DIM * H_DIM;
        float o0 = 0.f, o1 = 0.f;
        for (int k = 0; k < H_DIM; k++) {
            float hv = h_m[r * H_DIM + k];
            o0 += hv * W[k * H_DIM + lane];
            o1 += hv * W[k * H_DIM + lane + 64];
        }
        float* out = which ? hj : hi;
        out[r * H_DIM + lane] = o0;
        out[r * H_DIM + lane + 64] = o1;
    } else {
        int gid = (blockIdx.x - 256) * 256 + threadIdx.x;
        int r = gid >> 5, t = gid & 31;
        const float* w = (t < 16) ? wq : wk;
        int c = t & 15;
        float acc = 0.f;
        for (int s = 0; s < S_DIM; s++) acc += h_m[r * H_DIM + s] * w[s * S_DIM + c];
        if (t < 16) qm[r * S_DIM + c] = acc; else km[r * S_DIM + c] = acc;
    }
}

// ---------------- attention softmax -> Av mask (exact) ----------------
__global__ __launch_bounds__(256) void k_attn(const float* qm, const float* km,
                                              const unsigned char* adj, unsigned char* Av) {
    __shared__ float lrow[K_TOP];
    __shared__ float red[256];
    int i = blockIdx.x, t = threadIdx.x;
    float q[S_DIM];
    for (int s = 0; s < S_DIM; s++) q[s] = qm[i * S_DIM + s];
    for (int j = t; j < K_TOP; j += 256) {
        float acc = 0.f;
        for (int s = 0; s < S_DIM; s++) acc += q[s] * km[j * S_DIM + s];
        lrow[j] = acc * 0.25f;
    }
    __syncthreads();
    float mx = -1e30f;
    for (int j = t; j < K_TOP; j += 256) mx = fmaxf(mx, lrow[j]);
    red[t] = mx; __syncthreads();
    for (int o = 128; o > 0; o >>= 1) { if (t < o) red[t] = fmaxf(red[t], red[t + o]); __syncthreads(); }
    mx = red[0]; __syncthreads();
    float sum = 0.f;
    for (int j = t; j < K_TOP; j += 256) sum += expf(lrow[j] - mx);
    red[t] = sum; __syncthreads();
    for (int o = 128; o > 0; o >>= 1) { if (t < o) red[t] += red[t + o]; __syncthreads(); }
    float inv_s = 1.f / red[0];
    for (int j = t; j < K_TOP; j += 256) {
        float a = expf(lrow[j] - mx) * inv_s;
        Av[i * K_TOP + j] = (a > LAMBDA) && (!adj[i * K_TOP + j]) && (i != j);
    }
}

// ---------------- deterministic j-major pair compaction ----------------
__global__ __launch_bounds__(256) void k_pcount(const unsigned char* Av, int* bcount) {
    __shared__ int wsum[4];
    int idx = blockIdx.x * 256 + threadIdx.x;
    int j = idx >> 9, i = idx & (K_TOP - 1);
    bool act = Av[i * K_TOP + j] != 0;
    unsigned long long mask = __ballot(act);
    int lane = threadIdx.x & 63, wave = threadIdx.x >> 6;
    if (lane == 0) wsum[wave] = __popcll(mask);
    __syncthreads();
    if (threadIdx.x == 0) bcount[blockIdx.x] = wsum[0] + wsum[1] + wsum[2] + wsum[3];
}

__global__ __launch_bounds__(1024) void k_pscan(const int* bcount, int* boffset, int* total) {
    __shared__ int bufA[1024], bufB[1024];
    int t = threadIdx.x;
    bufA[t] = bcount[t];
    __syncthreads();
    int* in = bufA;
    int* out = bufB;
    for (int d = 1; d < 1024; d <<= 1) {
        out[t] = in[t] + (t >= d ? in[t - d] : 0);
        __syncthreads();
        int* tmp = in; in = out; out = tmp;
    }
    boffset[t] = in[t] - bcount[t];
    if (t == 1023) total[0] = in[1023];
}

// ---------------- scatter plist + fused sd {key, dist} ----------------
__global__ __launch_bounds__(256) void k_pscatter(const unsigned char* Av, const int* boffset,
                                                  const float* pos_m,
                                                  unsigned int* plist, float2* sd) {
    __shared__ int wsum[4], woff[4];
    int idx = blockIdx.x * 256 + threadIdx.x;
    int j = idx >> 9, i = idx & (K_TOP - 1);
    bool act = Av[i * K_TOP + j] != 0;
    unsigned long long mask = __ballot(act);
    int lane = threadIdx.x & 63, wave = threadIdx.x >> 6;
    if (lane == 0) wsum[wave] = __popcll(mask);
    __syncthreads();
    if (threadIdx.x == 0) {
        int s = 0;
        for (int w = 0; w < 4; w++) { woff[w] = s; s += wsum[w]; }
    }
    __syncthreads();
    if (act) {
        int pos = boffset[blockIdx.x] + woff[wave] + __popcll(mask & ((1ull << lane) - 1));
        unsigned int key = ((unsigned int)j << 9) | (unsigned int)i;
        plist[pos] = key;
        float dx = pos_m[i * 3 + 0] - pos_m[j * 3 + 0];
        float dy = pos_m[i * 3 + 1] - pos_m[j * 3 + 1];
        float dz = pos_m[i * 3 + 2] - pos_m[j * 3 + 2];
        float dd = sqrtf(dx * dx + dy * dy + dz * dz + 1e-12f);
        sd[pos] = make_float2(__uint_as_float(key), dd);
    }
}

// ---------------- per-pair attention scores: ztabS lookup ----------------
__global__ __launch_bounds__(256) void k_score_p(const float2* sd, const int* npairs,
                                                 const float* hi, const float* hj,
                                                 const float* __restrict__ ztabS,
                                                 const float* ab1, const float* aw2, const float* ab2,
                                                 float* sbuf) {
    int t = threadIdx.x, wave = t >> 6, lane = t & 63;
    float ab0 = ab1[lane], ab1v = ab1[lane + 64];
    float aw0 = aw2[lane], aw1v = aw2[lane + 64];
    float b2 = ab2[0];
    int n = npairs[0];
    int wid = blockIdx.x * 4 + wave;
    int nw = gridDim.x * 4;
    for (int p = wid; p < n; p += nw) {
        float2 s2 = sd[p];
        unsigned int key = __float_as_uint(s2.x);
        float dd = s2.y;
        int j = key >> 9, i = key & (K_TOP - 1);
        int ij = i * K_TOP + j;
        float s = dd * INV_DD;
        int b0 = min((int)s, NB - 2);
        float fr = s - b0;
        const float* r0 = ztabS + b0 * H_DIM;
        const float* r1 = r0 + H_DIM;
        float z0a = r0[lane],      z1a = r1[lane];
        float z0b = r0[lane + 64], z1b = r1[lane + 64];
        float zs0 = z0a + fr * (z1a - z0a);
        float zs1 = z0b + fr * (z1b - z0b);
        float v0 = hi[i * H_DIM + lane] + hj[j * H_DIM + lane] + ab0 + zs0;
        float v1 = hi[i * H_DIM + lane + 64] + hj[j * H_DIM + lane + 64] + ab1v + zs1;
        float pv = fmaxf(v0, 0.f) * aw0 + fmaxf(v1, 0.f) * aw1v;
        for (int o = 1; o < 64; o <<= 1) pv += __shfl_xor(pv, o);
        if (lane == 0) sbuf[ij] = pv + b2;
    }
}

// ---------------- row softmax (Av-guarded) -> decay (exact) ----------------
__global__ __launch_bounds__(256) void k_decay(const float* sbuf, const unsigned char* Av, float* decay) {
    __shared__ float srow[K_TOP];
    __shared__ float red[256];
    int i = blockIdx.x, t = threadIdx.x;
    for (int j = t; j < K_TOP; j += 256)
        srow[j] = Av[i * K_TOP + j] ? sbuf[i * K_TOP + j] : -1e9f;
    __syncthreads();
    float mx = -1e30f;
    for (int j = t; j < K_TOP; j += 256) mx = fmaxf(mx, srow[j]);
    red[t] = mx; __syncthreads();
    for (int o = 128; o > 0; o >>= 1) { if (t < o) red[t] = fmaxf(red[t], red[t + o]); __syncthreads(); }
    mx = red[0]; __syncthreads();
    float sum = 0.f;
    for (int j = t; j < K_TOP; j += 256) sum += (srow[j] > -5e8f) ? expf(srow[j] - mx) : 0.f;
    red[t] = sum; __syncthreads();
    for (int o = 128; o > 0; o >>= 1) { if (t < o) red[t] += red[t + o]; __syncthreads(); }
    float s_total = red[0];
    float inv_s = (s_total > 0.f) ? 1.f / s_total : 0.f;
    for (int j = t; j < K_TOP; j += 256)
        decay[i * K_TOP + j] = (srow[j] > -5e8f) ? expf(srow[j] - mx) * inv_s : 0.f;
}

// ---------------- packed pair data for aggd: {key, dd, dec} ----------------
__global__ __launch_bounds__(256) void k_pdat(const float2* sd, const int* npairs,
                                              const float* decay, float4* pd) {
    int n = npairs[0];
    for (int p = blockIdx.x * 256 + threadIdx.x; p < n; p += gridDim.x * 256) {
        float2 s2 = sd[p];
        unsigned int key = __float_as_uint(s2.x);
        int j = key >> 9, i = key & (K_TOP - 1);
        pd[p] = make_float4(s2.x, s2.y, decay[i * K_TOP + j], 0.f);
    }
}

// ---------------- agg_d: z1 table + second layer, short chunks ----------------
__global__ __launch_bounds__(256) void k_aggd_p2(const float4* pd, const int* npairs,
                                                 const float* xm,
                                                 const float* __restrict__ z1tab,
                                                 const float* mb1,
                                                 const float* mw2, const float* mb2,
                                                 float* agg_m) {
    __shared__ float tbuf[4][F_DIM];
    int t = threadIdx.x, wave = t >> 6, lane = t & 63;
    float w2r[F_DIM];
    #pragma unroll
    for (int k = 0; k < F_DIM; k++) w2r[k] = mw2[k * F_DIM + lane];
    float b1 = mb1[lane], b2v = mb2[lane];
    int n = npairs[0];
    int nchunks = (n + PCHUNK - 1) / PCHUNK;
    int wid = blockIdx.x * 4 + wave;
    int nw = gridDim.x * 4;
    for (int c = wid; c < nchunks; c += nw) {
        int p0 = c * PCHUNK;
        int p1 = min(p0 + PCHUNK, n);
        int curJ = -1;
        float acc = 0.f;
        for (int p = p0; p < p1; p++) {
            float4 q = pd[p];
            unsigned int key = __float_as_uint(q.x);
            float dd = q.y, dec = q.z;
            int j = key >> 9, i = key & (K_TOP - 1);
            float s = dd * INV_DD;
            int b0 = min((int)s, NB - 2);
            float fr = s - b0;
            float z0 = z1tab[b0 * F_DIM + lane];
            float z1 = z1tab[(b0 + 1) * F_DIM + lane];
            float z1v = z0 + fr * (z1 - z0);
            float tv = ssp_fast(dec * z1v + b1);
            tbuf[wave][lane] = tv;
            float w = b2v;
            const float4* t4v = (const float4*)tbuf[wave];
            #pragma unroll
            for (int kk = 0; kk < 16; kk++) {
                float4 tq = t4v[kk];
                w += tq.x * w2r[4 * kk + 0];
                w += tq.y * w2r[4 * kk + 1];
                w += tq.z * w2r[4 * kk + 2];
                w += tq.w * w2r[4 * kk + 3];
            }
            float contrib = xm[i * F_DIM + lane] * w * ccut_fast(dd);
            if (j != curJ) {
                if (curJ >= 0) atomicAdd(&agg_m[curJ * F_DIM + lane], acc);
                acc = 0.f;
                curJ = j;
            }
            acc += contrib;
        }
        if (curJ >= 0) atomicAdd(&agg_m[curJ * F_DIM + lane], acc);
    }
}

// ---------------- valid-edge filter: table lookup ----------------
__global__ __launch_bounds__(256) void k_aggs_p(const int4* vdat, const int* nve,
                                                const float* xm,
                                                const float* __restrict__ wtab,
                                                float* agg_m) {
    int t = threadIdx.x, wave = t >> 6, lane = t & 63;
    int n = nve[0];
    int wid = blockIdx.x * 4 + wave;
    int nw = gridDim.x * 4;
    for (int p = wid; p < n; p += nw) {
        int4 vd = vdat[p];
        int sm = vd.x, dm = vd.y;
        float d = __int_as_float(vd.z);
        float s = d * INV_DD;
        int b0 = min((int)s, NB - 2);
        float fr = s - b0;
        float w0 = wtab[b0 * F_DIM + lane];
        float w1 = wtab[(b0 + 1) * F_DIM + lane];
        float w = w0 + fr * (w1 - w0);
        atomicAdd(&agg_m[dm * F_DIM + lane], xm[sm * F_DIM + lane] * w);
    }
}

// ---------------- blend ----------------
__global__ __launch_bounds__(256) void k_blend(const float* h_local, const float* h_hier,
                                               const int* is_m, const int* invg, const float* m,
                                               float* h_out) {
    int idx = blockIdx.x * 256 + threadIdx.x;
    int n = idx >> 7, c = idx & 127;
    float mm = m[n];
    float hh = is_m[n] ? h_hier[invg[n] * H_DIM + c] : 0.f;
    h_out[idx] = (1.f - mm) * h_local[idx] + mm * hh;
}

// ---------------- parallel segment-sum pooling ----------------
__global__ __launch_bounds__(256) void k_pool(const float* __restrict__ h, const int* __restrict__ batch,
                                              float* pooled) {
    int c = threadIdx.x & 127, a = threadIdx.x >> 7;
    int n0 = blockIdx.x * 64;
    float acc = 0.f;
    int cur = batch[n0 + a];
    for (int i = a; i < 64; i += 2) {
        int n = n0 + i;
        int b = batch[n];
        if (b != cur) { atomicAdd(&pooled[cur * H_DIM + c], acc); acc = 0.f; cur = b; }
        acc += h[n * H_DIM + c];
    }
    atomicAdd(&pooled[cur * H_DIM + c], acc);
}

// ---------------- predict MLP ----------------
__global__ __launch_bounds__(128) void k_pred2(const float* pooled,
                                               const float* w1, const float* b1,
                                               const float* w2, const float* b2,
                                               void* outv, const int* flag) {
    __shared__ float c64[64];
    int b = blockIdx.x, t = threadIdx.x;
    if (t < 64) {
        float v = b1[t];
        for (int k = 0; k < H_DIM; k++) v += pooled[b * H_DIM + k] * w1[k * 64 + t];
        c64[t] = v * sigm_f(v);
    }
    __syncthreads();
    if (t == 0) {
        float o = b2[0];
        for (int k = 0; k < 64; k++) o += c64[k] * w2[k];
        if (flag[0]) ((float*)outv)[b] = o;
        else ((__hip_bfloat16*)outv)[b] = __float2bfloat16(o);
    }
}

extern "C" void kernel_launch(void* const* d_in, const int* in_sizes, int n_in,
                              void* d_out, int out_size, void* d_ws, size_t ws_size,
                              hipStream_t stream) {
    (void)n_in; (void)out_size; (void)ws_size;
    const int* atoms = (const int*)d_in[0];
    const int* src = (const int*)d_in[2];
    const int* dst = (const int*)d_in[3];
    const int* batch = (const int*)d_in[4];

    float* W = (float*)d_ws;
    int* dflag = (int*)W; W += 16;
    int* counters = (int*)W; W += 16;  // [0]=npairs, [1]=nve
    float* kvbuf = (float*)(counters + 4);

    static const int fidx[25] = {1,5,6,7,8,9,10,11,12,13,14,15,16,17,18,19,20,21,22,23,24,25,26,27,28};
    float* fin[29];
    ConvArgs ca;
    float* convBase = W;
    int off = 0;
    for (int q = 0; q < 25; q++) {
        int i = fidx[q];
        ca.p[q] = d_in[i];
        ca.off[q] = off;
        fin[i] = convBase + off;
        off += in_sizes[i];
    }
    ca.off[25] = off;
    W += off;

    k_detect<<<1, 256, 0, stream>>>((const unsigned short*)d_in[5], in_sizes[5], dflag);
    k_convert_all<<<(off + 255) / 256, 256, 0, stream>>>(ca, convBase, dflag);

    const float* posf = fin[1];
    const float* embf = fin[5];

    float* h      = W; W += N_ATOMS * H_DIM;
    float* h_loc  = W; W += N_ATOMS * H_DIM;
    float* xbuf   = W; W += N_ATOMS * F_DIM;
    float* aggbuf = W; W += N_ATOMS * F_DIM;
    float* scores = W; W += N_ATOMS;
    float* mbuf   = W; W += N_ATOMS;
    float* h_m    = W; W += K_TOP * H_DIM;
    float* pos_m  = W; W += K_TOP * 3;
    float* xm     = W; W += K_TOP * F_DIM;
    float* qm     = W; W += K_TOP * S_DIM;
    float* km     = W; W += K_TOP * S_DIM;
    float* decay  = W; W += K_TOP * K_TOP;
    float* sbuf   = W; W += K_TOP * K_TOP;
    float* hi     = W; W += K_TOP * H_DIM;
    float* hj     = W; W += K_TOP * H_DIM;
    float* agg_m  = W; W += K_TOP * F_DIM;
    float* h_hier = W; W += K_TOP * H_DIM;
    float* pooled = W; W += B_BATCH * H_DIM;
    float* z1tab  = W; W += NB * F_DIM;
    float* wtab   = W; W += NB * F_DIM;
    float* ztabS  = W; W += NB * H_DIM;
    int* rankb  = (int*)W; W += N_ATOMS;
    int* is_m   = (int*)W; W += N_ATOMS;
    int* invg   = (int*)W; W += N_ATOMS;
    int* midx   = (int*)W; W += K_TOP;
    unsigned int* plist = (unsigned int*)W; W += K_TOP * K_TOP;
    int* esorted = (int*)W; W += E_EDGES;
    int* ehist  = (int*)W; W += N_ATOMS;
    int* ebase  = (int*)W; W += N_ATOMS;
    int* ecur   = (int*)W; W += N_ATOMS;
    int* bcount = (int*)W; W += 1024;
    int* boffset = (int*)W; W += 1024;
    int4* edat  = (int4*)W; W += E_EDGES * 4;
    int4* vdat  = (int4*)W; W += E_EDGES * 4;
    float2* sd  = (float2*)W; W += K_TOP * K_TOP * 2;
    float4* pd  = (float4*)W; W += K_TOP * K_TOP * 4;
    unsigned char* adj = (unsigned char*)W; W += (K_TOP * K_TOP) / 4;
    unsigned char* Av  = (unsigned char*)W; W += (K_TOP * K_TOP) / 4;

    // one-time: counting-sort edges by dst + packed edge data
    (void)hipMemsetAsync(ehist, 0, N_ATOMS * sizeof(int), stream);
    k_ehist<<<E_EDGES / 256, 256, 0, stream>>>(dst, ehist);
    k_escan<<<1, 1024, 0, stream>>>(ehist, ebase, ecur);
    k_escatter<<<E_EDGES / 256, 256, 0, stream>>>(dst, ecur, esorted);
    k_edat<<<E_EDGES / 256, 256, 0, stream>>>(esorted, src, dst, posf, edat);

    k_embed<<<(N_ATOMS * H_DIM) / 256, 256, 0, stream>>>(atoms, embf, h);

    for (int l = 0; l < L_LAYERS; l++) {
        const float* mw1 = fin[6]  + l * G_DIM * F_DIM;
        const float* mb1 = fin[7]  + l * F_DIM;
        const float* mw2 = fin[8]  + l * F_DIM * F_DIM;
        const float* mb2 = fin[9]  + l * F_DIM;
        const float* cf1 = fin[10] + l * H_DIM * F_DIM;
        const float* cf2w = fin[11] + l * F_DIM * H_DIM;
        const float* cf2b = fin[12] + l * H_DIM;
        const float* lw  = fin[13] + l * H_DIM * H_DIM;
        const float* lb  = fin[14] + l * H_DIM;
        const float* aw1 = fin[15] + l * (2 * H_DIM + G_DIM) * H_DIM;
        const float* ab1 = fin[16] + l * H_DIM;
        const float* aw2 = fin[17] + l * H_DIM;
        const float* ab2 = fin[18] + l;
        const float* msw1 = fin[19] + l * S_DIM * MH_DIM;
        const float* msb1 = fin[20] + l * MH_DIM;
        const float* msw2 = fin[21] + l * MH_DIM;
        const float* msb2 = fin[22] + l;
        const float* wq  = fin[23] + l * S_DIM * S_DIM;
        const float* wk  = fin[24] + l * S_DIM * S_DIM;

        k_ftab<<<NB, 128, 0, stream>>>(mw1, mb1, mw2, mb2, aw1, z1tab, wtab, ztabS);
        k_x<<<N_ATOMS / 4, 256, 0, stream>>>(h, cf1, xbuf, aggbuf, N_ATOMS);
        k_edge_s<<<E_EDGES / (4 * EPW2), 256, 0, stream>>>(edat, xbuf, wtab, aggbuf);
        k_update<<<N_ATOMS / 4, 256, 0, stream>>>(aggbuf, h, cf2w, cf2b, lw, lb, h_loc, N_ATOMS);
        k_scores<<<N_ATOMS / 256, 256, 0, stream>>>(h_loc, msw1, msb1, msw2, msb2, scores);
        k_rank<<<N_ATOMS / 16, 256, 0, stream>>>(scores, rankb, kvbuf);
        k_select2<<<N_ATOMS / 16, 256, 0, stream>>>(scores, rankb, kvbuf, is_m, invg, midx, mbuf);
        k_gather<<<(K_TOP * H_DIM) / 256, 256, 0, stream>>>(midx, h_loc, posf, h_m, pos_m, adj, counters);
        k_x<<<K_TOP / 4, 256, 0, stream>>>(h_m, cf1, xm, agg_m, K_TOP);
        k_adj<<<E_EDGES / 256, 256, 0, stream>>>(src, dst, is_m, invg, pos_m, adj, vdat, counters + 1);
        k_hijqk<<<320, 256, 0, stream>>>(h_m, aw1, wq, wk, hi, hj, qm, km);
        k_attn<<<K_TOP, 256, 0, stream>>>(qm, km, adj, Av);
        k_pcount<<<(K_TOP * K_TOP) / 256, 256, 0, stream>>>(Av, bcount);
        k_pscan<<<1, 1024, 0, stream>>>(bcount, boffset, counters);
        k_pscatter<<<(K_TOP * K_TOP) / 256, 256, 0, stream>>>(Av, boffset, pos_m, plist, sd);
        k_score_p<<<4096, 256, 0, stream>>>(sd, counters, hi, hj, ztabS, ab1, aw2, ab2, sbuf);
        k_decay<<<K_TOP, 256, 0, stream>>>(sbuf, Av, decay);
        k_pdat<<<1024, 256, 0, stream>>>(sd, counters, decay, pd);
        k_aggd_p2<<<4096, 256, 0, stream>>>(pd, counters, xm, z1tab, mb1, mw2, mb2, agg_m);
        k_aggs_p<<<256, 256, 0, stream>>>(vdat, counters + 1, xm, wtab, agg_m);
        k_update<<<K_TOP / 4, 256, 0, stream>>>(agg_m, h_m, cf2w, cf2b, lw, lb, h_hier, K_TOP);
        k_blend<<<(N_ATOMS * H_DIM) / 256, 256, 0, stream>>>(h_loc, h_hier, is_m, invg, mbuf, h);
    }

    (void)hipMemsetAsync(pooled, 0, B_BATCH * H_DIM * sizeof(float), stream);
    k_pool<<<N_ATOMS / 64, 256, 0, stream>>>(h, batch, pooled);
    k_pred2<<<B_BATCH, 128, 0, stream>>>(pooled, fin[25], fin[26], fin[27], fin[28], d_out, dflag);
}